// Round 1
// baseline (1252.760 us; speedup 1.0000x reference)
//
#include <hip/hip_runtime.h>
#include <math.h>

#define NEG_SLOPE 0.2f
#define BN_EPS 1e-5f

__device__ __forceinline__ float d_leaky(float x){ return x > 0.f ? x : NEG_SLOPE * x; }
__device__ __forceinline__ float d_elu(float x){ return x > 0.f ? x : expm1f(x); }

__device__ __forceinline__ float wave_sum(float v){
  #pragma unroll
  for (int off = 32; off > 0; off >>= 1) v += __shfl_xor(v, off, 64);
  return v;
}

// ---------------- CSR build ----------------
__global__ void k_count(const int* __restrict__ dst, int* __restrict__ deg, int E){
  int e = blockIdx.x * blockDim.x + threadIdx.x;
  if (e < E) atomicAdd(&deg[dst[e]], 1);
}

__global__ __launch_bounds__(1024) void k_scan(const int* __restrict__ deg, int* __restrict__ rowp,
                                               float* __restrict__ dinv, float* __restrict__ sdinv, int n){
  __shared__ int tmp[1024];
  __shared__ int carry_s;
  int t = threadIdx.x;
  if (t == 0) carry_s = 0;
  __syncthreads();
  for (int base = 0; base < n; base += 1024){
    int i = base + t;
    int v = (i < n) ? deg[i] : 0;
    tmp[t] = v;
    __syncthreads();
    for (int off = 1; off < 1024; off <<= 1){
      int u = (t >= off) ? tmp[t - off] : 0;
      __syncthreads();
      tmp[t] += u;
      __syncthreads();
    }
    int incl = tmp[t];
    int carry = carry_s;
    if (i < n){
      rowp[i] = carry + incl - v;          // exclusive prefix
      dinv[i] = rsqrtf((float)(v + 1));    // GCN: deg incl. self-loop
      sdinv[i] = 1.0f / fmaxf((float)v, 1.0f); // SAGE mean divisor
    }
    __syncthreads();
    if (t == 1023) carry_s = carry + incl;
    __syncthreads();
  }
  if (t == 0) rowp[n] = carry_s;
}

__global__ void k_scatter(const int* __restrict__ src, const int* __restrict__ dst,
                          const int* __restrict__ rowp, int* __restrict__ fill,
                          int* __restrict__ colv, int E){
  int e = blockIdx.x * blockDim.x + threadIdx.x;
  if (e < E){
    int d = dst[e];
    int pos = rowp[d] + atomicAdd(&fill[d], 1);
    colv[pos] = src[e];
  }
}

// ---------------- generic tiled fp32 GEMM ----------------
// C[M x Nc] = act( A[M x K] @ W[K x Nc] + bias + res ), act: 0=none 1=relu
// block 256 threads, 64x64 tile, 4x4 micro-tile. K % 16 == 0, Nc % 64 == 0.
__global__ __launch_bounds__(256) void k_gemm(
    const float* __restrict__ A, const float* __restrict__ W,
    const float* __restrict__ bias, const float* __restrict__ res,
    float* __restrict__ C, int M, int K, int Nc, int act)
{
  __shared__ float As[16][68];  // [k][m], padded
  __shared__ float Ws[16][64];  // [k][n]
  int tid = threadIdx.x;
  int tx = tid & 15, ty = tid >> 4;
  int row0 = blockIdx.x * 64;
  int col0 = blockIdx.y * 64;
  float acc[4][4] = {};
  int lm  = tid >> 2;         // 0..63 row within tile (A load)
  int lk4 = (tid & 3) * 4;    // k quad (A load)
  int ln  = tid & 63;         // col (W load)
  int lkw = tid >> 6;         // 0..3 (W load)

  for (int k0 = 0; k0 < K; k0 += 16){
    int ar = row0 + lm;
    float4 av = make_float4(0.f, 0.f, 0.f, 0.f);
    if (ar < M) av = *(const float4*)(A + (size_t)ar * K + k0 + lk4);
    As[lk4 + 0][lm] = av.x; As[lk4 + 1][lm] = av.y;
    As[lk4 + 2][lm] = av.z; As[lk4 + 3][lm] = av.w;
    #pragma unroll
    for (int i = 0; i < 4; i++){
      int kk = lkw + 4 * i;
      Ws[kk][ln] = W[(size_t)(k0 + kk) * Nc + col0 + ln];
    }
    __syncthreads();
    #pragma unroll
    for (int kk = 0; kk < 16; ++kk){
      float4 a = *(const float4*)&As[kk][ty * 4];
      float4 b = *(const float4*)&Ws[kk][tx * 4];
      acc[0][0] += a.x * b.x; acc[0][1] += a.x * b.y; acc[0][2] += a.x * b.z; acc[0][3] += a.x * b.w;
      acc[1][0] += a.y * b.x; acc[1][1] += a.y * b.y; acc[1][2] += a.y * b.z; acc[1][3] += a.y * b.w;
      acc[2][0] += a.z * b.x; acc[2][1] += a.z * b.y; acc[2][2] += a.z * b.z; acc[2][3] += a.z * b.w;
      acc[3][0] += a.w * b.x; acc[3][1] += a.w * b.y; acc[3][2] += a.w * b.z; acc[3][3] += a.w * b.w;
    }
    __syncthreads();
  }

  int c0 = col0 + tx * 4;
  float4 bv = make_float4(0.f, 0.f, 0.f, 0.f);
  if (bias) bv = *(const float4*)(bias + c0);
  #pragma unroll
  for (int i = 0; i < 4; i++){
    int r = row0 + ty * 4 + i;
    if (r >= M) continue;
    float4 v;
    v.x = acc[i][0] + bv.x; v.y = acc[i][1] + bv.y;
    v.z = acc[i][2] + bv.z; v.w = acc[i][3] + bv.w;
    if (res){
      float4 rv = *(const float4*)(res + (size_t)r * Nc + c0);
      v.x += rv.x; v.y += rv.y; v.z += rv.z; v.w += rv.w;
    }
    if (act == 1){
      v.x = fmaxf(v.x, 0.f); v.y = fmaxf(v.y, 0.f);
      v.z = fmaxf(v.z, 0.f); v.w = fmaxf(v.w, 0.f);
    }
    *(float4*)(C + (size_t)r * Nc + c0) = v;
  }
}

// ---------------- GAT attention coefficients per node ----------------
// block = heads*64 threads; one block per node
__global__ void k_gat_attn(const float* __restrict__ h, const float* __restrict__ asrc,
                           const float* __restrict__ adst, float* __restrict__ a_s,
                           float* __restrict__ a_d, int n, int heads){
  int node = blockIdx.x;
  int head = threadIdx.x >> 6;
  int lane = threadIdx.x & 63;
  int HC = heads << 6;
  float v = h[(size_t)node * HC + (head << 6) + lane];
  float s = wave_sum(v * asrc[(head << 6) + lane]);
  float d = wave_sum(v * adst[(head << 6) + lane]);
  if (lane == 0){
    a_s[node * heads + head] = s;
    a_d[node * heads + head] = d;
  }
}

// ---------------- GAT aggregation (softmax over in-edges + self-loop) ----------------
// block = heads*64 threads; one block per node. out = elu(agg + bias)
__global__ void k_gat_agg(const float* __restrict__ h, const int* __restrict__ rowp,
                          const int* __restrict__ colv, const float* __restrict__ a_s,
                          const float* __restrict__ a_d, const float* __restrict__ bias,
                          float* __restrict__ out, int n, int heads){
  int node = blockIdx.x;
  int head = threadIdx.x >> 6;
  int c = threadIdx.x & 63;
  int HC = heads << 6;
  float ad = a_d[node * heads + head];
  int b = rowp[node], e = rowp[node + 1];
  float eself = d_leaky(a_s[node * heads + head] + ad);
  float m = eself;
  for (int i = b; i < e; i++){
    int s = colv[i];
    m = fmaxf(m, d_leaky(a_s[s * heads + head] + ad));
  }
  float ex = __expf(eself - m);
  float denom = ex;
  float acc = ex * h[(size_t)node * HC + (head << 6) + c];
  for (int i = b; i < e; i++){
    int s = colv[i];
    float exs = __expf(d_leaky(a_s[s * heads + head] + ad) - m);
    denom += exs;
    acc += exs * h[(size_t)s * HC + (head << 6) + c];
  }
  out[(size_t)node * HC + (head << 6) + c] = d_elu(acc / (denom + 1e-16f) + bias[(head << 6) + c]);
}

// ---------------- GCN aggregation ----------------
// out = relu( dinv[i]*( sum_j dinv[j]*h[j] + dinv[i]*h[i] ) + bias ), F=64
__global__ void k_gcn_agg(const float* __restrict__ h, const int* __restrict__ rowp,
                          const int* __restrict__ colv, const float* __restrict__ dinv,
                          const float* __restrict__ bias, float* __restrict__ out, int n){
  int node = blockIdx.x * 4 + (threadIdx.x >> 6);
  int c = threadIdx.x & 63;
  if (node >= n) return;
  float di = dinv[node];
  float acc = di * h[(size_t)node * 64 + c];
  int b = rowp[node], e = rowp[node + 1];
  for (int i = b; i < e; i++){
    int s = colv[i];
    acc += dinv[s] * h[(size_t)s * 64 + c];
  }
  out[(size_t)node * 64 + c] = fmaxf(di * acc + bias[c], 0.f);
}

// ---------------- SAGE mean aggregation (no self-loop) ----------------
__global__ void k_sage_agg(const float* __restrict__ xin, const int* __restrict__ rowp,
                           const int* __restrict__ colv, const float* __restrict__ sdinv,
                           float* __restrict__ out, int n, int F){
  int npb = blockDim.x / F;
  int node = blockIdx.x * npb + threadIdx.x / F;
  int c = threadIdx.x % F;
  if (node >= n) return;
  float acc = 0.f;
  int b = rowp[node], e = rowp[node + 1];
  for (int i = b; i < e; i++) acc += xin[(size_t)colv[i] * F + c];
  out[(size_t)node * F + c] = acc * sdinv[node];
}

// ---------------- BatchNorm ----------------
__global__ void k_bn_stats(const float* __restrict__ x, float* __restrict__ sums, int n){
  int c = threadIdx.x & 63;
  int rl = threadIdx.x >> 6; // 0..3
  float s = 0.f, q = 0.f;
  for (int r = blockIdx.x * 4 + rl; r < n; r += gridDim.x * 4){
    float v = x[(size_t)r * 64 + c];
    s += v; q += v * v;
  }
  __shared__ float ls[4][64], lq[4][64];
  ls[rl][c] = s; lq[rl][c] = q;
  __syncthreads();
  if (rl == 0){
    s = ls[0][c] + ls[1][c] + ls[2][c] + ls[3][c];
    q = lq[0][c] + lq[1][c] + lq[2][c] + lq[3][c];
    atomicAdd(&sums[c], s);
    atomicAdd(&sums[64 + c], q);
  }
}

__global__ void k_bn_apply(const float* __restrict__ x, const float* __restrict__ sums,
                           const float* __restrict__ g, const float* __restrict__ b,
                           float* __restrict__ outb, int n, int ldout){
  int idx = blockIdx.x * blockDim.x + threadIdx.x;
  if (idx >= n * 64) return;
  int r = idx >> 6, c = idx & 63;
  float m = sums[c] / (float)n;
  float var = sums[64 + c] / (float)n - m * m;
  outb[(size_t)r * ldout + c] = (x[idx] - m) * rsqrtf(var + BN_EPS) * g[c] + b[c];
}

// ---------------- final tiny FC (64 -> 2) ----------------
__global__ void k_fc2(const float* __restrict__ h, const float* __restrict__ w,
                      const float* __restrict__ b, float* __restrict__ out, int n){
  int node = blockIdx.x * 4 + (threadIdx.x >> 6);
  int lane = threadIdx.x & 63;
  if (node >= n) return;
  float v = h[(size_t)node * 64 + lane];
  float p0 = wave_sum(v * w[lane * 2 + 0]);
  float p1 = wave_sum(v * w[lane * 2 + 1]);
  if (lane == 0){
    out[node * 2 + 0] = p0 + b[0];
    out[node * 2 + 1] = p1 + b[1];
  }
}

static inline void gemm(const float* A, const float* W, const float* bias, const float* res,
                        float* C, int M, int K, int Nc, int act, hipStream_t stream){
  dim3 g((M + 63) / 64, Nc / 64);
  k_gemm<<<g, 256, 0, stream>>>(A, W, bias, res, C, M, K, Nc, act);
}

extern "C" void kernel_launch(void* const* d_in, const int* in_sizes, int n_in,
                              void* d_out, int out_size, void* d_ws, size_t ws_size,
                              hipStream_t stream){
  (void)n_in; (void)out_size; (void)ws_size;
  const float* x        = (const float*)d_in[0];
  const int*   ei       = (const int*)  d_in[1];
  const float* gcn1_w   = (const float*)d_in[2];
  const float* gcn1_b   = (const float*)d_in[3];
  const float* gcn2_w   = (const float*)d_in[4];
  const float* gcn2_b   = (const float*)d_in[5];
  const float* gat1_w   = (const float*)d_in[6];
  const float* gat1_as  = (const float*)d_in[7];
  const float* gat1_ad  = (const float*)d_in[8];
  const float* gat1_b   = (const float*)d_in[9];
  const float* gat2_w   = (const float*)d_in[10];
  const float* gat2_as  = (const float*)d_in[11];
  const float* gat2_ad  = (const float*)d_in[12];
  const float* gat2_b   = (const float*)d_in[13];
  const float* sage1_wl = (const float*)d_in[14];
  const float* sage1_bl = (const float*)d_in[15];
  const float* sage1_wr = (const float*)d_in[16];
  const float* sage2_wl = (const float*)d_in[17];
  const float* sage2_bl = (const float*)d_in[18];
  const float* sage2_wr = (const float*)d_in[19];
  const float* bn_gcn_g = (const float*)d_in[20];
  const float* bn_gcn_b = (const float*)d_in[21];
  const float* bn_gat_g = (const float*)d_in[22];
  const float* bn_gat_b = (const float*)d_in[23];
  const float* bn_sage_g= (const float*)d_in[24];
  const float* bn_sage_b= (const float*)d_in[25];
  const float* fc1_w    = (const float*)d_in[26];
  const float* fc1_b    = (const float*)d_in[27];
  const float* fc2_w    = (const float*)d_in[28];
  const float* fc2_b    = (const float*)d_in[29];
  float* out = (float*)d_out;

  const int N = in_sizes[0] / 128;
  const int E = in_sizes[1] / 2;
  const int* src = ei;
  const int* dst = ei + E;

  char* ws = (char*)d_ws;
  size_t off = 0;
  auto alloc = [&](size_t bytes) -> void* {
    void* p = ws + off;
    off = (off + bytes + 255) & ~(size_t)255;
    return p;
  };
  int*   deg   = (int*)  alloc((size_t)N * 4);
  int*   rowp  = (int*)  alloc((size_t)(N + 1) * 4);
  int*   fill  = (int*)  alloc((size_t)N * 4);
  int*   colv  = (int*)  alloc((size_t)E * 4);
  float* dinv  = (float*)alloc((size_t)N * 4);
  float* sdinv = (float*)alloc((size_t)N * 4);
  float* as1   = (float*)alloc((size_t)N * 4 * 4);
  float* ad1   = (float*)alloc((size_t)N * 4 * 4);
  float* as2   = (float*)alloc((size_t)N * 4);
  float* ad2   = (float*)alloc((size_t)N * 4);
  float* bnA   = (float*)alloc(128 * 4);
  float* bnB   = (float*)alloc(128 * 4);
  float* bnC   = (float*)alloc(128 * 4);
  float* bufA  = (float*)alloc((size_t)N * 256 * 4);
  float* bufB  = (float*)alloc((size_t)N * 256 * 4);
  float* t1    = (float*)alloc((size_t)N * 64 * 4);
  float* t2    = (float*)alloc((size_t)N * 64 * 4);
  float* t3    = (float*)alloc((size_t)N * 64 * 4);
  float* cat   = (float*)alloc((size_t)N * 192 * 4);

  hipMemsetAsync(deg, 0, (size_t)N * 4, stream);
  hipMemsetAsync(fill, 0, (size_t)N * 4, stream);
  hipMemsetAsync(bnA, 0, 128 * 4, stream);
  hipMemsetAsync(bnB, 0, 128 * 4, stream);
  hipMemsetAsync(bnC, 0, 128 * 4, stream);

  // CSR by destination
  k_count  <<<(E + 255) / 256, 256, 0, stream>>>(dst, deg, E);
  k_scan   <<<1, 1024, 0, stream>>>(deg, rowp, dinv, sdinv, N);
  k_scatter<<<(E + 255) / 256, 256, 0, stream>>>(src, dst, rowp, fill, colv, E);

  // ---- GAT branch (first: uses the big buffers) ----
  gemm(x, gat1_w, nullptr, nullptr, bufA, N, 128, 256, 0, stream);          // HA1
  k_gat_attn<<<N, 256, 0, stream>>>(bufA, gat1_as, gat1_ad, as1, ad1, N, 4);
  k_gat_agg <<<N, 256, 0, stream>>>(bufA, rowp, colv, as1, ad1, gat1_b, bufB, N, 4); // A1
  gemm(bufB, gat2_w, nullptr, nullptr, t1, N, 256, 64, 0, stream);          // HA2
  k_gat_attn<<<N, 64, 0, stream>>>(t1, gat2_as, gat2_ad, as2, ad2, N, 1);
  k_gat_agg <<<N, 64, 0, stream>>>(t1, rowp, colv, as2, ad2, gat2_b, t2, N, 1);      // A2
  k_bn_stats<<<128, 256, 0, stream>>>(t2, bnA, N);
  k_bn_apply<<<(N * 64 + 255) / 256, 256, 0, stream>>>(t2, bnA, bn_gat_g, bn_gat_b, cat + 64, N, 192);

  // ---- GCN branch ----
  gemm(x, gcn1_w, nullptr, nullptr, t1, N, 128, 64, 0, stream);             // H1
  k_gcn_agg<<<(N + 3) / 4, 256, 0, stream>>>(t1, rowp, colv, dinv, gcn1_b, t2, N);   // G1
  gemm(t2, gcn2_w, nullptr, nullptr, t1, N, 64, 64, 0, stream);             // H2
  k_gcn_agg<<<(N + 3) / 4, 256, 0, stream>>>(t1, rowp, colv, dinv, gcn2_b, t3, N);   // G2
  k_bn_stats<<<128, 256, 0, stream>>>(t3, bnB, N);
  k_bn_apply<<<(N * 64 + 255) / 256, 256, 0, stream>>>(t3, bnB, bn_gcn_g, bn_gcn_b, cat + 0, N, 192);

  // ---- SAGE branch ----
  k_sage_agg<<<(N + 1) / 2, 256, 0, stream>>>(x, rowp, colv, sdinv, bufA, N, 128);   // aggX
  gemm(x, sage1_wr, nullptr, nullptr, t1, N, 128, 64, 0, stream);           // T1 = x@wr
  gemm(bufA, sage1_wl, sage1_bl, t1, t2, N, 128, 64, 1, stream);            // S1 = relu(agg@wl + bl + T1)
  k_sage_agg<<<(N + 3) / 4, 256, 0, stream>>>(t2, rowp, colv, sdinv, bufA, N, 64);   // aggS
  gemm(t2, sage2_wr, nullptr, nullptr, t1, N, 64, 64, 0, stream);           // T2 = S1@wr
  gemm(bufA, sage2_wl, sage2_bl, t1, t3, N, 64, 64, 1, stream);             // S2
  k_bn_stats<<<128, 256, 0, stream>>>(t3, bnC, N);
  k_bn_apply<<<(N * 64 + 255) / 256, 256, 0, stream>>>(t3, bnC, bn_sage_g, bn_sage_b, cat + 128, N, 192);

  // ---- FC head ----
  gemm(cat, fc1_w, fc1_b, nullptr, t1, N, 192, 64, 1, stream);              // F1
  k_fc2<<<(N + 3) / 4, 256, 0, stream>>>(t1, fc2_w, fc2_b, out, N);
}

// Round 2
// 986.012 us; speedup vs baseline: 1.2705x; 1.2705x over previous
//
#include <hip/hip_runtime.h>
#include <math.h>

#define NEG_SLOPE 0.2f
#define BN_EPS 1e-5f

__device__ __forceinline__ float d_leaky(float x){ return x > 0.f ? x : NEG_SLOPE * x; }
__device__ __forceinline__ float d_elu(float x){ return x > 0.f ? x : expm1f(x); }

__device__ __forceinline__ float wave_sum(float v){
  #pragma unroll
  for (int off = 32; off > 0; off >>= 1) v += __shfl_xor(v, off, 64);
  return v;
}

// ---------------- CSR build ----------------
__global__ void k_count(const int* __restrict__ dst, int* __restrict__ deg, int E){
  int e = blockIdx.x * blockDim.x + threadIdx.x;
  if (e < E) atomicAdd(&deg[dst[e]], 1);
}

__global__ __launch_bounds__(1024) void k_scan(const int* __restrict__ deg, int* __restrict__ rowp,
                                               float* __restrict__ dinv, float* __restrict__ sdinv, int n){
  __shared__ int tmp[1024];
  __shared__ int carry_s;
  int t = threadIdx.x;
  if (t == 0) carry_s = 0;
  __syncthreads();
  for (int base = 0; base < n; base += 1024){
    int i = base + t;
    int v = (i < n) ? deg[i] : 0;
    tmp[t] = v;
    __syncthreads();
    for (int off = 1; off < 1024; off <<= 1){
      int u = (t >= off) ? tmp[t - off] : 0;
      __syncthreads();
      tmp[t] += u;
      __syncthreads();
    }
    int incl = tmp[t];
    int carry = carry_s;
    if (i < n){
      rowp[i] = carry + incl - v;          // exclusive prefix
      dinv[i] = rsqrtf((float)(v + 1));    // GCN: deg incl. self-loop
      sdinv[i] = 1.0f / fmaxf((float)v, 1.0f); // SAGE mean divisor
    }
    __syncthreads();
    if (t == 1023) carry_s = carry + incl;
    __syncthreads();
  }
  if (t == 0) rowp[n] = carry_s;
}

__global__ void k_scatter(const int* __restrict__ src, const int* __restrict__ dst,
                          const int* __restrict__ rowp, int* __restrict__ fill,
                          int* __restrict__ colv, int E){
  int e = blockIdx.x * blockDim.x + threadIdx.x;
  if (e < E){
    int d = dst[e];
    int pos = rowp[d] + atomicAdd(&fill[d], 1);
    colv[pos] = src[e];
  }
}

// ---------------- generic tiled fp32 GEMM ----------------
__global__ __launch_bounds__(256) void k_gemm(
    const float* __restrict__ A, const float* __restrict__ W,
    const float* __restrict__ bias, const float* __restrict__ res,
    float* __restrict__ C, int M, int K, int Nc, int act)
{
  __shared__ float As[16][68];  // [k][m], padded
  __shared__ float Ws[16][64];  // [k][n]
  int tid = threadIdx.x;
  int tx = tid & 15, ty = tid >> 4;
  int row0 = blockIdx.x * 64;
  int col0 = blockIdx.y * 64;
  float acc[4][4] = {};
  int lm  = tid >> 2;         // 0..63 row within tile (A load)
  int lk4 = (tid & 3) * 4;    // k quad (A load)
  int ln  = tid & 63;         // col (W load)
  int lkw = tid >> 6;         // 0..3 (W load)

  for (int k0 = 0; k0 < K; k0 += 16){
    int ar = row0 + lm;
    float4 av = make_float4(0.f, 0.f, 0.f, 0.f);
    if (ar < M) av = *(const float4*)(A + (size_t)ar * K + k0 + lk4);
    As[lk4 + 0][lm] = av.x; As[lk4 + 1][lm] = av.y;
    As[lk4 + 2][lm] = av.z; As[lk4 + 3][lm] = av.w;
    #pragma unroll
    for (int i = 0; i < 4; i++){
      int kk = lkw + 4 * i;
      Ws[kk][ln] = W[(size_t)(k0 + kk) * Nc + col0 + ln];
    }
    __syncthreads();
    #pragma unroll
    for (int kk = 0; kk < 16; ++kk){
      float4 a = *(const float4*)&As[kk][ty * 4];
      float4 b = *(const float4*)&Ws[kk][tx * 4];
      acc[0][0] += a.x * b.x; acc[0][1] += a.x * b.y; acc[0][2] += a.x * b.z; acc[0][3] += a.x * b.w;
      acc[1][0] += a.y * b.x; acc[1][1] += a.y * b.y; acc[1][2] += a.y * b.z; acc[1][3] += a.y * b.w;
      acc[2][0] += a.z * b.x; acc[2][1] += a.z * b.y; acc[2][2] += a.z * b.z; acc[2][3] += a.z * b.w;
      acc[3][0] += a.w * b.x; acc[3][1] += a.w * b.y; acc[3][2] += a.w * b.z; acc[3][3] += a.w * b.w;
    }
    __syncthreads();
  }

  int c0 = col0 + tx * 4;
  float4 bv = make_float4(0.f, 0.f, 0.f, 0.f);
  if (bias) bv = *(const float4*)(bias + c0);
  #pragma unroll
  for (int i = 0; i < 4; i++){
    int r = row0 + ty * 4 + i;
    if (r >= M) continue;
    float4 v;
    v.x = acc[i][0] + bv.x; v.y = acc[i][1] + bv.y;
    v.z = acc[i][2] + bv.z; v.w = acc[i][3] + bv.w;
    if (res){
      float4 rv = *(const float4*)(res + (size_t)r * Nc + c0);
      v.x += rv.x; v.y += rv.y; v.z += rv.z; v.w += rv.w;
    }
    if (act == 1){
      v.x = fmaxf(v.x, 0.f); v.y = fmaxf(v.y, 0.f);
      v.z = fmaxf(v.z, 0.f); v.w = fmaxf(v.w, 0.f);
    }
    *(float4*)(C + (size_t)r * Nc + c0) = v;
  }
}

// ---------------- GAT attention coefficients per node ----------------
// 4 nodes per block for heads=1; 1 node per block for heads=4 (256 threads both)
__global__ void k_gat_attn(const float* __restrict__ h, const float* __restrict__ asrc,
                           const float* __restrict__ adst, float* __restrict__ a_s,
                           float* __restrict__ a_d, int n, int heads){
  int wave = threadIdx.x >> 6;
  int lane = threadIdx.x & 63;
  int node, head;
  if (heads == 4){ node = blockIdx.x; head = wave; }
  else { node = blockIdx.x * 4 + wave; head = 0; }
  if (node >= n) return;
  int HC = heads << 6;
  float v = h[(size_t)node * HC + (head << 6) + lane];
  float s = wave_sum(v * asrc[(head << 6) + lane]);
  float d = wave_sum(v * adst[(head << 6) + lane]);
  if (lane == 0){
    a_s[node * heads + head] = s;
    a_d[node * heads + head] = d;
  }
}

// ---------------- GAT aggregation, heads=4, single-pass softmax (no max), unroll 4 ----
__global__ __launch_bounds__(256) void k_gat_agg4(
    const float* __restrict__ h, const int* __restrict__ rowp,
    const int* __restrict__ colv, const float* __restrict__ a_s,
    const float* __restrict__ a_d, const float* __restrict__ bias,
    float* __restrict__ out, int n){
  int node = blockIdx.x;
  int head = threadIdx.x >> 6;
  int c = threadIdx.x & 63;
  int hc = (head << 6) + c;
  float ad = a_d[node * 4 + head];
  int b = rowp[node], e = rowp[node + 1];
  float denom = __expf(d_leaky(a_s[node * 4 + head] + ad));
  float acc = denom * h[(size_t)node * 256 + hc];
  int i = b;
  for (; i + 4 <= e; i += 4){
    int s0 = colv[i+0], s1 = colv[i+1], s2 = colv[i+2], s3 = colv[i+3];
    float w0 = __expf(d_leaky(a_s[s0 * 4 + head] + ad));
    float w1 = __expf(d_leaky(a_s[s1 * 4 + head] + ad));
    float w2 = __expf(d_leaky(a_s[s2 * 4 + head] + ad));
    float w3 = __expf(d_leaky(a_s[s3 * 4 + head] + ad));
    float h0 = h[(size_t)s0 * 256 + hc];
    float h1 = h[(size_t)s1 * 256 + hc];
    float h2 = h[(size_t)s2 * 256 + hc];
    float h3 = h[(size_t)s3 * 256 + hc];
    denom += (w0 + w1) + (w2 + w3);
    acc += w0 * h0 + w1 * h1 + w2 * h2 + w3 * h3;
  }
  for (; i < e; i++){
    int s = colv[i];
    float w = __expf(d_leaky(a_s[s * 4 + head] + ad));
    denom += w;
    acc += w * h[(size_t)s * 256 + hc];
  }
  out[(size_t)node * 256 + hc] = d_elu(acc / (denom + 1e-16f) + bias[hc]);
}

// ---------------- GAT aggregation, heads=1, 4 nodes/block, unroll 4 ----------------
__global__ __launch_bounds__(256) void k_gat_agg1(
    const float* __restrict__ h, const int* __restrict__ rowp,
    const int* __restrict__ colv, const float* __restrict__ a_s,
    const float* __restrict__ a_d, const float* __restrict__ bias,
    float* __restrict__ out, int n){
  int node = blockIdx.x * 4 + (threadIdx.x >> 6);
  int c = threadIdx.x & 63;
  if (node >= n) return;
  float ad = a_d[node];
  int b = rowp[node], e = rowp[node + 1];
  float denom = __expf(d_leaky(a_s[node] + ad));
  float acc = denom * h[(size_t)node * 64 + c];
  int i = b;
  for (; i + 4 <= e; i += 4){
    int s0 = colv[i+0], s1 = colv[i+1], s2 = colv[i+2], s3 = colv[i+3];
    float w0 = __expf(d_leaky(a_s[s0] + ad));
    float w1 = __expf(d_leaky(a_s[s1] + ad));
    float w2 = __expf(d_leaky(a_s[s2] + ad));
    float w3 = __expf(d_leaky(a_s[s3] + ad));
    float h0 = h[(size_t)s0 * 64 + c];
    float h1 = h[(size_t)s1 * 64 + c];
    float h2 = h[(size_t)s2 * 64 + c];
    float h3 = h[(size_t)s3 * 64 + c];
    denom += (w0 + w1) + (w2 + w3);
    acc += w0 * h0 + w1 * h1 + w2 * h2 + w3 * h3;
  }
  for (; i < e; i++){
    int s = colv[i];
    float w = __expf(d_leaky(a_s[s] + ad));
    denom += w;
    acc += w * h[(size_t)s * 64 + c];
  }
  out[(size_t)node * 64 + c] = d_elu(acc / (denom + 1e-16f) + bias[c]);
}

// ---------------- GCN aggregation (F=64), unroll 4 ----------------
__global__ __launch_bounds__(256) void k_gcn_agg(
    const float* __restrict__ h, const int* __restrict__ rowp,
    const int* __restrict__ colv, const float* __restrict__ dinv,
    const float* __restrict__ bias, float* __restrict__ out, int n){
  int node = blockIdx.x * 4 + (threadIdx.x >> 6);
  int c = threadIdx.x & 63;
  if (node >= n) return;
  float di = dinv[node];
  float acc = di * h[(size_t)node * 64 + c];
  int b = rowp[node], e = rowp[node + 1];
  int i = b;
  for (; i + 4 <= e; i += 4){
    int s0 = colv[i+0], s1 = colv[i+1], s2 = colv[i+2], s3 = colv[i+3];
    float w0 = dinv[s0], w1 = dinv[s1], w2 = dinv[s2], w3 = dinv[s3];
    float h0 = h[(size_t)s0 * 64 + c];
    float h1 = h[(size_t)s1 * 64 + c];
    float h2 = h[(size_t)s2 * 64 + c];
    float h3 = h[(size_t)s3 * 64 + c];
    acc += w0 * h0 + w1 * h1 + w2 * h2 + w3 * h3;
  }
  for (; i < e; i++){
    int s = colv[i];
    acc += dinv[s] * h[(size_t)s * 64 + c];
  }
  out[(size_t)node * 64 + c] = fmaxf(di * acc + bias[c], 0.f);
}

// ---------------- SAGE mean aggregation (no self-loop), unroll 4 ----------------
__global__ __launch_bounds__(256) void k_sage_agg(
    const float* __restrict__ xin, const int* __restrict__ rowp,
    const int* __restrict__ colv, const float* __restrict__ sdinv,
    float* __restrict__ out, int n, int F){
  int npb = 256 / F;
  int node = blockIdx.x * npb + (int)threadIdx.x / F;
  int c = (int)threadIdx.x % F;
  if (node >= n) return;
  float acc = 0.f;
  int b = rowp[node], e = rowp[node + 1];
  int i = b;
  for (; i + 4 <= e; i += 4){
    int s0 = colv[i+0], s1 = colv[i+1], s2 = colv[i+2], s3 = colv[i+3];
    float h0 = xin[(size_t)s0 * F + c];
    float h1 = xin[(size_t)s1 * F + c];
    float h2 = xin[(size_t)s2 * F + c];
    float h3 = xin[(size_t)s3 * F + c];
    acc += (h0 + h1) + (h2 + h3);
  }
  for (; i < e; i++) acc += xin[(size_t)colv[i] * F + c];
  out[(size_t)node * F + c] = acc * sdinv[node];
}

// ---------------- BatchNorm ----------------
__global__ void k_bn_stats(const float* __restrict__ x, float* __restrict__ sums, int n){
  int c = threadIdx.x & 63;
  int rl = threadIdx.x >> 6; // 0..3
  float s = 0.f, q = 0.f;
  for (int r = blockIdx.x * 4 + rl; r < n; r += gridDim.x * 4){
    float v = x[(size_t)r * 64 + c];
    s += v; q += v * v;
  }
  __shared__ float ls[4][64], lq[4][64];
  ls[rl][c] = s; lq[rl][c] = q;
  __syncthreads();
  if (rl == 0){
    s = ls[0][c] + ls[1][c] + ls[2][c] + ls[3][c];
    q = lq[0][c] + lq[1][c] + lq[2][c] + lq[3][c];
    atomicAdd(&sums[c], s);
    atomicAdd(&sums[64 + c], q);
  }
}

__global__ void k_bn_apply(const float* __restrict__ x, const float* __restrict__ sums,
                           const float* __restrict__ g, const float* __restrict__ b,
                           float* __restrict__ outb, int n, int ldout){
  int idx = blockIdx.x * blockDim.x + threadIdx.x;
  if (idx >= n * 64) return;
  int r = idx >> 6, c = idx & 63;
  float m = sums[c] / (float)n;
  float var = sums[64 + c] / (float)n - m * m;
  outb[(size_t)r * ldout + c] = (x[idx] - m) * rsqrtf(var + BN_EPS) * g[c] + b[c];
}

// ---------------- final tiny FC (64 -> 2) ----------------
__global__ void k_fc2(const float* __restrict__ h, const float* __restrict__ w,
                      const float* __restrict__ b, float* __restrict__ out, int n){
  int node = blockIdx.x * 4 + (threadIdx.x >> 6);
  int lane = threadIdx.x & 63;
  if (node >= n) return;
  float v = h[(size_t)node * 64 + lane];
  float p0 = wave_sum(v * w[lane * 2 + 0]);
  float p1 = wave_sum(v * w[lane * 2 + 1]);
  if (lane == 0){
    out[node * 2 + 0] = p0 + b[0];
    out[node * 2 + 1] = p1 + b[1];
  }
}

static inline void gemm(const float* A, const float* W, const float* bias, const float* res,
                        float* C, int M, int K, int Nc, int act, hipStream_t stream){
  dim3 g((M + 63) / 64, Nc / 64);
  k_gemm<<<g, 256, 0, stream>>>(A, W, bias, res, C, M, K, Nc, act);
}

extern "C" void kernel_launch(void* const* d_in, const int* in_sizes, int n_in,
                              void* d_out, int out_size, void* d_ws, size_t ws_size,
                              hipStream_t stream){
  (void)n_in; (void)out_size; (void)ws_size;
  const float* x        = (const float*)d_in[0];
  const int*   ei       = (const int*)  d_in[1];
  const float* gcn1_w   = (const float*)d_in[2];
  const float* gcn1_b   = (const float*)d_in[3];
  const float* gcn2_w   = (const float*)d_in[4];
  const float* gcn2_b   = (const float*)d_in[5];
  const float* gat1_w   = (const float*)d_in[6];
  const float* gat1_as  = (const float*)d_in[7];
  const float* gat1_ad  = (const float*)d_in[8];
  const float* gat1_b   = (const float*)d_in[9];
  const float* gat2_w   = (const float*)d_in[10];
  const float* gat2_as  = (const float*)d_in[11];
  const float* gat2_ad  = (const float*)d_in[12];
  const float* gat2_b   = (const float*)d_in[13];
  const float* sage1_wl = (const float*)d_in[14];
  const float* sage1_bl = (const float*)d_in[15];
  const float* sage1_wr = (const float*)d_in[16];
  const float* sage2_wl = (const float*)d_in[17];
  const float* sage2_bl = (const float*)d_in[18];
  const float* sage2_wr = (const float*)d_in[19];
  const float* bn_gcn_g = (const float*)d_in[20];
  const float* bn_gcn_b = (const float*)d_in[21];
  const float* bn_gat_g = (const float*)d_in[22];
  const float* bn_gat_b = (const float*)d_in[23];
  const float* bn_sage_g= (const float*)d_in[24];
  const float* bn_sage_b= (const float*)d_in[25];
  const float* fc1_w    = (const float*)d_in[26];
  const float* fc1_b    = (const float*)d_in[27];
  const float* fc2_w    = (const float*)d_in[28];
  const float* fc2_b    = (const float*)d_in[29];
  float* out = (float*)d_out;

  const int N = in_sizes[0] / 128;
  const int E = in_sizes[1] / 2;
  const int* src = ei;
  const int* dst = ei + E;

  char* ws = (char*)d_ws;
  size_t off = 0;
  auto alloc = [&](size_t bytes) -> void* {
    void* p = ws + off;
    off = (off + bytes + 255) & ~(size_t)255;
    return p;
  };
  int*   deg   = (int*)  alloc((size_t)N * 4);
  int*   rowp  = (int*)  alloc((size_t)(N + 1) * 4);
  int*   fill  = (int*)  alloc((size_t)N * 4);
  int*   colv  = (int*)  alloc((size_t)E * 4);
  float* dinv  = (float*)alloc((size_t)N * 4);
  float* sdinv = (float*)alloc((size_t)N * 4);
  float* as1   = (float*)alloc((size_t)N * 4 * 4);
  float* ad1   = (float*)alloc((size_t)N * 4 * 4);
  float* as2   = (float*)alloc((size_t)N * 4);
  float* ad2   = (float*)alloc((size_t)N * 4);
  float* bnA   = (float*)alloc(128 * 4);
  float* bnB   = (float*)alloc(128 * 4);
  float* bnC   = (float*)alloc(128 * 4);
  float* bufA  = (float*)alloc((size_t)N * 256 * 4);
  float* bufB  = (float*)alloc((size_t)N * 256 * 4);
  float* t1    = (float*)alloc((size_t)N * 64 * 4);
  float* t2    = (float*)alloc((size_t)N * 64 * 4);
  float* t3    = (float*)alloc((size_t)N * 64 * 4);
  float* cat   = (float*)alloc((size_t)N * 192 * 4);

  hipMemsetAsync(deg, 0, (size_t)N * 4, stream);
  hipMemsetAsync(fill, 0, (size_t)N * 4, stream);
  hipMemsetAsync(bnA, 0, 128 * 4, stream);
  hipMemsetAsync(bnB, 0, 128 * 4, stream);
  hipMemsetAsync(bnC, 0, 128 * 4, stream);

  // CSR by destination
  k_count  <<<(E + 255) / 256, 256, 0, stream>>>(dst, deg, E);
  k_scan   <<<1, 1024, 0, stream>>>(deg, rowp, dinv, sdinv, N);
  k_scatter<<<(E + 255) / 256, 256, 0, stream>>>(src, dst, rowp, fill, colv, E);

  // ---- GAT branch ----
  gemm(x, gat1_w, nullptr, nullptr, bufA, N, 128, 256, 0, stream);          // HA1
  k_gat_attn<<<N, 256, 0, stream>>>(bufA, gat1_as, gat1_ad, as1, ad1, N, 4);
  k_gat_agg4<<<N, 256, 0, stream>>>(bufA, rowp, colv, as1, ad1, gat1_b, bufB, N);
  gemm(bufB, gat2_w, nullptr, nullptr, t1, N, 256, 64, 0, stream);          // HA2
  k_gat_attn<<<(N + 3) / 4, 256, 0, stream>>>(t1, gat2_as, gat2_ad, as2, ad2, N, 1);
  k_gat_agg1<<<(N + 3) / 4, 256, 0, stream>>>(t1, rowp, colv, as2, ad2, gat2_b, t2, N);
  k_bn_stats<<<128, 256, 0, stream>>>(t2, bnA, N);
  k_bn_apply<<<(N * 64 + 255) / 256, 256, 0, stream>>>(t2, bnA, bn_gat_g, bn_gat_b, cat + 64, N, 192);

  // ---- GCN branch ----
  gemm(x, gcn1_w, nullptr, nullptr, t1, N, 128, 64, 0, stream);             // H1
  k_gcn_agg<<<(N + 3) / 4, 256, 0, stream>>>(t1, rowp, colv, dinv, gcn1_b, t2, N);   // G1
  gemm(t2, gcn2_w, nullptr, nullptr, t1, N, 64, 64, 0, stream);             // H2
  k_gcn_agg<<<(N + 3) / 4, 256, 0, stream>>>(t1, rowp, colv, dinv, gcn2_b, t3, N);   // G2
  k_bn_stats<<<128, 256, 0, stream>>>(t3, bnB, N);
  k_bn_apply<<<(N * 64 + 255) / 256, 256, 0, stream>>>(t3, bnB, bn_gcn_g, bn_gcn_b, cat + 0, N, 192);

  // ---- SAGE branch ----
  k_sage_agg<<<(N + 1) / 2, 256, 0, stream>>>(x, rowp, colv, sdinv, bufA, N, 128);   // aggX
  gemm(x, sage1_wr, nullptr, nullptr, t1, N, 128, 64, 0, stream);           // T1 = x@wr
  gemm(bufA, sage1_wl, sage1_bl, t1, t2, N, 128, 64, 1, stream);            // S1 = relu(agg@wl + bl + T1)
  k_sage_agg<<<(N + 3) / 4, 256, 0, stream>>>(t2, rowp, colv, sdinv, bufA, N, 64);   // aggS
  gemm(t2, sage2_wr, nullptr, nullptr, t1, N, 64, 64, 0, stream);           // T2 = S1@wr
  gemm(bufA, sage2_wl, sage2_bl, t1, t3, N, 64, 64, 1, stream);             // S2
  k_bn_stats<<<128, 256, 0, stream>>>(t3, bnC, N);
  k_bn_apply<<<(N * 64 + 255) / 256, 256, 0, stream>>>(t3, bnC, bn_sage_g, bn_sage_b, cat + 128, N, 192);

  // ---- FC head ----
  gemm(cat, fc1_w, fc1_b, nullptr, t1, N, 192, 64, 1, stream);              // F1
  k_fc2<<<(N + 3) / 4, 256, 0, stream>>>(t1, fc2_w, fc2_b, out, N);
}

// Round 3
// 984.662 us; speedup vs baseline: 1.2723x; 1.0014x over previous
//
#include <hip/hip_runtime.h>
#include <math.h>

#define NEG_SLOPE 0.2f
#define BN_EPS 1e-5f

typedef short short8 __attribute__((ext_vector_type(8)));
typedef float floatx16 __attribute__((ext_vector_type(16)));

__device__ __forceinline__ float d_leaky(float x){ return x > 0.f ? x : NEG_SLOPE * x; }
__device__ __forceinline__ float d_elu(float x){ return x > 0.f ? x : expm1f(x); }

__device__ __forceinline__ unsigned short f2bf_rne(float f){
  unsigned int u = __float_as_uint(f);
  unsigned int r = (u + 0x7fffu + ((u >> 16) & 1u)) >> 16;
  return (unsigned short)r;
}
__device__ __forceinline__ float bf2f(unsigned short h){ return __uint_as_float((unsigned int)h << 16); }

__device__ __forceinline__ float wave_sum(float v){
  #pragma unroll
  for (int off = 32; off > 0; off >>= 1) v += __shfl_xor(v, off, 64);
  return v;
}

// ---------------- CSR build ----------------
__global__ void k_count(const int* __restrict__ dst, int* __restrict__ deg, int E){
  int e = blockIdx.x * blockDim.x + threadIdx.x;
  if (e < E) atomicAdd(&deg[dst[e]], 1);
}

__global__ __launch_bounds__(1024) void k_scan(const int* __restrict__ deg, int* __restrict__ rowp,
                                               float* __restrict__ dinv, float* __restrict__ sdinv, int n){
  __shared__ int tmp[1024];
  __shared__ int carry_s;
  int t = threadIdx.x;
  if (t == 0) carry_s = 0;
  __syncthreads();
  for (int base = 0; base < n; base += 1024){
    int i = base + t;
    int v = (i < n) ? deg[i] : 0;
    tmp[t] = v;
    __syncthreads();
    for (int off = 1; off < 1024; off <<= 1){
      int u = (t >= off) ? tmp[t - off] : 0;
      __syncthreads();
      tmp[t] += u;
      __syncthreads();
    }
    int incl = tmp[t];
    int carry = carry_s;
    if (i < n){
      rowp[i] = carry + incl - v;
      dinv[i] = rsqrtf((float)(v + 1));
      sdinv[i] = 1.0f / fmaxf((float)v, 1.0f);
    }
    __syncthreads();
    if (t == 1023) carry_s = carry + incl;
    __syncthreads();
  }
  if (t == 0) rowp[n] = carry_s;
}

__global__ void k_scatter(const int* __restrict__ src, const int* __restrict__ dst,
                          const int* __restrict__ rowp, int* __restrict__ fill,
                          int* __restrict__ colv, int* __restrict__ dstv, int E){
  int e = blockIdx.x * blockDim.x + threadIdx.x;
  if (e < E){
    int d = dst[e];
    int pos = rowp[d] + atomicAdd(&fill[d], 1);
    colv[pos] = src[e];
    dstv[pos] = d;
  }
}

// ---------------- split fp32 -> bf16 hi/lo ----------------
__global__ void k_asplit(const float* __restrict__ a, unsigned short* __restrict__ h,
                         unsigned short* __restrict__ l, int total){
  int i = blockIdx.x * blockDim.x + threadIdx.x;
  if (i < total){
    float v = a[i];
    unsigned short hh = f2bf_rne(v);
    h[i] = hh;
    l[i] = f2bf_rne(v - bf2f(hh));
  }
}

// ---------------- weight transpose + split: W[K][Nc] -> Wt_hi/lo[Nc][K] ----------------
struct WDesc { const float* w; unsigned short* th; unsigned short* tl; int K; int Nc; };
struct WPack { WDesc d[9]; };
__global__ void k_wsplit(WPack p){
  WDesc w = p.d[blockIdx.y];
  int total = w.K * w.Nc;
  for (int i = blockIdx.x * blockDim.x + threadIdx.x; i < total; i += gridDim.x * blockDim.x){
    int k = i / w.Nc, n = i % w.Nc;
    float v = w.w[i];
    unsigned short h = f2bf_rne(v);
    w.th[(size_t)n * w.K + k] = h;
    w.tl[(size_t)n * w.K + k] = f2bf_rne(v - bf2f(h));
  }
}

// ---------------- MFMA bf16x3 GEMM ----------------
// C[M x Nc] = act( A @ W + bias + res ),  A from split (Ah+Al), W from transposed split.
// A ~= Ah + Al captures fp32 to ~2^-18 rel; product uses AhBh + AhBl + AlBh.
// Block: 256 thr = 4 waves; tile 128 rows x 64 cols; wave = 32 rows x 2 col-tiles(32).
__global__ __launch_bounds__(256) void k_gemm_mfma(
    const unsigned short* __restrict__ Ah, const unsigned short* __restrict__ Al,
    const unsigned short* __restrict__ Bh, const unsigned short* __restrict__ Bl,
    const float* __restrict__ bias, const float* __restrict__ res,
    float* __restrict__ Cf, unsigned short* __restrict__ Ch, unsigned short* __restrict__ Cl,
    int M, int K, int Nc, int act)
{
  int wave = threadIdx.x >> 6, lane = threadIdx.x & 63;
  int m0 = blockIdx.x * 128 + wave * 32;
  int n0 = blockIdx.y * 64;
  int lr = lane & 31;
  int ko8 = (lane >> 5) * 8;
  floatx16 acc0 = {0,0,0,0,0,0,0,0,0,0,0,0,0,0,0,0};
  floatx16 acc1 = {0,0,0,0,0,0,0,0,0,0,0,0,0,0,0,0};
  int arow = m0 + lr; if (arow >= M) arow = M - 1;
  const unsigned short* ap_h = Ah + (size_t)arow * K + ko8;
  const unsigned short* ap_l = Al + (size_t)arow * K + ko8;
  const unsigned short* bp_h0 = Bh + (size_t)(n0 + lr) * K + ko8;
  const unsigned short* bp_l0 = Bl + (size_t)(n0 + lr) * K + ko8;
  const unsigned short* bp_h1 = bp_h0 + (size_t)32 * K;
  const unsigned short* bp_l1 = bp_l0 + (size_t)32 * K;
  for (int k0 = 0; k0 < K; k0 += 16){
    short8 a_h  = *(const short8*)(ap_h + k0);
    short8 a_l  = *(const short8*)(ap_l + k0);
    short8 b_h0 = *(const short8*)(bp_h0 + k0);
    short8 b_l0 = *(const short8*)(bp_l0 + k0);
    short8 b_h1 = *(const short8*)(bp_h1 + k0);
    short8 b_l1 = *(const short8*)(bp_l1 + k0);
    acc0 = __builtin_amdgcn_mfma_f32_32x32x16_bf16(a_l, b_h0, acc0, 0, 0, 0);
    acc0 = __builtin_amdgcn_mfma_f32_32x32x16_bf16(a_h, b_l0, acc0, 0, 0, 0);
    acc0 = __builtin_amdgcn_mfma_f32_32x32x16_bf16(a_h, b_h0, acc0, 0, 0, 0);
    acc1 = __builtin_amdgcn_mfma_f32_32x32x16_bf16(a_l, b_h1, acc1, 0, 0, 0);
    acc1 = __builtin_amdgcn_mfma_f32_32x32x16_bf16(a_h, b_l1, acc1, 0, 0, 0);
    acc1 = __builtin_amdgcn_mfma_f32_32x32x16_bf16(a_h, b_h1, acc1, 0, 0, 0);
  }
  int col0 = n0 + lr, col1 = col0 + 32;
  float bias0 = bias ? bias[col0] : 0.f;
  float bias1 = bias ? bias[col1] : 0.f;
  int rbase = m0 + 4 * (lane >> 5);
  #pragma unroll
  for (int reg = 0; reg < 16; reg++){
    int row = rbase + (reg & 3) + 8 * (reg >> 2);
    if (row >= M) continue;
    float v0 = acc0[reg] + bias0;
    float v1 = acc1[reg] + bias1;
    if (res){
      v0 += res[(size_t)row * Nc + col0];
      v1 += res[(size_t)row * Nc + col1];
    }
    if (act){ v0 = fmaxf(v0, 0.f); v1 = fmaxf(v1, 0.f); }
    if (Cf){
      Cf[(size_t)row * Nc + col0] = v0;
      Cf[(size_t)row * Nc + col1] = v1;
    }
    if (Ch){
      unsigned short h0 = f2bf_rne(v0), h1 = f2bf_rne(v1);
      Ch[(size_t)row * Nc + col0] = h0;
      Ch[(size_t)row * Nc + col1] = h1;
      Cl[(size_t)row * Nc + col0] = f2bf_rne(v0 - bf2f(h0));
      Cl[(size_t)row * Nc + col1] = f2bf_rne(v1 - bf2f(h1));
    }
  }
}

// ---------------- GAT attention coefficients per node ----------------
__global__ void k_gat_attn(const float* __restrict__ h, const float* __restrict__ asrc,
                           const float* __restrict__ adst, float* __restrict__ a_s,
                           float* __restrict__ a_d, int n, int heads){
  int wave = threadIdx.x >> 6;
  int lane = threadIdx.x & 63;
  int node, head;
  if (heads == 4){ node = blockIdx.x; head = wave; }
  else { node = blockIdx.x * 4 + wave; head = 0; }
  if (node >= n) return;
  int HC = heads << 6;
  float v = h[(size_t)node * HC + (head << 6) + lane];
  float s = wave_sum(v * asrc[(head << 6) + lane]);
  float d = wave_sum(v * adst[(head << 6) + lane]);
  if (lane == 0){
    a_s[node * heads + head] = s;
    a_d[node * heads + head] = d;
  }
}

// ---------------- per-edge GAT softmax numerators (edge-parallel, coalesced) ----------------
__global__ void k_edge_w(const int* __restrict__ colv, const int* __restrict__ dstv,
                         const float* __restrict__ a_s, const float* __restrict__ a_d,
                         float* __restrict__ w, int E, int heads){
  int i = blockIdx.x * blockDim.x + threadIdx.x;
  if (i >= E) return;
  int s = colv[i], d = dstv[i];
  for (int h = 0; h < heads; h++)
    w[(size_t)i * heads + h] = __expf(d_leaky(a_s[s * heads + h] + a_d[d * heads + h]));
}

// ---------------- GAT aggregation, heads=4 -> split bf16 out ----------------
__global__ __launch_bounds__(256) void k_gat_agg4(
    const float* __restrict__ h, const int* __restrict__ rowp,
    const int* __restrict__ colv, const float* __restrict__ w4,
    const float* __restrict__ a_s, const float* __restrict__ a_d,
    const float* __restrict__ bias,
    unsigned short* __restrict__ outh, unsigned short* __restrict__ outl, int n){
  int node = blockIdx.x;
  int head = threadIdx.x >> 6;
  int c = threadIdx.x & 63;
  int hc = (head << 6) + c;
  int b = rowp[node], e = rowp[node + 1];
  float denom = __expf(d_leaky(a_s[node * 4 + head] + a_d[node * 4 + head]));
  float acc = denom * h[(size_t)node * 256 + hc];
  int i = b;
  for (; i + 4 <= e; i += 4){
    int s0 = colv[i+0], s1 = colv[i+1], s2 = colv[i+2], s3 = colv[i+3];
    float w0 = w4[(size_t)(i+0) * 4 + head];
    float w1 = w4[(size_t)(i+1) * 4 + head];
    float w2 = w4[(size_t)(i+2) * 4 + head];
    float w3 = w4[(size_t)(i+3) * 4 + head];
    float h0 = h[(size_t)s0 * 256 + hc];
    float h1 = h[(size_t)s1 * 256 + hc];
    float h2 = h[(size_t)s2 * 256 + hc];
    float h3 = h[(size_t)s3 * 256 + hc];
    denom += (w0 + w1) + (w2 + w3);
    acc += w0 * h0 + w1 * h1 + w2 * h2 + w3 * h3;
  }
  for (; i < e; i++){
    int s = colv[i];
    float w = w4[(size_t)i * 4 + head];
    denom += w;
    acc += w * h[(size_t)s * 256 + hc];
  }
  float v = d_elu(acc / (denom + 1e-16f) + bias[hc]);
  unsigned short hh = f2bf_rne(v);
  outh[(size_t)node * 256 + hc] = hh;
  outl[(size_t)node * 256 + hc] = f2bf_rne(v - bf2f(hh));
}

// ---------------- GAT aggregation, heads=1, fp32 out ----------------
__global__ __launch_bounds__(256) void k_gat_agg1(
    const float* __restrict__ h, const int* __restrict__ rowp,
    const int* __restrict__ colv, const float* __restrict__ w1,
    const float* __restrict__ a_s, const float* __restrict__ a_d,
    const float* __restrict__ bias, float* __restrict__ out, int n){
  int node = blockIdx.x * 4 + (threadIdx.x >> 6);
  int c = threadIdx.x & 63;
  if (node >= n) return;
  int b = rowp[node], e = rowp[node + 1];
  float denom = __expf(d_leaky(a_s[node] + a_d[node]));
  float acc = denom * h[(size_t)node * 64 + c];
  int i = b;
  for (; i + 4 <= e; i += 4){
    int s0 = colv[i+0], s1 = colv[i+1], s2 = colv[i+2], s3 = colv[i+3];
    float w0 = w1[i+0], w1_ = w1[i+1], w2 = w1[i+2], w3 = w1[i+3];
    float h0 = h[(size_t)s0 * 64 + c];
    float h1 = h[(size_t)s1 * 64 + c];
    float h2 = h[(size_t)s2 * 64 + c];
    float h3 = h[(size_t)s3 * 64 + c];
    denom += (w0 + w1_) + (w2 + w3);
    acc += w0 * h0 + w1_ * h1 + w2 * h2 + w3 * h3;
  }
  for (; i < e; i++){
    int s = colv[i];
    float w = w1[i];
    denom += w;
    acc += w * h[(size_t)s * 64 + c];
  }
  out[(size_t)node * 64 + c] = d_elu(acc / (denom + 1e-16f) + bias[c]);
}

// ---------------- GCN aggregation (F=64): fp32 out or split out ----------------
__global__ __launch_bounds__(256) void k_gcn_agg(
    const float* __restrict__ h, const int* __restrict__ rowp,
    const int* __restrict__ colv, const float* __restrict__ dinv,
    const float* __restrict__ bias, float* __restrict__ outf,
    unsigned short* __restrict__ outh, unsigned short* __restrict__ outl, int n){
  int node = blockIdx.x * 4 + (threadIdx.x >> 6);
  int c = threadIdx.x & 63;
  if (node >= n) return;
  float di = dinv[node];
  float acc = di * h[(size_t)node * 64 + c];
  int b = rowp[node], e = rowp[node + 1];
  int i = b;
  for (; i + 4 <= e; i += 4){
    int s0 = colv[i+0], s1 = colv[i+1], s2 = colv[i+2], s3 = colv[i+3];
    float w0 = dinv[s0], w1 = dinv[s1], w2 = dinv[s2], w3 = dinv[s3];
    float h0 = h[(size_t)s0 * 64 + c];
    float h1 = h[(size_t)s1 * 64 + c];
    float h2 = h[(size_t)s2 * 64 + c];
    float h3 = h[(size_t)s3 * 64 + c];
    acc += w0 * h0 + w1 * h1 + w2 * h2 + w3 * h3;
  }
  for (; i < e; i++){
    int s = colv[i];
    acc += dinv[s] * h[(size_t)s * 64 + c];
  }
  float v = fmaxf(di * acc + bias[c], 0.f);
  if (outf) outf[(size_t)node * 64 + c] = v;
  if (outh){
    unsigned short hh = f2bf_rne(v);
    outh[(size_t)node * 64 + c] = hh;
    outl[(size_t)node * 64 + c] = f2bf_rne(v - bf2f(hh));
  }
}

// ---------------- SAGE mean aggregation -> split bf16 out ----------------
__global__ __launch_bounds__(256) void k_sage_agg(
    const float* __restrict__ xin, const int* __restrict__ rowp,
    const int* __restrict__ colv, const float* __restrict__ sdinv,
    unsigned short* __restrict__ outh, unsigned short* __restrict__ outl, int n, int F){
  int npb = 256 / F;
  int node = blockIdx.x * npb + (int)threadIdx.x / F;
  int c = (int)threadIdx.x % F;
  if (node >= n) return;
  float acc = 0.f;
  int b = rowp[node], e = rowp[node + 1];
  int i = b;
  for (; i + 4 <= e; i += 4){
    int s0 = colv[i+0], s1 = colv[i+1], s2 = colv[i+2], s3 = colv[i+3];
    float h0 = xin[(size_t)s0 * F + c];
    float h1 = xin[(size_t)s1 * F + c];
    float h2 = xin[(size_t)s2 * F + c];
    float h3 = xin[(size_t)s3 * F + c];
    acc += (h0 + h1) + (h2 + h3);
  }
  for (; i < e; i++) acc += xin[(size_t)colv[i] * F + c];
  float v = acc * sdinv[node];
  unsigned short hh = f2bf_rne(v);
  outh[(size_t)node * F + c] = hh;
  outl[(size_t)node * F + c] = f2bf_rne(v - bf2f(hh));
}

// ---------------- BatchNorm ----------------
__global__ void k_bn_stats(const float* __restrict__ x, float* __restrict__ sums, int n){
  int c = threadIdx.x & 63;
  int rl = threadIdx.x >> 6;
  float s = 0.f, q = 0.f;
  for (int r = blockIdx.x * 4 + rl; r < n; r += gridDim.x * 4){
    float v = x[(size_t)r * 64 + c];
    s += v; q += v * v;
  }
  __shared__ float ls[4][64], lq[4][64];
  ls[rl][c] = s; lq[rl][c] = q;
  __syncthreads();
  if (rl == 0){
    s = ls[0][c] + ls[1][c] + ls[2][c] + ls[3][c];
    q = lq[0][c] + lq[1][c] + lq[2][c] + lq[3][c];
    atomicAdd(&sums[c], s);
    atomicAdd(&sums[64 + c], q);
  }
}

// BN apply -> split bf16 into strided concat buffers
__global__ void k_bn_apply_split(const float* __restrict__ x, const float* __restrict__ sums,
                                 const float* __restrict__ g, const float* __restrict__ b,
                                 unsigned short* __restrict__ outh, unsigned short* __restrict__ outl,
                                 int n, int ldout, int coloff){
  int idx = blockIdx.x * blockDim.x + threadIdx.x;
  if (idx >= n * 64) return;
  int r = idx >> 6, c = idx & 63;
  float m = sums[c] / (float)n;
  float var = sums[64 + c] / (float)n - m * m;
  float v = (x[idx] - m) * rsqrtf(var + BN_EPS) * g[c] + b[c];
  unsigned short hh = f2bf_rne(v);
  outh[(size_t)r * ldout + coloff + c] = hh;
  outl[(size_t)r * ldout + coloff + c] = f2bf_rne(v - bf2f(hh));
}

// ---------------- final tiny FC (64 -> 2) ----------------
__global__ void k_fc2(const float* __restrict__ h, const float* __restrict__ w,
                      const float* __restrict__ b, float* __restrict__ out, int n){
  int node = blockIdx.x * 4 + (threadIdx.x >> 6);
  int lane = threadIdx.x & 63;
  if (node >= n) return;
  float v = h[(size_t)node * 64 + lane];
  float p0 = wave_sum(v * w[lane * 2 + 0]);
  float p1 = wave_sum(v * w[lane * 2 + 1]);
  if (lane == 0){
    out[node * 2 + 0] = p0 + b[0];
    out[node * 2 + 1] = p1 + b[1];
  }
}

extern "C" void kernel_launch(void* const* d_in, const int* in_sizes, int n_in,
                              void* d_out, int out_size, void* d_ws, size_t ws_size,
                              hipStream_t stream){
  (void)n_in; (void)out_size; (void)ws_size;
  const float* x        = (const float*)d_in[0];
  const int*   ei       = (const int*)  d_in[1];
  const float* gcn1_w   = (const float*)d_in[2];
  const float* gcn1_b   = (const float*)d_in[3];
  const float* gcn2_w   = (const float*)d_in[4];
  const float* gcn2_b   = (const float*)d_in[5];
  const float* gat1_w   = (const float*)d_in[6];
  const float* gat1_as  = (const float*)d_in[7];
  const float* gat1_ad  = (const float*)d_in[8];
  const float* gat1_b   = (const float*)d_in[9];
  const float* gat2_w   = (const float*)d_in[10];
  const float* gat2_as  = (const float*)d_in[11];
  const float* gat2_ad  = (const float*)d_in[12];
  const float* gat2_b   = (const float*)d_in[13];
  const float* sage1_wl = (const float*)d_in[14];
  const float* sage1_bl = (const float*)d_in[15];
  const float* sage1_wr = (const float*)d_in[16];
  const float* sage2_wl = (const float*)d_in[17];
  const float* sage2_bl = (const float*)d_in[18];
  const float* sage2_wr = (const float*)d_in[19];
  const float* bn_gcn_g = (const float*)d_in[20];
  const float* bn_gcn_b = (const float*)d_in[21];
  const float* bn_gat_g = (const float*)d_in[22];
  const float* bn_gat_b = (const float*)d_in[23];
  const float* bn_sage_g= (const float*)d_in[24];
  const float* bn_sage_b= (const float*)d_in[25];
  const float* fc1_w    = (const float*)d_in[26];
  const float* fc1_b    = (const float*)d_in[27];
  const float* fc2_w    = (const float*)d_in[28];
  const float* fc2_b    = (const float*)d_in[29];
  float* out = (float*)d_out;

  const int N = in_sizes[0] / 128;
  const int E = in_sizes[1] / 2;
  const int* src = ei;
  const int* dst = ei + E;

  char* ws = (char*)d_ws;
  size_t off = 0;
  auto alloc = [&](size_t bytes) -> void* {
    void* p = ws + off;
    off = (off + bytes + 255) & ~(size_t)255;
    return p;
  };
  int*   deg   = (int*)  alloc((size_t)N * 4);
  int*   rowp  = (int*)  alloc((size_t)(N + 1) * 4);
  int*   fill  = (int*)  alloc((size_t)N * 4);
  int*   colv  = (int*)  alloc((size_t)E * 4);
  int*   dstv  = (int*)  alloc((size_t)E * 4);
  float* dinv  = (float*)alloc((size_t)N * 4);
  float* sdinv = (float*)alloc((size_t)N * 4);
  float* as1   = (float*)alloc((size_t)N * 4 * 4);
  float* ad1   = (float*)alloc((size_t)N * 4 * 4);
  float* as2   = (float*)alloc((size_t)N * 4);
  float* ad2   = (float*)alloc((size_t)N * 4);
  float* w4    = (float*)alloc((size_t)E * 4 * 4);
  float* w1    = (float*)alloc((size_t)E * 4);
  float* bnA   = (float*)alloc(128 * 4);
  float* bnB   = (float*)alloc(128 * 4);
  float* bnC   = (float*)alloc(128 * 4);
  // x split
  unsigned short* xh = (unsigned short*)alloc((size_t)N * 128 * 2);
  unsigned short* xl = (unsigned short*)alloc((size_t)N * 128 * 2);
  // big fp32 buffer (GAT1 out), later carved for split temps
  float* bufA = (float*)alloc((size_t)N * 256 * 4);            // 51.2 MB
  // GAT1 split out; later reused for concat split buffers
  unsigned short* bh = (unsigned short*)alloc((size_t)N * 256 * 2);  // 25.6 MB
  unsigned short* bl = (unsigned short*)alloc((size_t)N * 256 * 2);  // 25.6 MB
  float* t1 = (float*)alloc((size_t)N * 64 * 4);
  float* t2 = (float*)alloc((size_t)N * 64 * 4);
  float* t3 = (float*)alloc((size_t)N * 64 * 4);
  // weight split pool
  auto walloc = [&](int K, int Nc, unsigned short** th, unsigned short** tl){
    *th = (unsigned short*)alloc((size_t)K * Nc * 2);
    *tl = (unsigned short*)alloc((size_t)K * Nc * 2);
  };
  unsigned short *gcn1h,*gcn1l,*gcn2h,*gcn2l,*gat1h,*gat1l,*gat2h,*gat2l;
  unsigned short *s1wlh,*s1wll,*s1wrh,*s1wrl,*s2wlh,*s2wll,*s2wrh,*s2wrl,*fc1h,*fc1l;
  walloc(128, 64, &gcn1h, &gcn1l);
  walloc(64, 64, &gcn2h, &gcn2l);
  walloc(128, 256, &gat1h, &gat1l);
  walloc(256, 64, &gat2h, &gat2l);
  walloc(128, 64, &s1wlh, &s1wll);
  walloc(128, 64, &s1wrh, &s1wrl);
  walloc(64, 64, &s2wlh, &s2wll);
  walloc(64, 64, &s2wrh, &s2wrl);
  walloc(192, 64, &fc1h, &fc1l);

  // carve bufA (dead after GAT2 GEMM) for split temporaries
  const size_t SEG = (size_t)N * 64 * 2;  // 6.4 MB, 256-aligned for N=50000
  char* pool = (char*)bufA;
  unsigned short* g2h   = (unsigned short*)(pool + 0 * SEG);
  unsigned short* g2l   = (unsigned short*)(pool + 1 * SEG);
  unsigned short* aggXh = (unsigned short*)(pool + 2 * SEG);  // N x 128
  unsigned short* aggXl = (unsigned short*)(pool + 4 * SEG);
  unsigned short* s1h   = (unsigned short*)(pool + 6 * SEG);
  unsigned short* s1l   = (unsigned short*)(pool + 7 * SEG);
  unsigned short* aggSh = (unsigned short*)(pool + 0 * SEG);  // reuse after GCN2
  unsigned short* aggSl = (unsigned short*)(pool + 1 * SEG);
  // concat split buffers alias bh/bl (dead after GAT2 GEMM); N*192*2 = 19.2MB <= 25.6MB
  unsigned short* cath = bh;
  unsigned short* catl = bl;

  hipMemsetAsync(deg, 0, (size_t)N * 4, stream);
  hipMemsetAsync(fill, 0, (size_t)N * 4, stream);
  hipMemsetAsync(bnA, 0, 128 * 4, stream);
  hipMemsetAsync(bnB, 0, 128 * 4, stream);
  hipMemsetAsync(bnC, 0, 128 * 4, stream);

  // CSR by destination
  k_count  <<<(E + 255) / 256, 256, 0, stream>>>(dst, deg, E);
  k_scan   <<<1, 1024, 0, stream>>>(deg, rowp, dinv, sdinv, N);
  k_scatter<<<(E + 255) / 256, 256, 0, stream>>>(src, dst, rowp, fill, colv, dstv, E);

  // weight splits (all 9 in one launch) + x split
  {
    WPack p;
    p.d[0] = {gcn1_w, gcn1h, gcn1l, 128, 64};
    p.d[1] = {gcn2_w, gcn2h, gcn2l, 64, 64};
    p.d[2] = {gat1_w, gat1h, gat1l, 128, 256};
    p.d[3] = {gat2_w, gat2h, gat2l, 256, 64};
    p.d[4] = {sage1_wl, s1wlh, s1wll, 128, 64};
    p.d[5] = {sage1_wr, s1wrh, s1wrl, 128, 64};
    p.d[6] = {sage2_wl, s2wlh, s2wll, 64, 64};
    p.d[7] = {sage2_wr, s2wrh, s2wrl, 64, 64};
    p.d[8] = {fc1_w, fc1h, fc1l, 192, 64};
    dim3 g(32, 9);
    k_wsplit<<<g, 256, 0, stream>>>(p);
  }
  k_asplit<<<(N * 128 + 255) / 256, 256, 0, stream>>>(x, xh, xl, N * 128);

  auto gemm = [&](const unsigned short* Ah, const unsigned short* Al,
                  const unsigned short* Bh, const unsigned short* Bl,
                  const float* bias, const float* res,
                  float* Cf, unsigned short* Ch, unsigned short* Cl,
                  int K, int Nc, int act){
    dim3 g((N + 127) / 128, Nc / 64);
    k_gemm_mfma<<<g, 256, 0, stream>>>(Ah, Al, Bh, Bl, bias, res, Cf, Ch, Cl, N, K, Nc, act);
  };

  // ---- GAT branch ----
  gemm(xh, xl, gat1h, gat1l, nullptr, nullptr, bufA, nullptr, nullptr, 128, 256, 0);  // HA1 fp32
  k_gat_attn<<<N, 256, 0, stream>>>(bufA, gat1_as, gat1_ad, as1, ad1, N, 4);
  k_edge_w<<<(E + 255) / 256, 256, 0, stream>>>(colv, dstv, as1, ad1, w4, E, 4);
  k_gat_agg4<<<N, 256, 0, stream>>>(bufA, rowp, colv, w4, as1, ad1, gat1_b, bh, bl, N);
  gemm(bh, bl, gat2h, gat2l, nullptr, nullptr, t1, nullptr, nullptr, 256, 64, 0);     // HA2 fp32
  k_gat_attn<<<(N + 3) / 4, 256, 0, stream>>>(t1, gat2_as, gat2_ad, as2, ad2, N, 1);
  k_edge_w<<<(E + 255) / 256, 256, 0, stream>>>(colv, dstv, as2, ad2, w1, E, 1);
  k_gat_agg1<<<(N + 3) / 4, 256, 0, stream>>>(t1, rowp, colv, w1, as2, ad2, gat2_b, t2, N);
  k_bn_stats<<<128, 256, 0, stream>>>(t2, bnA, N);
  k_bn_apply_split<<<(N * 64 + 255) / 256, 256, 0, stream>>>(t2, bnA, bn_gat_g, bn_gat_b, cath, catl, N, 192, 64);

  // ---- GCN branch ----
  gemm(xh, xl, gcn1h, gcn1l, nullptr, nullptr, t1, nullptr, nullptr, 128, 64, 0);     // H1
  k_gcn_agg<<<(N + 3) / 4, 256, 0, stream>>>(t1, rowp, colv, dinv, gcn1_b, nullptr, g2h, g2l, N);
  gemm(g2h, g2l, gcn2h, gcn2l, nullptr, nullptr, t1, nullptr, nullptr, 64, 64, 0);    // H2
  k_gcn_agg<<<(N + 3) / 4, 256, 0, stream>>>(t1, rowp, colv, dinv, gcn2_b, t3, nullptr, nullptr, N);
  k_bn_stats<<<128, 256, 0, stream>>>(t3, bnB, N);
  k_bn_apply_split<<<(N * 64 + 255) / 256, 256, 0, stream>>>(t3, bnB, bn_gcn_g, bn_gcn_b, cath, catl, N, 192, 0);

  // ---- SAGE branch ----
  k_sage_agg<<<(N + 1) / 2, 256, 0, stream>>>(x, rowp, colv, sdinv, aggXh, aggXl, N, 128);
  gemm(xh, xl, s1wrh, s1wrl, nullptr, nullptr, t1, nullptr, nullptr, 128, 64, 0);     // x@wr
  gemm(aggXh, aggXl, s1wlh, s1wll, sage1_bl, t1, t2, s1h, s1l, 128, 64, 1);           // S1 fp32+split
  k_sage_agg<<<(N + 3) / 4, 256, 0, stream>>>(t2, rowp, colv, sdinv, aggSh, aggSl, N, 64);
  gemm(s1h, s1l, s2wrh, s2wrl, nullptr, nullptr, t1, nullptr, nullptr, 64, 64, 0);    // S1@wr
  gemm(aggSh, aggSl, s2wlh, s2wll, sage2_bl, t1, t3, nullptr, nullptr, 64, 64, 1);    // S2
  k_bn_stats<<<128, 256, 0, stream>>>(t3, bnC, N);
  k_bn_apply_split<<<(N * 64 + 255) / 256, 256, 0, stream>>>(t3, bnC, bn_sage_g, bn_sage_b, cath, catl, N, 192, 128);

  // ---- FC head ----
  gemm(cath, catl, fc1h, fc1l, fc1_b, nullptr, t1, nullptr, nullptr, 192, 64, 1);     // F1
  k_fc2<<<(N + 3) / 4, 256, 0, stream>>>(t1, fc2_w, fc2_b, out, N);
}

// Round 4
// 838.153 us; speedup vs baseline: 1.4947x; 1.1748x over previous
//
#include <hip/hip_runtime.h>
#include <math.h>

#define NEG_SLOPE 0.2f
#define BN_EPS 1e-5f

typedef short short8 __attribute__((ext_vector_type(8)));
typedef float floatx16 __attribute__((ext_vector_type(16)));

__device__ __forceinline__ float d_leaky(float x){ return x > 0.f ? x : NEG_SLOPE * x; }
__device__ __forceinline__ float d_elu(float x){ return x > 0.f ? x : expm1f(x); }

__device__ __forceinline__ unsigned short f2bf_rne(float f){
  unsigned int u = __float_as_uint(f);
  unsigned int r = (u + 0x7fffu + ((u >> 16) & 1u)) >> 16;
  return (unsigned short)r;
}
__device__ __forceinline__ float bf2f(unsigned short h){ return __uint_as_float((unsigned int)h << 16); }
// unpack packed pair of bf16 (low ushort, high ushort) -> two floats
__device__ __forceinline__ float2 bf2x(unsigned int u){
  float2 r;
  r.x = __uint_as_float(u << 16);
  r.y = __uint_as_float(u & 0xffff0000u);
  return r;
}
__device__ __forceinline__ unsigned int packbf(float a, float b){
  return (unsigned int)f2bf_rne(a) | ((unsigned int)f2bf_rne(b) << 16);
}

__device__ __forceinline__ float wave_sum(float v){
  #pragma unroll
  for (int off = 32; off > 0; off >>= 1) v += __shfl_xor(v, off, 64);
  return v;
}
__device__ __forceinline__ int wave_scan_incl(int v, int lane){
  #pragma unroll
  for (int off = 1; off < 64; off <<= 1){
    int u = __shfl_up(v, off, 64);
    if (lane >= off) v += u;
  }
  return v;
}

// ---------------- CSR build ----------------
__global__ void k_count(const int* __restrict__ dst, int* __restrict__ deg, int E){
  int e = blockIdx.x * blockDim.x + threadIdx.x;
  if (e < E) atomicAdd(&deg[dst[e]], 1);
}

// 3-phase multi-block scan: each block handles 1024 elems (4/thread)
__global__ __launch_bounds__(256) void k_scan_a(const int* __restrict__ deg, int* __restrict__ bsum, int n){
  int t = threadIdx.x;
  int base = blockIdx.x * 1024 + t * 4;
  int d0=0,d1=0,d2=0,d3=0;
  if (base + 3 < n){ int4 v = *(const int4*)(deg + base); d0=v.x; d1=v.y; d2=v.z; d3=v.w; }
  else {
    if (base   < n) d0 = deg[base];
    if (base+1 < n) d1 = deg[base+1];
    if (base+2 < n) d2 = deg[base+2];
    if (base+3 < n) d3 = deg[base+3];
  }
  int s = d0+d1+d2+d3;
  __shared__ int wsm[4];
  int lane = t & 63, w = t >> 6;
  int incl = wave_scan_incl(s, lane);
  if (lane == 63) wsm[w] = incl;
  __syncthreads();
  if (t == 0) bsum[blockIdx.x] = wsm[0]+wsm[1]+wsm[2]+wsm[3];
}

__global__ void k_scan_b(int* __restrict__ bsum, int* __restrict__ rowp, int nb, int n){
  int t = threadIdx.x;  // 64 threads, nb <= 64
  int v = (t < nb) ? bsum[t] : 0;
  int incl = wave_scan_incl(v, t);
  if (t < nb) bsum[t] = incl - v;  // exclusive
  if (t == 63) rowp[n] = incl;     // grand total
}

__global__ __launch_bounds__(256) void k_scan_c(const int* __restrict__ deg, const int* __restrict__ bsum,
                                                int* __restrict__ rowp, float* __restrict__ dinv,
                                                float* __restrict__ sdinv, int n){
  int t = threadIdx.x;
  int base = blockIdx.x * 1024 + t * 4;
  int d0=0,d1=0,d2=0,d3=0;
  if (base + 3 < n){ int4 v = *(const int4*)(deg + base); d0=v.x; d1=v.y; d2=v.z; d3=v.w; }
  else {
    if (base   < n) d0 = deg[base];
    if (base+1 < n) d1 = deg[base+1];
    if (base+2 < n) d2 = deg[base+2];
    if (base+3 < n) d3 = deg[base+3];
  }
  int s = d0+d1+d2+d3;
  __shared__ int wsm[4];
  int lane = t & 63, w = t >> 6;
  int incl = wave_scan_incl(s, lane);
  if (lane == 63) wsm[w] = incl;
  __syncthreads();
  int woff = 0;
  #pragma unroll
  for (int j = 0; j < 4; j++) if (j < w) woff += wsm[j];
  int r = bsum[blockIdx.x] + woff + incl - s;
  int dd[4] = {d0,d1,d2,d3};
  #pragma unroll
  for (int j = 0; j < 4; j++){
    int i = base + j;
    if (i < n){
      rowp[i] = r;
      dinv[i] = rsqrtf((float)(dd[j] + 1));
      sdinv[i] = 1.0f / fmaxf((float)dd[j], 1.0f);
    }
    r += dd[j];
  }
}

__global__ void k_scatter(const int* __restrict__ src, const int* __restrict__ dst,
                          const int* __restrict__ rowp, int* __restrict__ fill,
                          int* __restrict__ colv, int* __restrict__ dstv, int E){
  int e = blockIdx.x * blockDim.x + threadIdx.x;
  if (e < E){
    int d = dst[e];
    int pos = rowp[d] + atomicAdd(&fill[d], 1);
    colv[pos] = src[e];
    dstv[pos] = d;
  }
}

// ---------------- split fp32 -> bf16 hi/lo ----------------
__global__ void k_asplit(const float* __restrict__ a, unsigned short* __restrict__ h,
                         unsigned short* __restrict__ l, int total){
  int i = blockIdx.x * blockDim.x + threadIdx.x;
  if (i < total){
    float v = a[i];
    unsigned short hh = f2bf_rne(v);
    h[i] = hh;
    l[i] = f2bf_rne(v - bf2f(hh));
  }
}

// ---------------- weight transpose + split: W[K][Nc] -> Wt_hi/lo[Nc][Kperm] ----------------
struct WDesc { const float* w; unsigned short* th; unsigned short* tl; int K; int Nc; int perm; };
struct WPack { WDesc d[9]; };
__global__ void k_wsplit(WPack p){
  WDesc w = p.d[blockIdx.y];
  int total = w.K * w.Nc;
  for (int i = blockIdx.x * blockDim.x + threadIdx.x; i < total; i += gridDim.x * blockDim.x){
    int k = i / w.Nc, n = i % w.Nc;
    int kd = w.perm ? ((k & 63) * 4 + (k >> 6)) : k;
    float v = w.w[i];
    unsigned short h = f2bf_rne(v);
    w.th[(size_t)n * w.K + kd] = h;
    w.tl[(size_t)n * w.K + kd] = f2bf_rne(v - bf2f(h));
  }
}

// ---------------- MFMA bf16x3 GEMM ----------------
// C = act(A@W + bias + res). A split hi/lo, W transposed split. ilv: head-interleaved bf16 out.
__global__ __launch_bounds__(256) void k_gemm_mfma(
    const unsigned short* __restrict__ Ah, const unsigned short* __restrict__ Al,
    const unsigned short* __restrict__ Bh, const unsigned short* __restrict__ Bl,
    const float* __restrict__ bias, const float* __restrict__ res,
    float* __restrict__ Cf, unsigned short* __restrict__ Ch, unsigned short* __restrict__ Cl,
    int M, int K, int Nc, int act, int ilv)
{
  int wave = threadIdx.x >> 6, lane = threadIdx.x & 63;
  int m0 = blockIdx.x * 128 + wave * 32;
  int n0 = blockIdx.y * 64;
  int lr = lane & 31;
  int ko8 = (lane >> 5) * 8;
  floatx16 acc0 = {0,0,0,0,0,0,0,0,0,0,0,0,0,0,0,0};
  floatx16 acc1 = {0,0,0,0,0,0,0,0,0,0,0,0,0,0,0,0};
  int arow = m0 + lr; if (arow >= M) arow = M - 1;
  const unsigned short* ap_h = Ah + (size_t)arow * K + ko8;
  const unsigned short* ap_l = Al + (size_t)arow * K + ko8;
  const unsigned short* bp_h0 = Bh + (size_t)(n0 + lr) * K + ko8;
  const unsigned short* bp_l0 = Bl + (size_t)(n0 + lr) * K + ko8;
  const unsigned short* bp_h1 = bp_h0 + (size_t)32 * K;
  const unsigned short* bp_l1 = bp_l0 + (size_t)32 * K;
  for (int k0 = 0; k0 < K; k0 += 16){
    short8 a_h  = *(const short8*)(ap_h + k0);
    short8 a_l  = *(const short8*)(ap_l + k0);
    short8 b_h0 = *(const short8*)(bp_h0 + k0);
    short8 b_l0 = *(const short8*)(bp_l0 + k0);
    short8 b_h1 = *(const short8*)(bp_h1 + k0);
    short8 b_l1 = *(const short8*)(bp_l1 + k0);
    acc0 = __builtin_amdgcn_mfma_f32_32x32x16_bf16(a_l, b_h0, acc0, 0, 0, 0);
    acc0 = __builtin_amdgcn_mfma_f32_32x32x16_bf16(a_h, b_l0, acc0, 0, 0, 0);
    acc0 = __builtin_amdgcn_mfma_f32_32x32x16_bf16(a_h, b_h0, acc0, 0, 0, 0);
    acc1 = __builtin_amdgcn_mfma_f32_32x32x16_bf16(a_l, b_h1, acc1, 0, 0, 0);
    acc1 = __builtin_amdgcn_mfma_f32_32x32x16_bf16(a_h, b_l1, acc1, 0, 0, 0);
    acc1 = __builtin_amdgcn_mfma_f32_32x32x16_bf16(a_h, b_h1, acc1, 0, 0, 0);
  }
  int col0 = n0 + lr, col1 = col0 + 32;
  float bias0 = bias ? bias[col0] : 0.f;
  float bias1 = bias ? bias[col1] : 0.f;
  int rbase = m0 + 4 * (lane >> 5);
  int head = col0 >> 6;  // same for col1 (col1 = col0+32, col0%64 < 32)
  #pragma unroll
  for (int reg = 0; reg < 16; reg++){
    int row = rbase + (reg & 3) + 8 * (reg >> 2);
    if (row >= M) continue;
    float v0 = acc0[reg] + bias0;
    float v1 = acc1[reg] + bias1;
    if (res){
      v0 += res[(size_t)row * Nc + col0];
      v1 += res[(size_t)row * Nc + col1];
    }
    if (act){ v0 = fmaxf(v0, 0.f); v1 = fmaxf(v1, 0.f); }
    if (Cf){
      Cf[(size_t)row * Nc + col0] = v0;
      Cf[(size_t)row * Nc + col1] = v1;
    }
    if (Ch){
      size_t i0, i1;
      if (ilv){
        i0 = (size_t)row * Nc + (size_t)(col0 & 63) * 4 + head;
        i1 = (size_t)row * Nc + (size_t)(col1 & 63) * 4 + head;
      } else {
        i0 = (size_t)row * Nc + col0;
        i1 = (size_t)row * Nc + col1;
      }
      unsigned short h0 = f2bf_rne(v0), h1 = f2bf_rne(v1);
      Ch[i0] = h0; Ch[i1] = h1;
      if (Cl){
        Cl[i0] = f2bf_rne(v0 - bf2f(h0));
        Cl[i1] = f2bf_rne(v1 - bf2f(h1));
      }
    }
  }
}

// ---------------- GAT1 attention coeffs (interleaved bf16 h), wave per node ----------------
__global__ __launch_bounds__(256) void k_gat_attn4(
    const unsigned short* __restrict__ h, const float* __restrict__ asrc,
    const float* __restrict__ adst, float* __restrict__ a_s, float* __restrict__ a_d, int n){
  int node = blockIdx.x * 4 + (threadIdx.x >> 6);
  int c = threadIdx.x & 63;
  if (node >= n) return;
  uint2 u = *(const uint2*)(h + (size_t)node * 256 + c * 4);
  float2 p0 = bf2x(u.x), p1 = bf2x(u.y);
  float s0 = wave_sum(p0.x * asrc[c]);
  float s1 = wave_sum(p0.y * asrc[64 + c]);
  float s2 = wave_sum(p1.x * asrc[128 + c]);
  float s3 = wave_sum(p1.y * asrc[192 + c]);
  float d0 = wave_sum(p0.x * adst[c]);
  float d1 = wave_sum(p0.y * adst[64 + c]);
  float d2 = wave_sum(p1.x * adst[128 + c]);
  float d3 = wave_sum(p1.y * adst[192 + c]);
  if (c == 0){
    *(float4*)(a_s + (size_t)node * 4) = make_float4(s0, s1, s2, s3);
    *(float4*)(a_d + (size_t)node * 4) = make_float4(d0, d1, d2, d3);
  }
}

// ---------------- GAT2 attention coeffs (bf16 h), wave per node ----------------
__global__ __launch_bounds__(256) void k_gat_attn1(
    const unsigned short* __restrict__ h, const float* __restrict__ asrc,
    const float* __restrict__ adst, float* __restrict__ a_s, float* __restrict__ a_d, int n){
  int node = blockIdx.x * 4 + (threadIdx.x >> 6);
  int c = threadIdx.x & 63;
  if (node >= n) return;
  float v = bf2f(h[(size_t)node * 64 + c]);
  float s = wave_sum(v * asrc[c]);
  float d = wave_sum(v * adst[c]);
  if (c == 0){ a_s[node] = s; a_d[node] = d; }
}

// ---------------- per-edge softmax numerators ----------------
__global__ void k_edge_w4(const int* __restrict__ colv, const int* __restrict__ dstv,
                          const float* __restrict__ a_s, const float* __restrict__ a_d,
                          float* __restrict__ w4, int E){
  int i = blockIdx.x * blockDim.x + threadIdx.x;
  if (i >= E) return;
  float4 s4 = *(const float4*)(a_s + (size_t)colv[i] * 4);
  float4 d4 = *(const float4*)(a_d + (size_t)dstv[i] * 4);
  float4 w;
  w.x = __expf(d_leaky(s4.x + d4.x));
  w.y = __expf(d_leaky(s4.y + d4.y));
  w.z = __expf(d_leaky(s4.z + d4.z));
  w.w = __expf(d_leaky(s4.w + d4.w));
  *(float4*)(w4 + (size_t)i * 4) = w;
}

__global__ void k_edge_w1(const int* __restrict__ colv, const int* __restrict__ dstv,
                          const float* __restrict__ a_s, const float* __restrict__ a_d,
                          float* __restrict__ w1, int E){
  int i = blockIdx.x * blockDim.x + threadIdx.x;
  if (i >= E) return;
  w1[i] = __expf(d_leaky(a_s[colv[i]] + a_d[dstv[i]]));
}

// ---------------- GAT1 aggregation: interleaved bf16, wave/node, all 4 heads ----------------
__global__ __launch_bounds__(256) void k_gat_agg4(
    const unsigned short* __restrict__ h, const int* __restrict__ rowp,
    const int* __restrict__ colv, const float* __restrict__ w4,
    const float* __restrict__ a_s, const float* __restrict__ a_d,
    const float* __restrict__ bias,
    unsigned short* __restrict__ outh, unsigned short* __restrict__ outl, int n){
  int node = blockIdx.x * 4 + (threadIdx.x >> 6);
  int c = threadIdx.x & 63;
  if (node >= n) return;
  float4 asn = *(const float4*)(a_s + (size_t)node * 4);
  float4 adn = *(const float4*)(a_d + (size_t)node * 4);
  float ws0 = __expf(d_leaky(asn.x + adn.x));
  float ws1 = __expf(d_leaky(asn.y + adn.y));
  float ws2 = __expf(d_leaky(asn.z + adn.z));
  float ws3 = __expf(d_leaky(asn.w + adn.w));
  uint2 su = *(const uint2*)(h + (size_t)node * 256 + c * 4);
  float2 sp0 = bf2x(su.x), sp1 = bf2x(su.y);
  float den0 = ws0, den1 = ws1, den2 = ws2, den3 = ws3;
  float acc0 = ws0 * sp0.x, acc1 = ws1 * sp0.y, acc2 = ws2 * sp1.x, acc3 = ws3 * sp1.y;
  int b = rowp[node], e = rowp[node + 1];
  int i = b;
  for (; i + 8 <= e; i += 8){
    int s[8]; float4 w[8]; uint2 hv[8];
    #pragma unroll
    for (int j = 0; j < 8; j++) s[j] = colv[i + j];
    #pragma unroll
    for (int j = 0; j < 8; j++) w[j] = *(const float4*)(w4 + (size_t)(i + j) * 4);
    #pragma unroll
    for (int j = 0; j < 8; j++) hv[j] = *(const uint2*)(h + (size_t)s[j] * 256 + c * 4);
    #pragma unroll
    for (int j = 0; j < 8; j++){
      float2 a = bf2x(hv[j].x), bb = bf2x(hv[j].y);
      den0 += w[j].x; den1 += w[j].y; den2 += w[j].z; den3 += w[j].w;
      acc0 += w[j].x * a.x;  acc1 += w[j].y * a.y;
      acc2 += w[j].z * bb.x; acc3 += w[j].w * bb.y;
    }
  }
  for (; i < e; i++){
    int s = colv[i];
    float4 w = *(const float4*)(w4 + (size_t)i * 4);
    uint2 hv = *(const uint2*)(h + (size_t)s * 256 + c * 4);
    float2 a = bf2x(hv.x), bb = bf2x(hv.y);
    den0 += w.x; den1 += w.y; den2 += w.z; den3 += w.w;
    acc0 += w.x * a.x;  acc1 += w.y * a.y;
    acc2 += w.z * bb.x; acc3 += w.w * bb.y;
  }
  float v0 = d_elu(acc0 / (den0 + 1e-16f) + bias[c]);
  float v1 = d_elu(acc1 / (den1 + 1e-16f) + bias[64 + c]);
  float v2 = d_elu(acc2 / (den2 + 1e-16f) + bias[128 + c]);
  float v3 = d_elu(acc3 / (den3 + 1e-16f) + bias[192 + c]);
  unsigned short h0 = f2bf_rne(v0), h1 = f2bf_rne(v1), h2 = f2bf_rne(v2), h3 = f2bf_rne(v3);
  uint2 oh; oh.x = (unsigned int)h0 | ((unsigned int)h1 << 16);
  oh.y = (unsigned int)h2 | ((unsigned int)h3 << 16);
  *(uint2*)(outh + (size_t)node * 256 + c * 4) = oh;
  uint2 ol; ol.x = packbf(v0 - bf2f(h0), v1 - bf2f(h1));
  ol.y = packbf(v2 - bf2f(h2), v3 - bf2f(h3));
  *(uint2*)(outl + (size_t)node * 256 + c * 4) = ol;
}

// ---------------- GAT2 aggregation: bf16 in, fp32 out ----------------
__global__ __launch_bounds__(256) void k_gat_agg1(
    const unsigned short* __restrict__ h, const int* __restrict__ rowp,
    const int* __restrict__ colv, const float* __restrict__ w1,
    const float* __restrict__ a_s, const float* __restrict__ a_d,
    const float* __restrict__ bias, float* __restrict__ out, int n){
  int node = blockIdx.x * 4 + (threadIdx.x >> 6);
  int c = threadIdx.x & 63;
  if (node >= n) return;
  float den = __expf(d_leaky(a_s[node] + a_d[node]));
  float acc = den * bf2f(h[(size_t)node * 64 + c]);
  int b = rowp[node], e = rowp[node + 1];
  int i = b;
  for (; i + 8 <= e; i += 8){
    int s[8]; float w[8]; unsigned short hv[8];
    #pragma unroll
    for (int j = 0; j < 8; j++) s[j] = colv[i + j];
    #pragma unroll
    for (int j = 0; j < 8; j++) w[j] = w1[i + j];
    #pragma unroll
    for (int j = 0; j < 8; j++) hv[j] = h[(size_t)s[j] * 64 + c];
    #pragma unroll
    for (int j = 0; j < 8; j++){ den += w[j]; acc += w[j] * bf2f(hv[j]); }
  }
  for (; i < e; i++){
    int s = colv[i];
    float w = w1[i];
    den += w;
    acc += w * bf2f(h[(size_t)s * 64 + c]);
  }
  out[(size_t)node * 64 + c] = d_elu(acc / (den + 1e-16f) + bias[c]);
}

// ---------------- GCN aggregation: bf16 in, fp32 or split out ----------------
__global__ __launch_bounds__(256) void k_gcn_agg(
    const unsigned short* __restrict__ h, const int* __restrict__ rowp,
    const int* __restrict__ colv, const float* __restrict__ dinv,
    const float* __restrict__ bias, float* __restrict__ outf,
    unsigned short* __restrict__ outh, unsigned short* __restrict__ outl, int n){
  int node = blockIdx.x * 4 + (threadIdx.x >> 6);
  int c = threadIdx.x & 63;
  if (node >= n) return;
  float di = dinv[node];
  float acc = di * bf2f(h[(size_t)node * 64 + c]);
  int b = rowp[node], e = rowp[node + 1];
  int i = b;
  for (; i + 8 <= e; i += 8){
    int s[8]; float w[8]; unsigned short hv[8];
    #pragma unroll
    for (int j = 0; j < 8; j++) s[j] = colv[i + j];
    #pragma unroll
    for (int j = 0; j < 8; j++) w[j] = dinv[s[j]];
    #pragma unroll
    for (int j = 0; j < 8; j++) hv[j] = h[(size_t)s[j] * 64 + c];
    #pragma unroll
    for (int j = 0; j < 8; j++) acc += w[j] * bf2f(hv[j]);
  }
  for (; i < e; i++){
    int s = colv[i];
    acc += dinv[s] * bf2f(h[(size_t)s * 64 + c]);
  }
  float v = fmaxf(di * acc + bias[c], 0.f);
  if (outf) outf[(size_t)node * 64 + c] = v;
  if (outh){
    unsigned short hh = f2bf_rne(v);
    outh[(size_t)node * 64 + c] = hh;
    outl[(size_t)node * 64 + c] = f2bf_rne(v - bf2f(hh));
  }
}

// ---------------- SAGE mean aggregation, F=64 bf16 in -> split out ----------------
__global__ __launch_bounds__(256) void k_sage_agg64(
    const unsigned short* __restrict__ xin, const int* __restrict__ rowp,
    const int* __restrict__ colv, const float* __restrict__ sdinv,
    unsigned short* __restrict__ outh, unsigned short* __restrict__ outl, int n){
  int node = blockIdx.x * 4 + (threadIdx.x >> 6);
  int c = threadIdx.x & 63;
  if (node >= n) return;
  float acc = 0.f;
  int b = rowp[node], e = rowp[node + 1];
  int i = b;
  for (; i + 8 <= e; i += 8){
    int s[8]; unsigned short hv[8];
    #pragma unroll
    for (int j = 0; j < 8; j++) s[j] = colv[i + j];
    #pragma unroll
    for (int j = 0; j < 8; j++) hv[j] = xin[(size_t)s[j] * 64 + c];
    #pragma unroll
    for (int j = 0; j < 8; j++) acc += bf2f(hv[j]);
  }
  for (; i < e; i++) acc += bf2f(xin[(size_t)colv[i] * 64 + c]);
  float v = acc * sdinv[node];
  unsigned short hh = f2bf_rne(v);
  outh[(size_t)node * 64 + c] = hh;
  outl[(size_t)node * 64 + c] = f2bf_rne(v - bf2f(hh));
}

// ---------------- SAGE mean aggregation, F=128 bf16 in -> split out ----------------
__global__ __launch_bounds__(256) void k_sage_agg128(
    const unsigned short* __restrict__ xin, const int* __restrict__ rowp,
    const int* __restrict__ colv, const float* __restrict__ sdinv,
    unsigned short* __restrict__ outh, unsigned short* __restrict__ outl, int n){
  int node = blockIdx.x * 4 + (threadIdx.x >> 6);
  int c = threadIdx.x & 63;
  if (node >= n) return;
  float acc0 = 0.f, acc1 = 0.f;
  int b = rowp[node], e = rowp[node + 1];
  int i = b;
  for (; i + 8 <= e; i += 8){
    int s[8]; unsigned int hv[8];
    #pragma unroll
    for (int j = 0; j < 8; j++) s[j] = colv[i + j];
    #pragma unroll
    for (int j = 0; j < 8; j++) hv[j] = *(const unsigned int*)(xin + (size_t)s[j] * 128 + c * 2);
    #pragma unroll
    for (int j = 0; j < 8; j++){ float2 p = bf2x(hv[j]); acc0 += p.x; acc1 += p.y; }
  }
  for (; i < e; i++){
    float2 p = bf2x(*(const unsigned int*)(xin + (size_t)colv[i] * 128 + c * 2));
    acc0 += p.x; acc1 += p.y;
  }
  float sd = sdinv[node];
  float v0 = acc0 * sd, v1 = acc1 * sd;
  unsigned short h0 = f2bf_rne(v0), h1 = f2bf_rne(v1);
  *(unsigned int*)(outh + (size_t)node * 128 + c * 2) = (unsigned int)h0 | ((unsigned int)h1 << 16);
  *(unsigned int*)(outl + (size_t)node * 128 + c * 2) = packbf(v0 - bf2f(h0), v1 - bf2f(h1));
}

// ---------------- BatchNorm ----------------
__global__ void k_bn_stats(const float* __restrict__ x, float* __restrict__ sums, int n){
  int c = threadIdx.x & 63;
  int rl = threadIdx.x >> 6;
  float s = 0.f, q = 0.f;
  for (int r = blockIdx.x * 4 + rl; r < n; r += gridDim.x * 4){
    float v = x[(size_t)r * 64 + c];
    s += v; q += v * v;
  }
  __shared__ float ls[4][64], lq[4][64];
  ls[rl][c] = s; lq[rl][c] = q;
  __syncthreads();
  if (rl == 0){
    s = ls[0][c] + ls[1][c] + ls[2][c] + ls[3][c];
    q = lq[0][c] + lq[1][c] + lq[2][c] + lq[3][c];
    atomicAdd(&sums[c], s);
    atomicAdd(&sums[64 + c], q);
  }
}

__global__ void k_bn_apply_split(const float* __restrict__ x, const float* __restrict__ sums,
                                 const float* __restrict__ g, const float* __restrict__ b,
                                 unsigned short* __restrict__ outh, unsigned short* __restrict__ outl,
                                 int n, int ldout, int coloff){
  int idx = blockIdx.x * blockDim.x + threadIdx.x;
  if (idx >= n * 64) return;
  int r = idx >> 6, c = idx & 63;
  float m = sums[c] / (float)n;
  float var = sums[64 + c] / (float)n - m * m;
  float v = (x[idx] - m) * rsqrtf(var + BN_EPS) * g[c] + b[c];
  unsigned short hh = f2bf_rne(v);
  outh[(size_t)r * ldout + coloff + c] = hh;
  outl[(size_t)r * ldout + coloff + c] = f2bf_rne(v - bf2f(hh));
}

// ---------------- final tiny FC (64 -> 2) ----------------
__global__ void k_fc2(const float* __restrict__ h, const float* __restrict__ w,
                      const float* __restrict__ b, float* __restrict__ out, int n){
  int node = blockIdx.x * 4 + (threadIdx.x >> 6);
  int lane = threadIdx.x & 63;
  if (node >= n) return;
  float v = h[(size_t)node * 64 + lane];
  float p0 = wave_sum(v * w[lane * 2 + 0]);
  float p1 = wave_sum(v * w[lane * 2 + 1]);
  if (lane == 0){
    out[node * 2 + 0] = p0 + b[0];
    out[node * 2 + 1] = p1 + b[1];
  }
}

extern "C" void kernel_launch(void* const* d_in, const int* in_sizes, int n_in,
                              void* d_out, int out_size, void* d_ws, size_t ws_size,
                              hipStream_t stream){
  (void)n_in; (void)out_size; (void)ws_size;
  const float* x        = (const float*)d_in[0];
  const int*   ei       = (const int*)  d_in[1];
  const float* gcn1_w   = (const float*)d_in[2];
  const float* gcn1_b   = (const float*)d_in[3];
  const float* gcn2_w   = (const float*)d_in[4];
  const float* gcn2_b   = (const float*)d_in[5];
  const float* gat1_w   = (const float*)d_in[6];
  const float* gat1_as  = (const float*)d_in[7];
  const float* gat1_ad  = (const float*)d_in[8];
  const float* gat1_b   = (const float*)d_in[9];
  const float* gat2_w   = (const float*)d_in[10];
  const float* gat2_as  = (const float*)d_in[11];
  const float* gat2_ad  = (const float*)d_in[12];
  const float* gat2_b   = (const float*)d_in[13];
  const float* sage1_wl = (const float*)d_in[14];
  const float* sage1_bl = (const float*)d_in[15];
  const float* sage1_wr = (const float*)d_in[16];
  const float* sage2_wl = (const float*)d_in[17];
  const float* sage2_bl = (const float*)d_in[18];
  const float* sage2_wr = (const float*)d_in[19];
  const float* bn_gcn_g = (const float*)d_in[20];
  const float* bn_gcn_b = (const float*)d_in[21];
  const float* bn_gat_g = (const float*)d_in[22];
  const float* bn_gat_b = (const float*)d_in[23];
  const float* bn_sage_g= (const float*)d_in[24];
  const float* bn_sage_b= (const float*)d_in[25];
  const float* fc1_w    = (const float*)d_in[26];
  const float* fc1_b    = (const float*)d_in[27];
  const float* fc2_w    = (const float*)d_in[28];
  const float* fc2_b    = (const float*)d_in[29];
  float* out = (float*)d_out;

  const int N = in_sizes[0] / 128;
  const int E = in_sizes[1] / 2;
  const int* src = ei;
  const int* dst = ei + E;
  const int nb = (N + 1023) / 1024;

  char* ws = (char*)d_ws;
  size_t off = 0;
  auto alloc = [&](size_t bytes) -> void* {
    void* p = ws + off;
    off = (off + bytes + 255) & ~(size_t)255;
    return p;
  };
  int*   deg   = (int*)  alloc((size_t)N * 4);
  int*   rowp  = (int*)  alloc((size_t)(N + 1) * 4);
  int*   fill  = (int*)  alloc((size_t)N * 4);
  int*   colv  = (int*)  alloc((size_t)E * 4);
  int*   dstv  = (int*)  alloc((size_t)E * 4);
  int*   bsum  = (int*)  alloc(64 * 4);
  float* dinv  = (float*)alloc((size_t)N * 4);
  float* sdinv = (float*)alloc((size_t)N * 4);
  float* as1   = (float*)alloc((size_t)N * 4 * 4);
  float* ad1   = (float*)alloc((size_t)N * 4 * 4);
  float* as2   = (float*)alloc((size_t)N * 4);
  float* ad2   = (float*)alloc((size_t)N * 4);
  float* w4    = (float*)alloc((size_t)E * 4 * 4);
  float* w1    = (float*)alloc((size_t)E * 4);
  float* bnA   = (float*)alloc(128 * 4);
  float* bnB   = (float*)alloc(128 * 4);
  float* bnC   = (float*)alloc(128 * 4);
  unsigned short* xh   = (unsigned short*)alloc((size_t)N * 128 * 2);
  unsigned short* xl   = (unsigned short*)alloc((size_t)N * 128 * 2);
  unsigned short* gath = (unsigned short*)alloc((size_t)N * 256 * 2);   // GAT1 out (ilv bf16)
  unsigned short* oh   = (unsigned short*)alloc((size_t)N * 256 * 2);   // agg4 out hi (ilv)
  unsigned short* ol   = (unsigned short*)alloc((size_t)N * 256 * 2);   // agg4 out lo
  unsigned short* t1h  = (unsigned short*)alloc((size_t)N * 64 * 2);    // GAT2 out bf16
  unsigned short* g1h  = (unsigned short*)alloc((size_t)N * 64 * 2);
  unsigned short* g2h  = (unsigned short*)alloc((size_t)N * 64 * 2);
  unsigned short* g2l  = (unsigned short*)alloc((size_t)N * 64 * 2);
  unsigned short* tg2h = (unsigned short*)alloc((size_t)N * 64 * 2);
  float* t1 = (float*)alloc((size_t)N * 64 * 4);
  float* t2 = (float*)alloc((size_t)N * 64 * 4);
  auto walloc = [&](int K, int Nc, unsigned short** th, unsigned short** tl){
    *th = (unsigned short*)alloc((size_t)K * Nc * 2);
    *tl = (unsigned short*)alloc((size_t)K * Nc * 2);
  };
  unsigned short *gcn1h,*gcn1l,*gcn2h,*gcn2l,*gat1h,*gat1l,*gat2h,*gat2l;
  unsigned short *s1wlh,*s1wll,*s1wrh,*s1wrl,*s2wlh,*s2wll,*s2wrh,*s2wrl,*fc1h,*fc1l;
  walloc(128, 64, &gcn1h, &gcn1l);
  walloc(64, 64, &gcn2h, &gcn2l);
  walloc(128, 256, &gat1h, &gat1l);
  walloc(256, 64, &gat2h, &gat2l);
  walloc(128, 64, &s1wlh, &s1wll);
  walloc(128, 64, &s1wrh, &s1wrl);
  walloc(64, 64, &s2wlh, &s2wll);
  walloc(64, 64, &s2wrh, &s2wrl);
  walloc(192, 64, &fc1h, &fc1l);

  // aliases (lifetime-disjoint)
  unsigned short* aggXh = gath;                       // SAGE agg(x): gath dead after agg4
  unsigned short* aggXl = gath + (size_t)N * 128;
  unsigned short* s1h   = g1h;                        // SAGE S1: GCN buffers dead
  unsigned short* s1l   = g2h;
  unsigned short* aggSh = g2l;
  unsigned short* aggSl = tg2h;
  unsigned short* cath  = oh;                         // concat: oh/ol dead after GAT2 GEMM
  unsigned short* catl  = ol;

  hipMemsetAsync(deg, 0, (size_t)N * 4, stream);
  hipMemsetAsync(fill, 0, (size_t)N * 4, stream);
  hipMemsetAsync(bnA, 0, 128 * 4, stream);
  hipMemsetAsync(bnB, 0, 128 * 4, stream);
  hipMemsetAsync(bnC, 0, 128 * 4, stream);

  // CSR by destination (multi-block scan)
  k_count <<<(E + 255) / 256, 256, 0, stream>>>(dst, deg, E);
  k_scan_a<<<nb, 256, 0, stream>>>(deg, bsum, N);
  k_scan_b<<<1, 64, 0, stream>>>(bsum, rowp, nb, N);
  k_scan_c<<<nb, 256, 0, stream>>>(deg, bsum, rowp, dinv, sdinv, N);
  k_scatter<<<(E + 255) / 256, 256, 0, stream>>>(src, dst, rowp, fill, colv, dstv, E);

  // weight splits + x split
  {
    WPack p;
    p.d[0] = {gcn1_w, gcn1h, gcn1l, 128, 64, 0};
    p.d[1] = {gcn2_w, gcn2h, gcn2l, 64, 64, 0};
    p.d[2] = {gat1_w, gat1h, gat1l, 128, 256, 0};
    p.d[3] = {gat2_w, gat2h, gat2l, 256, 64, 1};   // perm matches interleaved A
    p.d[4] = {sage1_wl, s1wlh, s1wll, 128, 64, 0};
    p.d[5] = {sage1_wr, s1wrh, s1wrl, 128, 64, 0};
    p.d[6] = {sage2_wl, s2wlh, s2wll, 64, 64, 0};
    p.d[7] = {sage2_wr, s2wrh, s2wrl, 64, 64, 0};
    p.d[8] = {fc1_w, fc1h, fc1l, 192, 64, 0};
    dim3 g(32, 9);
    k_wsplit<<<g, 256, 0, stream>>>(p);
  }
  k_asplit<<<(N * 128 + 255) / 256, 256, 0, stream>>>(x, xh, xl, N * 128);

  auto gemm = [&](const unsigned short* Ah, const unsigned short* Al,
                  const unsigned short* Bh, const unsigned short* Bl,
                  const float* bias, const float* res,
                  float* Cf, unsigned short* Ch, unsigned short* Cl,
                  int K, int Nc, int act, int ilv){
    dim3 g((N + 127) / 128, Nc / 64);
    k_gemm_mfma<<<g, 256, 0, stream>>>(Ah, Al, Bh, Bl, bias, res, Cf, Ch, Cl, N, K, Nc, act, ilv);
  };

  // ---- GAT branch ----
  gemm(xh, xl, gat1h, gat1l, nullptr, nullptr, nullptr, gath, nullptr, 128, 256, 0, 1); // HA1 (ilv bf16)
  k_gat_attn4<<<(N + 3) / 4, 256, 0, stream>>>(gath, gat1_as, gat1_ad, as1, ad1, N);
  k_edge_w4<<<(E + 255) / 256, 256, 0, stream>>>(colv, dstv, as1, ad1, w4, E);
  k_gat_agg4<<<(N + 3) / 4, 256, 0, stream>>>(gath, rowp, colv, w4, as1, ad1, gat1_b, oh, ol, N);
  gemm(oh, ol, gat2h, gat2l, nullptr, nullptr, nullptr, t1h, nullptr, 256, 64, 0, 0);   // HA2 bf16
  k_gat_attn1<<<(N + 3) / 4, 256, 0, stream>>>(t1h, gat2_as, gat2_ad, as2, ad2, N);
  k_edge_w1<<<(E + 255) / 256, 256, 0, stream>>>(colv, dstv, as2, ad2, w1, E);
  k_gat_agg1<<<(N + 3) / 4, 256, 0, stream>>>(t1h, rowp, colv, w1, as2, ad2, gat2_b, t2, N);
  k_bn_stats<<<128, 256, 0, stream>>>(t2, bnA, N);
  k_bn_apply_split<<<(N * 64 + 255) / 256, 256, 0, stream>>>(t2, bnA, bn_gat_g, bn_gat_b, cath, catl, N, 192, 64);

  // ---- GCN branch ----
  gemm(xh, xl, gcn1h, gcn1l, nullptr, nullptr, nullptr, g1h, nullptr, 128, 64, 0, 0);   // H1 bf16
  k_gcn_agg<<<(N + 3) / 4, 256, 0, stream>>>(g1h, rowp, colv, dinv, gcn1_b, nullptr, g2h, g2l, N);
  gemm(g2h, g2l, gcn2h, gcn2l, nullptr, nullptr, nullptr, tg2h, nullptr, 64, 64, 0, 0); // H2 bf16
  k_gcn_agg<<<(N + 3) / 4, 256, 0, stream>>>(tg2h, rowp, colv, dinv, gcn2_b, t2, nullptr, nullptr, N);
  k_bn_stats<<<128, 256, 0, stream>>>(t2, bnB, N);
  k_bn_apply_split<<<(N * 64 + 255) / 256, 256, 0, stream>>>(t2, bnB, bn_gcn_g, bn_gcn_b, cath, catl, N, 192, 0);

  // ---- SAGE branch ----
  k_sage_agg128<<<(N + 3) / 4, 256, 0, stream>>>(xh, rowp, colv, sdinv, aggXh, aggXl, N);
  gemm(xh, xl, s1wrh, s1wrl, nullptr, nullptr, t1, nullptr, nullptr, 128, 64, 0, 0);    // x@wr fp32
  gemm(aggXh, aggXl, s1wlh, s1wll, sage1_bl, t1, nullptr, s1h, s1l, 128, 64, 1, 0);     // S1 split
  k_sage_agg64<<<(N + 3) / 4, 256, 0, stream>>>(s1h, rowp, colv, sdinv, aggSh, aggSl, N);
  gemm(s1h, s1l, s2wrh, s2wrl, nullptr, nullptr, t1, nullptr, nullptr, 64, 64, 0, 0);   // S1@wr fp32
  gemm(aggSh, aggSl, s2wlh, s2wll, sage2_bl, t1, t2, nullptr, nullptr, 64, 64, 1, 0);   // S2 fp32
  k_bn_stats<<<128, 256, 0, stream>>>(t2, bnC, N);
  k_bn_apply_split<<<(N * 64 + 255) / 256, 256, 0, stream>>>(t2, bnC, bn_sage_g, bn_sage_b, cath, catl, N, 192, 128);

  // ---- FC head ----
  gemm(cath, catl, fc1h, fc1l, fc1_b, nullptr, t1, nullptr, nullptr, 192, 64, 1, 0);    // F1 fp32
  k_fc2<<<(N + 3) / 4, 256, 0, stream>>>(t1, fc2_w, fc2_b, out, N);
}

// Round 5
// 809.508 us; speedup vs baseline: 1.5476x; 1.0354x over previous
//
#include <hip/hip_runtime.h>
#include <math.h>

#define NEG_SLOPE 0.2f
#define BN_EPS 1e-5f

typedef short short8 __attribute__((ext_vector_type(8)));
typedef float floatx16 __attribute__((ext_vector_type(16)));

__device__ __forceinline__ float d_leaky(float x){ return x > 0.f ? x : NEG_SLOPE * x; }
__device__ __forceinline__ float d_elu(float x){ return x > 0.f ? x : expm1f(x); }

__device__ __forceinline__ unsigned short f2bf_rne(float f){
  unsigned int u = __float_as_uint(f);
  unsigned int r = (u + 0x7fffu + ((u >> 16) & 1u)) >> 16;
  return (unsigned short)r;
}
__device__ __forceinline__ float bf2f(unsigned short h){ return __uint_as_float((unsigned int)h << 16); }
__device__ __forceinline__ float2 bf2x(unsigned int u){
  float2 r;
  r.x = __uint_as_float(u << 16);
  r.y = __uint_as_float(u & 0xffff0000u);
  return r;
}
__device__ __forceinline__ unsigned int packbf(float a, float b){
  return (unsigned int)f2bf_rne(a) | ((unsigned int)f2bf_rne(b) << 16);
}

__device__ __forceinline__ float wave_sum(float v){
  #pragma unroll
  for (int off = 32; off > 0; off >>= 1) v += __shfl_xor(v, off, 64);
  return v;
}
__device__ __forceinline__ int wave_scan_incl(int v, int lane){
  #pragma unroll
  for (int off = 1; off < 64; off <<= 1){
    int u = __shfl_up(v, off, 64);
    if (lane >= off) v += u;
  }
  return v;
}

// ---------------- CSR build ----------------
__global__ void k_count(const int* __restrict__ dst, int* __restrict__ deg, int E){
  int e = blockIdx.x * blockDim.x + threadIdx.x;
  if (e < E) atomicAdd(&deg[dst[e]], 1);
}

__global__ __launch_bounds__(256) void k_scan_a(const int* __restrict__ deg, int* __restrict__ bsum, int n){
  int t = threadIdx.x;
  int base = blockIdx.x * 1024 + t * 4;
  int d0=0,d1=0,d2=0,d3=0;
  if (base + 3 < n){ int4 v = *(const int4*)(deg + base); d0=v.x; d1=v.y; d2=v.z; d3=v.w; }
  else {
    if (base   < n) d0 = deg[base];
    if (base+1 < n) d1 = deg[base+1];
    if (base+2 < n) d2 = deg[base+2];
    if (base+3 < n) d3 = deg[base+3];
  }
  int s = d0+d1+d2+d3;
  __shared__ int wsm[4];
  int lane = t & 63, w = t >> 6;
  int incl = wave_scan_incl(s, lane);
  if (lane == 63) wsm[w] = incl;
  __syncthreads();
  if (t == 0) bsum[blockIdx.x] = wsm[0]+wsm[1]+wsm[2]+wsm[3];
}

__global__ void k_scan_b(int* __restrict__ bsum, int* __restrict__ rowp, int nb, int n){
  int t = threadIdx.x;  // 64 threads, nb <= 64
  int v = (t < nb) ? bsum[t] : 0;
  int incl = wave_scan_incl(v, t);
  if (t < nb) bsum[t] = incl - v;
  if (t == 63) rowp[n] = incl;
}

__global__ __launch_bounds__(256) void k_scan_c(const int* __restrict__ deg, const int* __restrict__ bsum,
                                                int* __restrict__ rowp, float* __restrict__ dinv,
                                                float* __restrict__ sdinv, int n){
  int t = threadIdx.x;
  int base = blockIdx.x * 1024 + t * 4;
  int d0=0,d1=0,d2=0,d3=0;
  if (base + 3 < n){ int4 v = *(const int4*)(deg + base); d0=v.x; d1=v.y; d2=v.z; d3=v.w; }
  else {
    if (base   < n) d0 = deg[base];
    if (base+1 < n) d1 = deg[base+1];
    if (base+2 < n) d2 = deg[base+2];
    if (base+3 < n) d3 = deg[base+3];
  }
  int s = d0+d1+d2+d3;
  __shared__ int wsm[4];
  int lane = t & 63, w = t >> 6;
  int incl = wave_scan_incl(s, lane);
  if (lane == 63) wsm[w] = incl;
  __syncthreads();
  int woff = 0;
  #pragma unroll
  for (int j = 0; j < 4; j++) if (j < w) woff += wsm[j];
  int r = bsum[blockIdx.x] + woff + incl - s;
  int dd[4] = {d0,d1,d2,d3};
  #pragma unroll
  for (int j = 0; j < 4; j++){
    int i = base + j;
    if (i < n){
      rowp[i] = r;
      dinv[i] = rsqrtf((float)(dd[j] + 1));
      sdinv[i] = 1.0f / fmaxf((float)dd[j], 1.0f);
    }
    r += dd[j];
  }
}

__global__ void k_scatter(const int* __restrict__ src, const int* __restrict__ dst,
                          const int* __restrict__ rowp, int* __restrict__ fill,
                          int* __restrict__ colv, int* __restrict__ dstv, int E){
  int e = blockIdx.x * blockDim.x + threadIdx.x;
  if (e < E){
    int d = dst[e];
    int pos = rowp[d] + atomicAdd(&fill[d], 1);
    colv[pos] = src[e];
    dstv[pos] = d;
  }
}

// ---------------- split fp32 -> bf16 hi/lo ----------------
__global__ void k_asplit(const float* __restrict__ a, unsigned short* __restrict__ h,
                         unsigned short* __restrict__ l, int total){
  int i = blockIdx.x * blockDim.x + threadIdx.x;
  if (i < total){
    float v = a[i];
    unsigned short hh = f2bf_rne(v);
    h[i] = hh;
    l[i] = f2bf_rne(v - bf2f(hh));
  }
}

// ---------------- weight transpose + split: W[K][Nc] -> Wt_hi/lo[Ncperm][Kperm] ----------------
// perm: 0 none; 1 = K-permute (for interleaved-A GEMM, gat2); 2 = col-permute (head-interleave C, gat1)
struct WDesc { const float* w; unsigned short* th; unsigned short* tl; int K; int Nc; int perm; };
struct WPack { WDesc d[9]; };
__global__ void k_wsplit(WPack p){
  WDesc w = p.d[blockIdx.y];
  int total = w.K * w.Nc;
  for (int i = blockIdx.x * blockDim.x + threadIdx.x; i < total; i += gridDim.x * blockDim.x){
    int k = i / w.Nc, n = i % w.Nc;
    int kd = (w.perm == 1) ? ((k & 63) * 4 + (k >> 6)) : k;
    int nd = (w.perm == 2) ? (((n & 63) << 2) | (n >> 6)) : n;
    float v = w.w[i];
    unsigned short h = f2bf_rne(v);
    w.th[(size_t)nd * w.K + kd] = h;
    w.tl[(size_t)nd * w.K + kd] = f2bf_rne(v - bf2f(h));
  }
}

// ---------------- MFMA bf16x3 GEMM ----------------
// C = act(A@W + bias + res). A split hi/lo, W transposed split. All stores contiguous.
__global__ __launch_bounds__(256) void k_gemm_mfma(
    const unsigned short* __restrict__ Ah, const unsigned short* __restrict__ Al,
    const unsigned short* __restrict__ Bh, const unsigned short* __restrict__ Bl,
    const float* __restrict__ bias, const float* __restrict__ res,
    float* __restrict__ Cf, unsigned short* __restrict__ Ch, unsigned short* __restrict__ Cl,
    int M, int K, int Nc, int act)
{
  int wave = threadIdx.x >> 6, lane = threadIdx.x & 63;
  int m0 = blockIdx.x * 128 + wave * 32;
  int n0 = blockIdx.y * 64;
  int lr = lane & 31;
  int ko8 = (lane >> 5) * 8;
  floatx16 acc0 = {0,0,0,0,0,0,0,0,0,0,0,0,0,0,0,0};
  floatx16 acc1 = {0,0,0,0,0,0,0,0,0,0,0,0,0,0,0,0};
  int arow = m0 + lr; if (arow >= M) arow = M - 1;
  const unsigned short* ap_h = Ah + (size_t)arow * K + ko8;
  const unsigned short* ap_l = Al + (size_t)arow * K + ko8;
  const unsigned short* bp_h0 = Bh + (size_t)(n0 + lr) * K + ko8;
  const unsigned short* bp_l0 = Bl + (size_t)(n0 + lr) * K + ko8;
  const unsigned short* bp_h1 = bp_h0 + (size_t)32 * K;
  const unsigned short* bp_l1 = bp_l0 + (size_t)32 * K;
  for (int k0 = 0; k0 < K; k0 += 16){
    short8 a_h  = *(const short8*)(ap_h + k0);
    short8 a_l  = *(const short8*)(ap_l + k0);
    short8 b_h0 = *(const short8*)(bp_h0 + k0);
    short8 b_l0 = *(const short8*)(bp_l0 + k0);
    short8 b_h1 = *(const short8*)(bp_h1 + k0);
    short8 b_l1 = *(const short8*)(bp_l1 + k0);
    acc0 = __builtin_amdgcn_mfma_f32_32x32x16_bf16(a_l, b_h0, acc0, 0, 0, 0);
    acc0 = __builtin_amdgcn_mfma_f32_32x32x16_bf16(a_h, b_l0, acc0, 0, 0, 0);
    acc0 = __builtin_amdgcn_mfma_f32_32x32x16_bf16(a_h, b_h0, acc0, 0, 0, 0);
    acc1 = __builtin_amdgcn_mfma_f32_32x32x16_bf16(a_l, b_h1, acc1, 0, 0, 0);
    acc1 = __builtin_amdgcn_mfma_f32_32x32x16_bf16(a_h, b_l1, acc1, 0, 0, 0);
    acc1 = __builtin_amdgcn_mfma_f32_32x32x16_bf16(a_h, b_h1, acc1, 0, 0, 0);
  }
  int col0 = n0 + lr, col1 = col0 + 32;
  float bias0 = bias ? bias[col0] : 0.f;
  float bias1 = bias ? bias[col1] : 0.f;
  int rbase = m0 + 4 * (lane >> 5);
  #pragma unroll
  for (int reg = 0; reg < 16; reg++){
    int row = rbase + (reg & 3) + 8 * (reg >> 2);
    if (row >= M) continue;
    float v0 = acc0[reg] + bias0;
    float v1 = acc1[reg] + bias1;
    if (res){
      v0 += res[(size_t)row * Nc + col0];
      v1 += res[(size_t)row * Nc + col1];
    }
    if (act){ v0 = fmaxf(v0, 0.f); v1 = fmaxf(v1, 0.f); }
    if (Cf){
      Cf[(size_t)row * Nc + col0] = v0;
      Cf[(size_t)row * Nc + col1] = v1;
    }
    if (Ch){
      size_t i0 = (size_t)row * Nc + col0;
      size_t i1 = (size_t)row * Nc + col1;
      unsigned short h0 = f2bf_rne(v0), h1 = f2bf_rne(v1);
      Ch[i0] = h0; Ch[i1] = h1;
      if (Cl){
        Cl[i0] = f2bf_rne(v0 - bf2f(h0));
        Cl[i1] = f2bf_rne(v1 - bf2f(h1));
      }
    }
  }
}

// ---------------- GAT1 attention coeffs (interleaved bf16 h), wave per node ----------------
__global__ __launch_bounds__(256) void k_gat_attn4(
    const unsigned short* __restrict__ h, const float* __restrict__ asrc,
    const float* __restrict__ adst, float* __restrict__ a_s, float* __restrict__ a_d, int n){
  int node = blockIdx.x * 4 + (threadIdx.x >> 6);
  int c = threadIdx.x & 63;
  if (node >= n) return;
  uint2 u = *(const uint2*)(h + (size_t)node * 256 + c * 4);
  float2 p0 = bf2x(u.x), p1 = bf2x(u.y);
  float s0 = wave_sum(p0.x * asrc[c]);
  float s1 = wave_sum(p0.y * asrc[64 + c]);
  float s2 = wave_sum(p1.x * asrc[128 + c]);
  float s3 = wave_sum(p1.y * asrc[192 + c]);
  float d0 = wave_sum(p0.x * adst[c]);
  float d1 = wave_sum(p0.y * adst[64 + c]);
  float d2 = wave_sum(p1.x * adst[128 + c]);
  float d3 = wave_sum(p1.y * adst[192 + c]);
  if (c == 0){
    *(float4*)(a_s + (size_t)node * 4) = make_float4(s0, s1, s2, s3);
    *(float4*)(a_d + (size_t)node * 4) = make_float4(d0, d1, d2, d3);
  }
}

// ---------------- GAT2 attention coeffs (bf16 h), wave per node ----------------
__global__ __launch_bounds__(256) void k_gat_attn1(
    const unsigned short* __restrict__ h, const float* __restrict__ asrc,
    const float* __restrict__ adst, float* __restrict__ a_s, float* __restrict__ a_d, int n){
  int node = blockIdx.x * 4 + (threadIdx.x >> 6);
  int c = threadIdx.x & 63;
  if (node >= n) return;
  float v = bf2f(h[(size_t)node * 64 + c]);
  float s = wave_sum(v * asrc[c]);
  float d = wave_sum(v * adst[c]);
  if (c == 0){ a_s[node] = s; a_d[node] = d; }
}

// ---------------- per-edge softmax numerators ----------------
__global__ void k_edge_w4(const int* __restrict__ colv, const int* __restrict__ dstv,
                          const float* __restrict__ a_s, const float* __restrict__ a_d,
                          float* __restrict__ w4, int E){
  int i = blockIdx.x * blockDim.x + threadIdx.x;
  if (i >= E) return;
  float4 s4 = *(const float4*)(a_s + (size_t)colv[i] * 4);
  float4 d4 = *(const float4*)(a_d + (size_t)dstv[i] * 4);
  float4 w;
  w.x = __expf(d_leaky(s4.x + d4.x));
  w.y = __expf(d_leaky(s4.y + d4.y));
  w.z = __expf(d_leaky(s4.z + d4.z));
  w.w = __expf(d_leaky(s4.w + d4.w));
  *(float4*)(w4 + (size_t)i * 4) = w;
}

__global__ void k_edge_w1(const int* __restrict__ colv, const int* __restrict__ dstv,
                          const float* __restrict__ a_s, const float* __restrict__ a_d,
                          float* __restrict__ w1, int E){
  int i = blockIdx.x * blockDim.x + threadIdx.x;
  if (i >= E) return;
  w1[i] = __expf(d_leaky(a_s[colv[i]] + a_d[dstv[i]]));
}

// ---------------- GAT1 aggregation: interleaved bf16, wave/node, all 4 heads ----------------
__global__ __launch_bounds__(256) void k_gat_agg4(
    const unsigned short* __restrict__ h, const int* __restrict__ rowp,
    const int* __restrict__ colv, const float* __restrict__ w4,
    const float* __restrict__ a_s, const float* __restrict__ a_d,
    const float* __restrict__ bias,
    unsigned short* __restrict__ outh, unsigned short* __restrict__ outl, int n){
  int node = blockIdx.x * 4 + (threadIdx.x >> 6);
  int c = threadIdx.x & 63;
  if (node >= n) return;
  float4 asn = *(const float4*)(a_s + (size_t)node * 4);
  float4 adn = *(const float4*)(a_d + (size_t)node * 4);
  float ws0 = __expf(d_leaky(asn.x + adn.x));
  float ws1 = __expf(d_leaky(asn.y + adn.y));
  float ws2 = __expf(d_leaky(asn.z + adn.z));
  float ws3 = __expf(d_leaky(asn.w + adn.w));
  uint2 su = *(const uint2*)(h + (size_t)node * 256 + c * 4);
  float2 sp0 = bf2x(su.x), sp1 = bf2x(su.y);
  float den0 = ws0, den1 = ws1, den2 = ws2, den3 = ws3;
  float acc0 = ws0 * sp0.x, acc1 = ws1 * sp0.y, acc2 = ws2 * sp1.x, acc3 = ws3 * sp1.y;
  int b = rowp[node], e = rowp[node + 1];
  int i = b;
  for (; i + 8 <= e; i += 8){
    int s[8]; float4 w[8]; uint2 hv[8];
    #pragma unroll
    for (int j = 0; j < 8; j++) s[j] = colv[i + j];
    #pragma unroll
    for (int j = 0; j < 8; j++) w[j] = *(const float4*)(w4 + (size_t)(i + j) * 4);
    #pragma unroll
    for (int j = 0; j < 8; j++) hv[j] = *(const uint2*)(h + (size_t)s[j] * 256 + c * 4);
    #pragma unroll
    for (int j = 0; j < 8; j++){
      float2 a = bf2x(hv[j].x), bb = bf2x(hv[j].y);
      den0 += w[j].x; den1 += w[j].y; den2 += w[j].z; den3 += w[j].w;
      acc0 += w[j].x * a.x;  acc1 += w[j].y * a.y;
      acc2 += w[j].z * bb.x; acc3 += w[j].w * bb.y;
    }
  }
  for (; i < e; i++){
    int s = colv[i];
    float4 w = *(const float4*)(w4 + (size_t)i * 4);
    uint2 hv = *(const uint2*)(h + (size_t)s * 256 + c * 4);
    float2 a = bf2x(hv.x), bb = bf2x(hv.y);
    den0 += w.x; den1 += w.y; den2 += w.z; den3 += w.w;
    acc0 += w.x * a.x;  acc1 += w.y * a.y;
    acc2 += w.z * bb.x; acc3 += w.w * bb.y;
  }
  float v0 = d_elu(acc0 / (den0 + 1e-16f) + bias[c]);
  float v1 = d_elu(acc1 / (den1 + 1e-16f) + bias[64 + c]);
  float v2 = d_elu(acc2 / (den2 + 1e-16f) + bias[128 + c]);
  float v3 = d_elu(acc3 / (den3 + 1e-16f) + bias[192 + c]);
  unsigned short h0 = f2bf_rne(v0), h1 = f2bf_rne(v1), h2 = f2bf_rne(v2), h3 = f2bf_rne(v3);
  uint2 oh; oh.x = (unsigned int)h0 | ((unsigned int)h1 << 16);
  oh.y = (unsigned int)h2 | ((unsigned int)h3 << 16);
  *(uint2*)(outh + (size_t)node * 256 + c * 4) = oh;
  uint2 ol; ol.x = packbf(v0 - bf2f(h0), v1 - bf2f(h1));
  ol.y = packbf(v2 - bf2f(h2), v3 - bf2f(h3));
  *(uint2*)(outl + (size_t)node * 256 + c * 4) = ol;
}

// ---------------- GAT2 aggregation: bf16 in, fp32 out ----------------
__global__ __launch_bounds__(256) void k_gat_agg1(
    const unsigned short* __restrict__ h, const int* __restrict__ rowp,
    const int* __restrict__ colv, const float* __restrict__ w1,
    const float* __restrict__ a_s, const float* __restrict__ a_d,
    const float* __restrict__ bias, float* __restrict__ out, int n){
  int node = blockIdx.x * 4 + (threadIdx.x >> 6);
  int c = threadIdx.x & 63;
  if (node >= n) return;
  float den = __expf(d_leaky(a_s[node] + a_d[node]));
  float acc = den * bf2f(h[(size_t)node * 64 + c]);
  int b = rowp[node], e = rowp[node + 1];
  int i = b;
  for (; i + 8 <= e; i += 8){
    int s[8]; float w[8]; unsigned short hv[8];
    #pragma unroll
    for (int j = 0; j < 8; j++) s[j] = colv[i + j];
    #pragma unroll
    for (int j = 0; j < 8; j++) w[j] = w1[i + j];
    #pragma unroll
    for (int j = 0; j < 8; j++) hv[j] = h[(size_t)s[j] * 64 + c];
    #pragma unroll
    for (int j = 0; j < 8; j++){ den += w[j]; acc += w[j] * bf2f(hv[j]); }
  }
  for (; i < e; i++){
    int s = colv[i];
    float w = w1[i];
    den += w;
    acc += w * bf2f(h[(size_t)s * 64 + c]);
  }
  out[(size_t)node * 64 + c] = d_elu(acc / (den + 1e-16f) + bias[c]);
}

// ---------------- GCN aggregation: bf16 in, fp32 or split out ----------------
__global__ __launch_bounds__(256) void k_gcn_agg(
    const unsigned short* __restrict__ h, const int* __restrict__ rowp,
    const int* __restrict__ colv, const float* __restrict__ dinv,
    const float* __restrict__ bias, float* __restrict__ outf,
    unsigned short* __restrict__ outh, unsigned short* __restrict__ outl, int n){
  int node = blockIdx.x * 4 + (threadIdx.x >> 6);
  int c = threadIdx.x & 63;
  if (node >= n) return;
  float di = dinv[node];
  float acc = di * bf2f(h[(size_t)node * 64 + c]);
  int b = rowp[node], e = rowp[node + 1];
  int i = b;
  for (; i + 8 <= e; i += 8){
    int s[8]; float w[8]; unsigned short hv[8];
    #pragma unroll
    for (int j = 0; j < 8; j++) s[j] = colv[i + j];
    #pragma unroll
    for (int j = 0; j < 8; j++) w[j] = dinv[s[j]];
    #pragma unroll
    for (int j = 0; j < 8; j++) hv[j] = h[(size_t)s[j] * 64 + c];
    #pragma unroll
    for (int j = 0; j < 8; j++) acc += w[j] * bf2f(hv[j]);
  }
  for (; i < e; i++){
    int s = colv[i];
    acc += dinv[s] * bf2f(h[(size_t)s * 64 + c]);
  }
  float v = fmaxf(di * acc + bias[c], 0.f);
  if (outf) outf[(size_t)node * 64 + c] = v;
  if (outh){
    unsigned short hh = f2bf_rne(v);
    outh[(size_t)node * 64 + c] = hh;
    outl[(size_t)node * 64 + c] = f2bf_rne(v - bf2f(hh));
  }
}

// ---------------- SAGE mean aggregation, F=64 bf16 in -> split out ----------------
__global__ __launch_bounds__(256) void k_sage_agg64(
    const unsigned short* __restrict__ xin, const int* __restrict__ rowp,
    const int* __restrict__ colv, const float* __restrict__ sdinv,
    unsigned short* __restrict__ outh, unsigned short* __restrict__ outl, int n){
  int node = blockIdx.x * 4 + (threadIdx.x >> 6);
  int c = threadIdx.x & 63;
  if (node >= n) return;
  float acc = 0.f;
  int b = rowp[node], e = rowp[node + 1];
  int i = b;
  for (; i + 8 <= e; i += 8){
    int s[8]; unsigned short hv[8];
    #pragma unroll
    for (int j = 0; j < 8; j++) s[j] = colv[i + j];
    #pragma unroll
    for (int j = 0; j < 8; j++) hv[j] = xin[(size_t)s[j] * 64 + c];
    #pragma unroll
    for (int j = 0; j < 8; j++) acc += bf2f(hv[j]);
  }
  for (; i < e; i++) acc += bf2f(xin[(size_t)colv[i] * 64 + c]);
  float v = acc * sdinv[node];
  unsigned short hh = f2bf_rne(v);
  outh[(size_t)node * 64 + c] = hh;
  outl[(size_t)node * 64 + c] = f2bf_rne(v - bf2f(hh));
}

// ---------------- SAGE mean aggregation, F=128 bf16 in -> split out ----------------
__global__ __launch_bounds__(256) void k_sage_agg128(
    const unsigned short* __restrict__ xin, const int* __restrict__ rowp,
    const int* __restrict__ colv, const float* __restrict__ sdinv,
    unsigned short* __restrict__ outh, unsigned short* __restrict__ outl, int n){
  int node = blockIdx.x * 4 + (threadIdx.x >> 6);
  int c = threadIdx.x & 63;
  if (node >= n) return;
  float acc0 = 0.f, acc1 = 0.f;
  int b = rowp[node], e = rowp[node + 1];
  int i = b;
  for (; i + 8 <= e; i += 8){
    int s[8]; unsigned int hv[8];
    #pragma unroll
    for (int j = 0; j < 8; j++) s[j] = colv[i + j];
    #pragma unroll
    for (int j = 0; j < 8; j++) hv[j] = *(const unsigned int*)(xin + (size_t)s[j] * 128 + c * 2);
    #pragma unroll
    for (int j = 0; j < 8; j++){ float2 p = bf2x(hv[j]); acc0 += p.x; acc1 += p.y; }
  }
  for (; i < e; i++){
    float2 p = bf2x(*(const unsigned int*)(xin + (size_t)colv[i] * 128 + c * 2));
    acc0 += p.x; acc1 += p.y;
  }
  float sd = sdinv[node];
  float v0 = acc0 * sd, v1 = acc1 * sd;
  unsigned short h0 = f2bf_rne(v0), h1 = f2bf_rne(v1);
  *(unsigned int*)(outh + (size_t)node * 128 + c * 2) = (unsigned int)h0 | ((unsigned int)h1 << 16);
  *(unsigned int*)(outl + (size_t)node * 128 + c * 2) = packbf(v0 - bf2f(h0), v1 - bf2f(h1));
}

// ---------------- BatchNorm ----------------
__global__ void k_bn_stats(const float* __restrict__ x, float* __restrict__ sums, int n){
  int c = threadIdx.x & 63;
  int rl = threadIdx.x >> 6;
  float s = 0.f, q = 0.f;
  for (int r = blockIdx.x * 4 + rl; r < n; r += gridDim.x * 4){
    float v = x[(size_t)r * 64 + c];
    s += v; q += v * v;
  }
  __shared__ float ls[4][64], lq[4][64];
  ls[rl][c] = s; lq[rl][c] = q;
  __syncthreads();
  if (rl == 0){
    s = ls[0][c] + ls[1][c] + ls[2][c] + ls[3][c];
    q = lq[0][c] + lq[1][c] + lq[2][c] + lq[3][c];
    atomicAdd(&sums[c], s);
    atomicAdd(&sums[64 + c], q);
  }
}

__global__ void k_bn_apply_split(const float* __restrict__ x, const float* __restrict__ sums,
                                 const float* __restrict__ g, const float* __restrict__ b,
                                 unsigned short* __restrict__ outh, unsigned short* __restrict__ outl,
                                 int n, int ldout, int coloff){
  int idx = blockIdx.x * blockDim.x + threadIdx.x;
  if (idx >= n * 64) return;
  int r = idx >> 6, c = idx & 63;
  float m = sums[c] / (float)n;
  float var = sums[64 + c] / (float)n - m * m;
  float v = (x[idx] - m) * rsqrtf(var + BN_EPS) * g[c] + b[c];
  unsigned short hh = f2bf_rne(v);
  outh[(size_t)r * ldout + coloff + c] = hh;
  outl[(size_t)r * ldout + coloff + c] = f2bf_rne(v - bf2f(hh));
}

// ---------------- final tiny FC (64 -> 2) ----------------
__global__ void k_fc2(const float* __restrict__ h, const float* __restrict__ w,
                      const float* __restrict__ b, float* __restrict__ out, int n){
  int node = blockIdx.x * 4 + (threadIdx.x >> 6);
  int lane = threadIdx.x & 63;
  if (node >= n) return;
  float v = h[(size_t)node * 64 + lane];
  float p0 = wave_sum(v * w[lane * 2 + 0]);
  float p1 = wave_sum(v * w[lane * 2 + 1]);
  if (lane == 0){
    out[node * 2 + 0] = p0 + b[0];
    out[node * 2 + 1] = p1 + b[1];
  }
}

extern "C" void kernel_launch(void* const* d_in, const int* in_sizes, int n_in,
                              void* d_out, int out_size, void* d_ws, size_t ws_size,
                              hipStream_t stream){
  (void)n_in; (void)out_size; (void)ws_size;
  const float* x        = (const float*)d_in[0];
  const int*   ei       = (const int*)  d_in[1];
  const float* gcn1_w   = (const float*)d_in[2];
  const float* gcn1_b   = (const float*)d_in[3];
  const float* gcn2_w   = (const float*)d_in[4];
  const float* gcn2_b   = (const float*)d_in[5];
  const float* gat1_w   = (const float*)d_in[6];
  const float* gat1_as  = (const float*)d_in[7];
  const float* gat1_ad  = (const float*)d_in[8];
  const float* gat1_b   = (const float*)d_in[9];
  const float* gat2_w   = (const float*)d_in[10];
  const float* gat2_as  = (const float*)d_in[11];
  const float* gat2_ad  = (const float*)d_in[12];
  const float* gat2_b   = (const float*)d_in[13];
  const float* sage1_wl = (const float*)d_in[14];
  const float* sage1_bl = (const float*)d_in[15];
  const float* sage1_wr = (const float*)d_in[16];
  const float* sage2_wl = (const float*)d_in[17];
  const float* sage2_bl = (const float*)d_in[18];
  const float* sage2_wr = (const float*)d_in[19];
  const float* bn_gcn_g = (const float*)d_in[20];
  const float* bn_gcn_b = (const float*)d_in[21];
  const float* bn_gat_g = (const float*)d_in[22];
  const float* bn_gat_b = (const float*)d_in[23];
  const float* bn_sage_g= (const float*)d_in[24];
  const float* bn_sage_b= (const float*)d_in[25];
  const float* fc1_w    = (const float*)d_in[26];
  const float* fc1_b    = (const float*)d_in[27];
  const float* fc2_w    = (const float*)d_in[28];
  const float* fc2_b    = (const float*)d_in[29];
  float* out = (float*)d_out;

  const int N = in_sizes[0] / 128;
  const int E = in_sizes[1] / 2;
  const int* src = ei;
  const int* dst = ei + E;
  const int nb = (N + 1023) / 1024;

  char* ws = (char*)d_ws;
  size_t off = 0;
  auto alloc = [&](size_t bytes) -> void* {
    void* p = ws + off;
    off = (off + bytes + 255) & ~(size_t)255;
    return p;
  };
  int*   deg   = (int*)  alloc((size_t)N * 4);
  int*   rowp  = (int*)  alloc((size_t)(N + 1) * 4);
  int*   fill  = (int*)  alloc((size_t)N * 4);
  int*   colv  = (int*)  alloc((size_t)E * 4);
  int*   dstv  = (int*)  alloc((size_t)E * 4);
  int*   bsum  = (int*)  alloc(64 * 4);
  float* dinv  = (float*)alloc((size_t)N * 4);
  float* sdinv = (float*)alloc((size_t)N * 4);
  float* as1   = (float*)alloc((size_t)N * 4 * 4);
  float* ad1   = (float*)alloc((size_t)N * 4 * 4);
  float* as2   = (float*)alloc((size_t)N * 4);
  float* ad2   = (float*)alloc((size_t)N * 4);
  float* w4    = (float*)alloc((size_t)E * 4 * 4);
  float* w1    = (float*)alloc((size_t)E * 4);
  float* bnA   = (float*)alloc(128 * 4);
  float* bnB   = (float*)alloc(128 * 4);
  float* bnC   = (float*)alloc(128 * 4);
  unsigned short* xh   = (unsigned short*)alloc((size_t)N * 128 * 2);
  unsigned short* xl   = (unsigned short*)alloc((size_t)N * 128 * 2);
  unsigned short* gath = (unsigned short*)alloc((size_t)N * 256 * 2);   // GAT1 out (ilv bf16)
  unsigned short* oh   = (unsigned short*)alloc((size_t)N * 256 * 2);   // agg4 out hi (ilv)
  unsigned short* ol   = (unsigned short*)alloc((size_t)N * 256 * 2);   // agg4 out lo
  unsigned short* t1h  = (unsigned short*)alloc((size_t)N * 64 * 2);    // GAT2 out bf16
  unsigned short* g1h  = (unsigned short*)alloc((size_t)N * 64 * 2);
  unsigned short* g2h  = (unsigned short*)alloc((size_t)N * 64 * 2);
  unsigned short* g2l  = (unsigned short*)alloc((size_t)N * 64 * 2);
  unsigned short* tg2h = (unsigned short*)alloc((size_t)N * 64 * 2);
  float* t1 = (float*)alloc((size_t)N * 64 * 4);
  float* t2 = (float*)alloc((size_t)N * 64 * 4);
  auto walloc = [&](int K, int Nc, unsigned short** th, unsigned short** tl){
    *th = (unsigned short*)alloc((size_t)K * Nc * 2);
    *tl = (unsigned short*)alloc((size_t)K * Nc * 2);
  };
  unsigned short *gcn1h,*gcn1l,*gcn2h,*gcn2l,*gat1h,*gat1l,*gat2h,*gat2l;
  unsigned short *s1wlh,*s1wll,*s1wrh,*s1wrl,*s2wlh,*s2wll,*s2wrh,*s2wrl,*fc1h,*fc1l;
  walloc(128, 64, &gcn1h, &gcn1l);
  walloc(64, 64, &gcn2h, &gcn2l);
  walloc(128, 256, &gat1h, &gat1l);
  walloc(256, 64, &gat2h, &gat2l);
  walloc(128, 64, &s1wlh, &s1wll);
  walloc(128, 64, &s1wrh, &s1wrl);
  walloc(64, 64, &s2wlh, &s2wll);
  walloc(64, 64, &s2wrh, &s2wrl);
  walloc(192, 64, &fc1h, &fc1l);

  // aliases (lifetime-disjoint)
  unsigned short* aggXh = gath;                       // SAGE agg(x): gath dead after agg4
  unsigned short* aggXl = gath + (size_t)N * 128;
  unsigned short* s1h   = g1h;                        // SAGE S1: GCN buffers dead
  unsigned short* s1l   = g2h;
  unsigned short* aggSh = g2l;
  unsigned short* aggSl = tg2h;
  unsigned short* cath  = oh;                         // concat: oh/ol dead after GAT2 GEMM
  unsigned short* catl  = ol;

  hipMemsetAsync(deg, 0, (size_t)N * 4, stream);
  hipMemsetAsync(fill, 0, (size_t)N * 4, stream);
  hipMemsetAsync(bnA, 0, 128 * 4, stream);
  hipMemsetAsync(bnB, 0, 128 * 4, stream);
  hipMemsetAsync(bnC, 0, 128 * 4, stream);

  // CSR by destination (multi-block scan)
  k_count <<<(E + 255) / 256, 256, 0, stream>>>(dst, deg, E);
  k_scan_a<<<nb, 256, 0, stream>>>(deg, bsum, N);
  k_scan_b<<<1, 64, 0, stream>>>(bsum, rowp, nb, N);
  k_scan_c<<<nb, 256, 0, stream>>>(deg, bsum, rowp, dinv, sdinv, N);
  k_scatter<<<(E + 255) / 256, 256, 0, stream>>>(src, dst, rowp, fill, colv, dstv, E);

  // weight splits + x split
  {
    WPack p;
    p.d[0] = {gcn1_w, gcn1h, gcn1l, 128, 64, 0};
    p.d[1] = {gcn2_w, gcn2h, gcn2l, 64, 64, 0};
    p.d[2] = {gat1_w, gat1h, gat1l, 128, 256, 2};  // col-perm -> GEMM writes interleaved directly
    p.d[3] = {gat2_w, gat2h, gat2l, 256, 64, 1};   // K-perm matches interleaved A
    p.d[4] = {sage1_wl, s1wlh, s1wll, 128, 64, 0};
    p.d[5] = {sage1_wr, s1wrh, s1wrl, 128, 64, 0};
    p.d[6] = {sage2_wl, s2wlh, s2wll, 64, 64, 0};
    p.d[7] = {sage2_wr, s2wrh, s2wrl, 64, 64, 0};
    p.d[8] = {fc1_w, fc1h, fc1l, 192, 64, 0};
    dim3 g(32, 9);
    k_wsplit<<<g, 256, 0, stream>>>(p);
  }
  k_asplit<<<(N * 128 + 255) / 256, 256, 0, stream>>>(x, xh, xl, N * 128);

  auto gemm = [&](const unsigned short* Ah, const unsigned short* Al,
                  const unsigned short* Bh, const unsigned short* Bl,
                  const float* bias, const float* res,
                  float* Cf, unsigned short* Ch, unsigned short* Cl,
                  int K, int Nc, int act){
    dim3 g((N + 127) / 128, Nc / 64);
    k_gemm_mfma<<<g, 256, 0, stream>>>(Ah, Al, Bh, Bl, bias, res, Cf, Ch, Cl, N, K, Nc, act);
  };

  // ---- GAT branch ----
  gemm(xh, xl, gat1h, gat1l, nullptr, nullptr, nullptr, gath, nullptr, 128, 256, 0); // HA1 (ilv via B col-perm)
  k_gat_attn4<<<(N + 3) / 4, 256, 0, stream>>>(gath, gat1_as, gat1_ad, as1, ad1, N);
  k_edge_w4<<<(E + 255) / 256, 256, 0, stream>>>(colv, dstv, as1, ad1, w4, E);
  k_gat_agg4<<<(N + 3) / 4, 256, 0, stream>>>(gath, rowp, colv, w4, as1, ad1, gat1_b, oh, ol, N);
  gemm(oh, ol, gat2h, gat2l, nullptr, nullptr, nullptr, t1h, nullptr, 256, 64, 0);   // HA2 bf16
  k_gat_attn1<<<(N + 3) / 4, 256, 0, stream>>>(t1h, gat2_as, gat2_ad, as2, ad2, N);
  k_edge_w1<<<(E + 255) / 256, 256, 0, stream>>>(colv, dstv, as2, ad2, w1, E);
  k_gat_agg1<<<(N + 3) / 4, 256, 0, stream>>>(t1h, rowp, colv, w1, as2, ad2, gat2_b, t2, N);
  k_bn_stats<<<128, 256, 0, stream>>>(t2, bnA, N);
  k_bn_apply_split<<<(N * 64 + 255) / 256, 256, 0, stream>>>(t2, bnA, bn_gat_g, bn_gat_b, cath, catl, N, 192, 64);

  // ---- GCN branch ----
  gemm(xh, xl, gcn1h, gcn1l, nullptr, nullptr, nullptr, g1h, nullptr, 128, 64, 0);   // H1 bf16
  k_gcn_agg<<<(N + 3) / 4, 256, 0, stream>>>(g1h, rowp, colv, dinv, gcn1_b, nullptr, g2h, g2l, N);
  gemm(g2h, g2l, gcn2h, gcn2l, nullptr, nullptr, nullptr, tg2h, nullptr, 64, 64, 0); // H2 bf16
  k_gcn_agg<<<(N + 3) / 4, 256, 0, stream>>>(tg2h, rowp, colv, dinv, gcn2_b, t2, nullptr, nullptr, N);
  k_bn_stats<<<128, 256, 0, stream>>>(t2, bnB, N);
  k_bn_apply_split<<<(N * 64 + 255) / 256, 256, 0, stream>>>(t2, bnB, bn_gcn_g, bn_gcn_b, cath, catl, N, 192, 0);

  // ---- SAGE branch ----
  k_sage_agg128<<<(N + 3) / 4, 256, 0, stream>>>(xh, rowp, colv, sdinv, aggXh, aggXl, N);
  gemm(xh, xl, s1wrh, s1wrl, nullptr, nullptr, t1, nullptr, nullptr, 128, 64, 0);    // x@wr fp32
  gemm(aggXh, aggXl, s1wlh, s1wll, sage1_bl, t1, nullptr, s1h, s1l, 128, 64, 1);     // S1 split
  k_sage_agg64<<<(N + 3) / 4, 256, 0, stream>>>(s1h, rowp, colv, sdinv, aggSh, aggSl, N);
  gemm(s1h, s1l, s2wrh, s2wrl, nullptr, nullptr, t1, nullptr, nullptr, 64, 64, 0);   // S1@wr fp32
  gemm(aggSh, aggSl, s2wlh, s2wll, sage2_bl, t1, t2, nullptr, nullptr, 64, 64, 1);   // S2 fp32
  k_bn_stats<<<128, 256, 0, stream>>>(t2, bnC, N);
  k_bn_apply_split<<<(N * 64 + 255) / 256, 256, 0, stream>>>(t2, bnC, bn_sage_g, bn_sage_b, cath, catl, N, 192, 128);

  // ---- FC head ----
  gemm(cath, catl, fc1h, fc1l, fc1_b, nullptr, t1, nullptr, nullptr, 192, 64, 1);    // F1 fp32
  k_fc2<<<(N + 3) / 4, 256, 0, stream>>>(t1, fc2_w, fc2_b, out, N);
}

// Round 7
// 797.240 us; speedup vs baseline: 1.5714x; 1.0154x over previous
//
#include <hip/hip_runtime.h>
#include <math.h>

#define NEG_SLOPE 0.2f
#define BN_EPS 1e-5f

typedef short short8 __attribute__((ext_vector_type(8)));
typedef float floatx16 __attribute__((ext_vector_type(16)));

__device__ __forceinline__ float d_leaky(float x){ return x > 0.f ? x : NEG_SLOPE * x; }
__device__ __forceinline__ float d_elu(float x){ return x > 0.f ? x : expm1f(x); }

__device__ __forceinline__ unsigned short f2bf_rne(float f){
  unsigned int u = __float_as_uint(f);
  unsigned int r = (u + 0x7fffu + ((u >> 16) & 1u)) >> 16;
  return (unsigned short)r;
}
__device__ __forceinline__ float bf2f(unsigned short h){ return __uint_as_float((unsigned int)h << 16); }
__device__ __forceinline__ float2 bf2x(unsigned int u){
  float2 r;
  r.x = __uint_as_float(u << 16);
  r.y = __uint_as_float(u & 0xffff0000u);
  return r;
}

__device__ __forceinline__ float wave_sum(float v){
  #pragma unroll
  for (int off = 32; off > 0; off >>= 1) v += __shfl_xor(v, off, 64);
  return v;
}
__device__ __forceinline__ int wave_scan_incl(int v, int lane){
  #pragma unroll
  for (int off = 1; off < 64; off <<= 1){
    int u = __shfl_up(v, off, 64);
    if (lane >= off) v += u;
  }
  return v;
}

// ---------------- CSR build ----------------
__global__ void k_count(const int* __restrict__ dst, int* __restrict__ deg, int E){
  int e = blockIdx.x * blockDim.x + threadIdx.x;
  if (e < E) atomicAdd(&deg[dst[e]], 1);
}

__global__ __launch_bounds__(256) void k_scan_a(const int* __restrict__ deg, int* __restrict__ bsum, int n){
  int t = threadIdx.x;
  int base = blockIdx.x * 1024 + t * 4;
  int d0=0,d1=0,d2=0,d3=0;
  if (base + 3 < n){ int4 v = *(const int4*)(deg + base); d0=v.x; d1=v.y; d2=v.z; d3=v.w; }
  else {
    if (base   < n) d0 = deg[base];
    if (base+1 < n) d1 = deg[base+1];
    if (base+2 < n) d2 = deg[base+2];
    if (base+3 < n) d3 = deg[base+3];
  }
  int s = d0+d1+d2+d3;
  __shared__ int wsm[4];
  int lane = t & 63, w = t >> 6;
  int incl = wave_scan_incl(s, lane);
  if (lane == 63) wsm[w] = incl;
  __syncthreads();
  if (t == 0) bsum[blockIdx.x] = wsm[0]+wsm[1]+wsm[2]+wsm[3];
}

__global__ void k_scan_b(int* __restrict__ bsum, int* __restrict__ rowp, int nb, int n){
  int t = threadIdx.x;  // 64 threads, nb <= 64
  int v = (t < nb) ? bsum[t] : 0;
  int incl = wave_scan_incl(v, t);
  if (t < nb) bsum[t] = incl - v;
  if (t == 63) rowp[n] = incl;
}

__global__ __launch_bounds__(256) void k_scan_c(const int* __restrict__ deg, const int* __restrict__ bsum,
                                                int* __restrict__ rowp, float* __restrict__ dinv,
                                                float* __restrict__ sdinv, int n){
  int t = threadIdx.x;
  int base = blockIdx.x * 1024 + t * 4;
  int d0=0,d1=0,d2=0,d3=0;
  if (base + 3 < n){ int4 v = *(const int4*)(deg + base); d0=v.x; d1=v.y; d2=v.z; d3=v.w; }
  else {
    if (base   < n) d0 = deg[base];
    if (base+1 < n) d1 = deg[base+1];
    if (base+2 < n) d2 = deg[base+2];
    if (base+3 < n) d3 = deg[base+3];
  }
  int s = d0+d1+d2+d3;
  __shared__ int wsm[4];
  int lane = t & 63, w = t >> 6;
  int incl = wave_scan_incl(s, lane);
  if (lane == 63) wsm[w] = incl;
  __syncthreads();
  int woff = 0;
  #pragma unroll
  for (int j = 0; j < 4; j++) if (j < w) woff += wsm[j];
  int r = bsum[blockIdx.x] + woff + incl - s;
  int dd[4] = {d0,d1,d2,d3};
  #pragma unroll
  for (int j = 0; j < 4; j++){
    int i = base + j;
    if (i < n){
      rowp[i] = r;
      dinv[i] = rsqrtf((float)(dd[j] + 1));
      sdinv[i] = 1.0f / fmaxf((float)dd[j], 1.0f);
    }
    r += dd[j];
  }
}

__global__ void k_scatter(const int* __restrict__ src, const int* __restrict__ dst,
                          const int* __restrict__ rowp, int* __restrict__ fill,
                          int* __restrict__ colv, int* __restrict__ dstv, int E){
  int e = blockIdx.x * blockDim.x + threadIdx.x;
  if (e < E){
    int d = dst[e];
    int pos = rowp[d] + atomicAdd(&fill[d], 1);
    colv[pos] = src[e];
    dstv[pos] = d;
  }
}

// ---------------- split fp32 -> bf16 hi/lo ----------------
__global__ void k_asplit(const float* __restrict__ a, unsigned short* __restrict__ h,
                         unsigned short* __restrict__ l, int total){
  int i = blockIdx.x * blockDim.x + threadIdx.x;
  if (i < total){
    float v = a[i];
    unsigned short hh = f2bf_rne(v);
    h[i] = hh;
    l[i] = f2bf_rne(v - bf2f(hh));
  }
}

// ---------------- weight transpose + split ----------------
// perm: 0 none; 1 = K-permute (interleaved-A GEMM, gat2); 2 = col-permute (head-interleave C, gat1)
struct WDesc { const float* w; unsigned short* th; unsigned short* tl; int K; int Nc; int perm; };
struct WPack { WDesc d[8]; };
__global__ void k_wsplit(WPack p){
  WDesc w = p.d[blockIdx.y];
  int total = w.K * w.Nc;
  for (int i = blockIdx.x * blockDim.x + threadIdx.x; i < total; i += gridDim.x * blockDim.x){
    int k = i / w.Nc, n = i % w.Nc;
    int kd = (w.perm == 1) ? ((k & 63) * 4 + (k >> 6)) : k;
    int nd = (w.perm == 2) ? (((n & 63) << 2) | (n >> 6)) : n;
    float v = w.w[i];
    unsigned short h = f2bf_rne(v);
    w.th[(size_t)nd * w.K + kd] = h;
    w.tl[(size_t)nd * w.K + kd] = f2bf_rne(v - bf2f(h));
  }
}

// ---------------- MFMA GEMM: C = act(A@W + bias), bf16-hi out ----------------
// A hi (+optional lo), W transposed split hi/lo (NB rows). Cols < nc1 -> C1 (ld nc1),
// cols >= nc1 -> C2 (ld NB-nc1). Tile 128x64 per block, 4 waves.
__global__ __launch_bounds__(256) void k_gemm_mfma(
    const unsigned short* __restrict__ Ah, const unsigned short* __restrict__ Al,
    const unsigned short* __restrict__ Bh, const unsigned short* __restrict__ Bl,
    const float* __restrict__ bias,
    unsigned short* __restrict__ C1, int nc1, unsigned short* __restrict__ C2,
    int M, int K, int NB, int act)
{
  int wave = threadIdx.x >> 6, lane = threadIdx.x & 63;
  int m0 = blockIdx.x * 128 + wave * 32;
  int n0 = blockIdx.y * 64;
  int lr = lane & 31;
  int ko8 = (lane >> 5) * 8;
  floatx16 acc0 = {0,0,0,0,0,0,0,0,0,0,0,0,0,0,0,0};
  floatx16 acc1 = {0,0,0,0,0,0,0,0,0,0,0,0,0,0,0,0};
  int arow = m0 + lr; if (arow >= M) arow = M - 1;
  const unsigned short* ap_h = Ah + (size_t)arow * K + ko8;
  const unsigned short* ap_l = Al ? Al + (size_t)arow * K + ko8 : nullptr;
  const unsigned short* bp_h0 = Bh + (size_t)(n0 + lr) * K + ko8;
  const unsigned short* bp_l0 = Bl + (size_t)(n0 + lr) * K + ko8;
  const unsigned short* bp_h1 = bp_h0 + (size_t)32 * K;
  const unsigned short* bp_l1 = bp_l0 + (size_t)32 * K;
  for (int k0 = 0; k0 < K; k0 += 16){
    short8 a_h  = *(const short8*)(ap_h + k0);
    short8 b_h0 = *(const short8*)(bp_h0 + k0);
    short8 b_l0 = *(const short8*)(bp_l0 + k0);
    short8 b_h1 = *(const short8*)(bp_h1 + k0);
    short8 b_l1 = *(const short8*)(bp_l1 + k0);
    if (ap_l){
      short8 a_l = *(const short8*)(ap_l + k0);
      acc0 = __builtin_amdgcn_mfma_f32_32x32x16_bf16(a_l, b_h0, acc0, 0, 0, 0);
      acc1 = __builtin_amdgcn_mfma_f32_32x32x16_bf16(a_l, b_h1, acc1, 0, 0, 0);
    }
    acc0 = __builtin_amdgcn_mfma_f32_32x32x16_bf16(a_h, b_l0, acc0, 0, 0, 0);
    acc0 = __builtin_amdgcn_mfma_f32_32x32x16_bf16(a_h, b_h0, acc0, 0, 0, 0);
    acc1 = __builtin_amdgcn_mfma_f32_32x32x16_bf16(a_h, b_l1, acc1, 0, 0, 0);
    acc1 = __builtin_amdgcn_mfma_f32_32x32x16_bf16(a_h, b_h1, acc1, 0, 0, 0);
  }
  int col0 = n0 + lr, col1 = col0 + 32;
  float bias0 = bias ? bias[col0] : 0.f;
  float bias1 = bias ? bias[col1] : 0.f;
  unsigned short* Cp; int ld, c0, c1;
  if (C2 && col0 >= nc1){ Cp = C2; ld = NB - nc1; c0 = col0 - nc1; c1 = col1 - nc1; }
  else { Cp = C1; ld = nc1; c0 = col0; c1 = col1; }
  int rbase = m0 + 4 * (lane >> 5);
  #pragma unroll
  for (int reg = 0; reg < 16; reg++){
    int row = rbase + (reg & 3) + 8 * (reg >> 2);
    if (row >= M) continue;
    float v0 = acc0[reg] + bias0;
    float v1 = acc1[reg] + bias1;
    if (act){ v0 = fmaxf(v0, 0.f); v1 = fmaxf(v1, 0.f); }
    Cp[(size_t)row * ld + c0] = f2bf_rne(v0);
    Cp[(size_t)row * ld + c1] = f2bf_rne(v1);
  }
}

// ---------------- dual-A MFMA GEMM: out = relu(A1@B1 + A2@B2 + bias), bf16 out ----------------
// Nc = 64 fixed. A1 hi-only; A2 hi (+opt lo). Write at row*ldc + coloff + col.
__global__ __launch_bounds__(256) void k_gemm_dual(
    const unsigned short* __restrict__ A1h, const unsigned short* __restrict__ B1h,
    const unsigned short* __restrict__ B1l, int K1,
    const unsigned short* __restrict__ A2h, const unsigned short* __restrict__ A2l,
    const unsigned short* __restrict__ B2h, const unsigned short* __restrict__ B2l, int K2,
    const float* __restrict__ bias,
    unsigned short* __restrict__ outh, int ldc, int coloff, int M)
{
  int wave = threadIdx.x >> 6, lane = threadIdx.x & 63;
  int m0 = blockIdx.x * 128 + wave * 32;
  int lr = lane & 31;
  int ko8 = (lane >> 5) * 8;
  floatx16 acc0 = {0,0,0,0,0,0,0,0,0,0,0,0,0,0,0,0};
  floatx16 acc1 = {0,0,0,0,0,0,0,0,0,0,0,0,0,0,0,0};
  int arow = m0 + lr; if (arow >= M) arow = M - 1;
  {
    const unsigned short* ap = A1h + (size_t)arow * K1 + ko8;
    const unsigned short* bh0 = B1h + (size_t)lr * K1 + ko8;
    const unsigned short* bl0 = B1l + (size_t)lr * K1 + ko8;
    const unsigned short* bh1 = bh0 + (size_t)32 * K1;
    const unsigned short* bl1 = bl0 + (size_t)32 * K1;
    for (int k0 = 0; k0 < K1; k0 += 16){
      short8 a = *(const short8*)(ap + k0);
      short8 h0 = *(const short8*)(bh0 + k0);
      short8 l0 = *(const short8*)(bl0 + k0);
      short8 h1 = *(const short8*)(bh1 + k0);
      short8 l1 = *(const short8*)(bl1 + k0);
      acc0 = __builtin_amdgcn_mfma_f32_32x32x16_bf16(a, l0, acc0, 0, 0, 0);
      acc0 = __builtin_amdgcn_mfma_f32_32x32x16_bf16(a, h0, acc0, 0, 0, 0);
      acc1 = __builtin_amdgcn_mfma_f32_32x32x16_bf16(a, l1, acc1, 0, 0, 0);
      acc1 = __builtin_amdgcn_mfma_f32_32x32x16_bf16(a, h1, acc1, 0, 0, 0);
    }
  }
  {
    const unsigned short* ap = A2h + (size_t)arow * K2 + ko8;
    const unsigned short* al = A2l ? A2l + (size_t)arow * K2 + ko8 : nullptr;
    const unsigned short* bh0 = B2h + (size_t)lr * K2 + ko8;
    const unsigned short* bl0 = B2l + (size_t)lr * K2 + ko8;
    const unsigned short* bh1 = bh0 + (size_t)32 * K2;
    const unsigned short* bl1 = bl0 + (size_t)32 * K2;
    for (int k0 = 0; k0 < K2; k0 += 16){
      short8 a = *(const short8*)(ap + k0);
      short8 h0 = *(const short8*)(bh0 + k0);
      short8 l0 = *(const short8*)(bl0 + k0);
      short8 h1 = *(const short8*)(bh1 + k0);
      short8 l1 = *(const short8*)(bl1 + k0);
      if (al){
        short8 a2 = *(const short8*)(al + k0);
        acc0 = __builtin_amdgcn_mfma_f32_32x32x16_bf16(a2, h0, acc0, 0, 0, 0);
        acc1 = __builtin_amdgcn_mfma_f32_32x32x16_bf16(a2, h1, acc1, 0, 0, 0);
      }
      acc0 = __builtin_amdgcn_mfma_f32_32x32x16_bf16(a, l0, acc0, 0, 0, 0);
      acc0 = __builtin_amdgcn_mfma_f32_32x32x16_bf16(a, h0, acc0, 0, 0, 0);
      acc1 = __builtin_amdgcn_mfma_f32_32x32x16_bf16(a, l1, acc1, 0, 0, 0);
      acc1 = __builtin_amdgcn_mfma_f32_32x32x16_bf16(a, h1, acc1, 0, 0, 0);
    }
  }
  int col0 = lr, col1 = lr + 32;
  float bias0 = bias[col0], bias1 = bias[col1];
  int rbase = m0 + 4 * (lane >> 5);
  #pragma unroll
  for (int reg = 0; reg < 16; reg++){
    int row = rbase + (reg & 3) + 8 * (reg >> 2);
    if (row >= M) continue;
    float v0 = fmaxf(acc0[reg] + bias0, 0.f);
    float v1 = fmaxf(acc1[reg] + bias1, 0.f);
    outh[(size_t)row * ldc + coloff + col0] = f2bf_rne(v0);
    outh[(size_t)row * ldc + coloff + col1] = f2bf_rne(v1);
  }
}

// ---------------- GAT1 attention coeffs (interleaved bf16 h) ----------------
__global__ __launch_bounds__(256) void k_gat_attn4(
    const unsigned short* __restrict__ h, const float* __restrict__ asrc,
    const float* __restrict__ adst, float* __restrict__ a_s, float* __restrict__ a_d, int n){
  int node = blockIdx.x * 4 + (threadIdx.x >> 6);
  int c = threadIdx.x & 63;
  if (node >= n) return;
  uint2 u = *(const uint2*)(h + (size_t)node * 256 + c * 4);
  float2 p0 = bf2x(u.x), p1 = bf2x(u.y);
  float s0 = wave_sum(p0.x * asrc[c]);
  float s1 = wave_sum(p0.y * asrc[64 + c]);
  float s2 = wave_sum(p1.x * asrc[128 + c]);
  float s3 = wave_sum(p1.y * asrc[192 + c]);
  float d0 = wave_sum(p0.x * adst[c]);
  float d1 = wave_sum(p0.y * adst[64 + c]);
  float d2 = wave_sum(p1.x * adst[128 + c]);
  float d3 = wave_sum(p1.y * adst[192 + c]);
  if (c == 0){
    *(float4*)(a_s + (size_t)node * 4) = make_float4(s0, s1, s2, s3);
    *(float4*)(a_d + (size_t)node * 4) = make_float4(d0, d1, d2, d3);
  }
}

// ---------------- GAT2 attention coeffs (bf16 h) ----------------
__global__ __launch_bounds__(256) void k_gat_attn1(
    const unsigned short* __restrict__ h, const float* __restrict__ asrc,
    const float* __restrict__ adst, float* __restrict__ a_s, float* __restrict__ a_d, int n){
  int node = blockIdx.x * 4 + (threadIdx.x >> 6);
  int c = threadIdx.x & 63;
  if (node >= n) return;
  float v = bf2f(h[(size_t)node * 64 + c]);
  float s = wave_sum(v * asrc[c]);
  float d = wave_sum(v * adst[c]);
  if (c == 0){ a_s[node] = s; a_d[node] = d; }
}

// ---------------- per-edge softmax numerators ----------------
__global__ void k_edge_w4(const int* __restrict__ colv, const int* __restrict__ dstv,
                          const float* __restrict__ a_s, const float* __restrict__ a_d,
                          float* __restrict__ w4, int E){
  int i = blockIdx.x * blockDim.x + threadIdx.x;
  if (i >= E) return;
  float4 s4 = *(const float4*)(a_s + (size_t)colv[i] * 4);
  float4 d4 = *(const float4*)(a_d + (size_t)dstv[i] * 4);
  float4 w;
  w.x = __expf(d_leaky(s4.x + d4.x));
  w.y = __expf(d_leaky(s4.y + d4.y));
  w.z = __expf(d_leaky(s4.z + d4.z));
  w.w = __expf(d_leaky(s4.w + d4.w));
  *(float4*)(w4 + (size_t)i * 4) = w;
}

__global__ void k_edge_w1(const int* __restrict__ colv, const int* __restrict__ dstv,
                          const float* __restrict__ a_s, const float* __restrict__ a_d,
                          float* __restrict__ w1, int E){
  int i = blockIdx.x * blockDim.x + threadIdx.x;
  if (i >= E) return;
  w1[i] = __expf(d_leaky(a_s[colv[i]] + a_d[dstv[i]]));
}

// ---------------- GAT1 aggregation: interleaved bf16, wave/node, 4 heads, bf16 out ----------------
__global__ __launch_bounds__(256) void k_gat_agg4(
    const unsigned short* __restrict__ h, const int* __restrict__ rowp,
    const int* __restrict__ colv, const float* __restrict__ w4,
    const float* __restrict__ a_s, const float* __restrict__ a_d,
    const float* __restrict__ bias, unsigned short* __restrict__ outh, int n){
  int node = blockIdx.x * 4 + (threadIdx.x >> 6);
  int c = threadIdx.x & 63;
  if (node >= n) return;
  float4 asn = *(const float4*)(a_s + (size_t)node * 4);
  float4 adn = *(const float4*)(a_d + (size_t)node * 4);
  float ws0 = __expf(d_leaky(asn.x + adn.x));
  float ws1 = __expf(d_leaky(asn.y + adn.y));
  float ws2 = __expf(d_leaky(asn.z + adn.z));
  float ws3 = __expf(d_leaky(asn.w + adn.w));
  uint2 su = *(const uint2*)(h + (size_t)node * 256 + c * 4);
  float2 sp0 = bf2x(su.x), sp1 = bf2x(su.y);
  float den0 = ws0, den1 = ws1, den2 = ws2, den3 = ws3;
  float acc0 = ws0 * sp0.x, acc1 = ws1 * sp0.y, acc2 = ws2 * sp1.x, acc3 = ws3 * sp1.y;
  int b = rowp[node], e = rowp[node + 1];
  int i = b;
  for (; i + 8 <= e; i += 8){
    int s[8]; float4 w[8]; uint2 hv[8];
    #pragma unroll
    for (int j = 0; j < 8; j++) s[j] = colv[i + j];
    #pragma unroll
    for (int j = 0; j < 8; j++) w[j] = *(const float4*)(w4 + (size_t)(i + j) * 4);
    #pragma unroll
    for (int j = 0; j < 8; j++) hv[j] = *(const uint2*)(h + (size_t)s[j] * 256 + c * 4);
    #pragma unroll
    for (int j = 0; j < 8; j++){
      float2 a = bf2x(hv[j].x), bb = bf2x(hv[j].y);
      den0 += w[j].x; den1 += w[j].y; den2 += w[j].z; den3 += w[j].w;
      acc0 += w[j].x * a.x;  acc1 += w[j].y * a.y;
      acc2 += w[j].z * bb.x; acc3 += w[j].w * bb.y;
    }
  }
  for (; i < e; i++){
    int s = colv[i];
    float4 w = *(const float4*)(w4 + (size_t)i * 4);
    uint2 hv = *(const uint2*)(h + (size_t)s * 256 + c * 4);
    float2 a = bf2x(hv.x), bb = bf2x(hv.y);
    den0 += w.x; den1 += w.y; den2 += w.z; den3 += w.w;
    acc0 += w.x * a.x;  acc1 += w.y * a.y;
    acc2 += w.z * bb.x; acc3 += w.w * bb.y;
  }
  float v0 = d_elu(acc0 / (den0 + 1e-16f) + bias[c]);
  float v1 = d_elu(acc1 / (den1 + 1e-16f) + bias[64 + c]);
  float v2 = d_elu(acc2 / (den2 + 1e-16f) + bias[128 + c]);
  float v3 = d_elu(acc3 / (den3 + 1e-16f) + bias[192 + c]);
  uint2 oh;
  oh.x = (unsigned int)f2bf_rne(v0) | ((unsigned int)f2bf_rne(v1) << 16);
  oh.y = (unsigned int)f2bf_rne(v2) | ((unsigned int)f2bf_rne(v3) << 16);
  *(uint2*)(outh + (size_t)node * 256 + c * 4) = oh;
}

// ---------------- GAT2 aggregation: bf16 in, pre-BN bf16 out into cat ----------------
__global__ __launch_bounds__(256) void k_gat_agg1(
    const unsigned short* __restrict__ h, const int* __restrict__ rowp,
    const int* __restrict__ colv, const float* __restrict__ w1,
    const float* __restrict__ a_s, const float* __restrict__ a_d,
    const float* __restrict__ bias, unsigned short* __restrict__ outh,
    int ldo, int co, int n){
  int node = blockIdx.x * 4 + (threadIdx.x >> 6);
  int c = threadIdx.x & 63;
  if (node >= n) return;
  float den = __expf(d_leaky(a_s[node] + a_d[node]));
  float acc = den * bf2f(h[(size_t)node * 64 + c]);
  int b = rowp[node], e = rowp[node + 1];
  int i = b;
  for (; i + 8 <= e; i += 8){
    int s[8]; float w[8]; unsigned short hv[8];
    #pragma unroll
    for (int j = 0; j < 8; j++) s[j] = colv[i + j];
    #pragma unroll
    for (int j = 0; j < 8; j++) w[j] = w1[i + j];
    #pragma unroll
    for (int j = 0; j < 8; j++) hv[j] = h[(size_t)s[j] * 64 + c];
    #pragma unroll
    for (int j = 0; j < 8; j++){ den += w[j]; acc += w[j] * bf2f(hv[j]); }
  }
  for (; i < e; i++){
    int s = colv[i];
    float w = w1[i];
    den += w;
    acc += w * bf2f(h[(size_t)s * 64 + c]);
  }
  float v = d_elu(acc / (den + 1e-16f) + bias[c]);
  outh[(size_t)node * ldo + co + c] = f2bf_rne(v);
}

// ---------------- GCN aggregation: bf16 in, bf16 out (ldo/co) ----------------
__global__ __launch_bounds__(256) void k_gcn_agg(
    const unsigned short* __restrict__ h, const int* __restrict__ rowp,
    const int* __restrict__ colv, const float* __restrict__ dinv,
    const float* __restrict__ bias, unsigned short* __restrict__ outh,
    int ldo, int co, int n){
  int node = blockIdx.x * 4 + (threadIdx.x >> 6);
  int c = threadIdx.x & 63;
  if (node >= n) return;
  float di = dinv[node];
  float acc = di * bf2f(h[(size_t)node * 64 + c]);
  int b = rowp[node], e = rowp[node + 1];
  int i = b;
  for (; i + 8 <= e; i += 8){
    int s[8]; float w[8]; unsigned short hv[8];
    #pragma unroll
    for (int j = 0; j < 8; j++) s[j] = colv[i + j];
    #pragma unroll
    for (int j = 0; j < 8; j++) w[j] = dinv[s[j]];
    #pragma unroll
    for (int j = 0; j < 8; j++) hv[j] = h[(size_t)s[j] * 64 + c];
    #pragma unroll
    for (int j = 0; j < 8; j++) acc += w[j] * bf2f(hv[j]);
  }
  for (; i < e; i++){
    int s = colv[i];
    acc += dinv[s] * bf2f(h[(size_t)s * 64 + c]);
  }
  float v = fmaxf(di * acc + bias[c], 0.f);
  outh[(size_t)node * ldo + co + c] = f2bf_rne(v);
}

// ---------------- SAGE mean aggregation, F=64 bf16 in -> bf16 out ----------------
__global__ __launch_bounds__(256) void k_sage_agg64(
    const unsigned short* __restrict__ xin, const int* __restrict__ rowp,
    const int* __restrict__ colv, const float* __restrict__ sdinv,
    unsigned short* __restrict__ outh, int n){
  int node = blockIdx.x * 4 + (threadIdx.x >> 6);
  int c = threadIdx.x & 63;
  if (node >= n) return;
  float acc = 0.f;
  int b = rowp[node], e = rowp[node + 1];
  int i = b;
  for (; i + 8 <= e; i += 8){
    int s[8]; unsigned short hv[8];
    #pragma unroll
    for (int j = 0; j < 8; j++) s[j] = colv[i + j];
    #pragma unroll
    for (int j = 0; j < 8; j++) hv[j] = xin[(size_t)s[j] * 64 + c];
    #pragma unroll
    for (int j = 0; j < 8; j++) acc += bf2f(hv[j]);
  }
  for (; i < e; i++) acc += bf2f(xin[(size_t)colv[i] * 64 + c]);
  outh[(size_t)node * 64 + c] = f2bf_rne(acc * sdinv[node]);
}

// ---------------- SAGE mean aggregation, F=128 bf16 in -> bf16 out ----------------
__global__ __launch_bounds__(256) void k_sage_agg128(
    const unsigned short* __restrict__ xin, const int* __restrict__ rowp,
    const int* __restrict__ colv, const float* __restrict__ sdinv,
    unsigned short* __restrict__ outh, int n){
  int node = blockIdx.x * 4 + (threadIdx.x >> 6);
  int c = threadIdx.x & 63;
  if (node >= n) return;
  float acc0 = 0.f, acc1 = 0.f;
  int b = rowp[node], e = rowp[node + 1];
  int i = b;
  for (; i + 8 <= e; i += 8){
    int s[8]; unsigned int hv[8];
    #pragma unroll
    for (int j = 0; j < 8; j++) s[j] = colv[i + j];
    #pragma unroll
    for (int j = 0; j < 8; j++) hv[j] = *(const unsigned int*)(xin + (size_t)s[j] * 128 + c * 2);
    #pragma unroll
    for (int j = 0; j < 8; j++){ float2 p = bf2x(hv[j]); acc0 += p.x; acc1 += p.y; }
  }
  for (; i < e; i++){
    float2 p = bf2x(*(const unsigned int*)(xin + (size_t)colv[i] * 128 + c * 2));
    acc0 += p.x; acc1 += p.y;
  }
  float sd = sdinv[node];
  *(unsigned int*)(outh + (size_t)node * 128 + c * 2) =
      (unsigned int)f2bf_rne(acc0 * sd) | ((unsigned int)f2bf_rne(acc1 * sd) << 16);
}

// ---------------- BN stats from bf16 cat segment ----------------
__global__ void k_bn_stats_b(const unsigned short* __restrict__ x, float* __restrict__ sums,
                             int n, int ld, int co){
  int c = threadIdx.x & 63;
  int rl = threadIdx.x >> 6;
  float s = 0.f, q = 0.f;
  for (int r = blockIdx.x * 4 + rl; r < n; r += gridDim.x * 4){
    float v = bf2f(x[(size_t)r * ld + co + c]);
    s += v; q += v * v;
  }
  __shared__ float ls[4][64], lq[4][64];
  ls[rl][c] = s; lq[rl][c] = q;
  __syncthreads();
  if (rl == 0){
    s = ls[0][c] + ls[1][c] + ls[2][c] + ls[3][c];
    q = lq[0][c] + lq[1][c] + lq[2][c] + lq[3][c];
    atomicAdd(&sums[c], s);
    atomicAdd(&sums[64 + c], q);
  }
}

// ---------------- fold BN into fc1 weights ----------------
// cat col c: branch 0 = gcn (0..63, bnB), 1 = gat (64..127, bnA), 2 = sage (128..191, bnC)
__global__ __launch_bounds__(256) void k_bnfold(
    const float* __restrict__ bnGCN, const float* __restrict__ bnGAT, const float* __restrict__ bnSAGE,
    const float* __restrict__ gg, const float* __restrict__ gb,
    const float* __restrict__ ag, const float* __restrict__ ab,
    const float* __restrict__ sg, const float* __restrict__ sb,
    const float* __restrict__ w, const float* __restrict__ wb, float nf,
    unsigned short* __restrict__ fwh, unsigned short* __restrict__ fwl, float* __restrict__ fb)
{
  int tid = threadIdx.x;
  auto st = [&](int c, float& s, float& t){
    int cc = c & 63;
    const float *bn, *g, *b;
    if (c < 64){ bn = bnGCN; g = gg; b = gb; }
    else if (c < 128){ bn = bnGAT; g = ag; b = ab; }
    else { bn = bnSAGE; g = sg; b = sb; }
    float m = bn[cc] / nf;
    float var = bn[64 + cc] / nf - m * m;
    float inv = rsqrtf(var + BN_EPS);
    s = inv * g[cc];
    t = b[cc] - m * inv * g[cc];
  };
  if (tid < 64){
    float acc = wb[tid];
    for (int c = 0; c < 192; c++){
      float s, t; st(c, s, t);
      acc += t * w[c * 64 + tid];
    }
    fb[tid] = acc;
  }
  for (int i = tid; i < 192 * 64; i += 256){
    int c = i >> 6, nn = i & 63;
    float s, t; st(c, s, t);
    float v = s * w[i];
    unsigned short hh = f2bf_rne(v);
    fwh[nn * 192 + c] = hh;
    fwl[nn * 192 + c] = f2bf_rne(v - bf2f(hh));
  }
}

// ---------------- final tiny FC (64 -> 2), bf16 in ----------------
__global__ void k_fc2(const unsigned short* __restrict__ h, const float* __restrict__ w,
                      const float* __restrict__ b, float* __restrict__ out, int n){
  int node = blockIdx.x * 4 + (threadIdx.x >> 6);
  int lane = threadIdx.x & 63;
  if (node >= n) return;
  float v = bf2f(h[(size_t)node * 64 + lane]);
  float p0 = wave_sum(v * w[lane * 2 + 0]);
  float p1 = wave_sum(v * w[lane * 2 + 1]);
  if (lane == 0){
    out[node * 2 + 0] = p0 + b[0];
    out[node * 2 + 1] = p1 + b[1];
  }
}

extern "C" void kernel_launch(void* const* d_in, const int* in_sizes, int n_in,
                              void* d_out, int out_size, void* d_ws, size_t ws_size,
                              hipStream_t stream){
  (void)n_in; (void)out_size; (void)ws_size;
  const float* x        = (const float*)d_in[0];
  const int*   ei       = (const int*)  d_in[1];
  const float* gcn1_w   = (const float*)d_in[2];
  const float* gcn1_b   = (const float*)d_in[3];
  const float* gcn2_w   = (const float*)d_in[4];
  const float* gcn2_b   = (const float*)d_in[5];
  const float* gat1_w   = (const float*)d_in[6];
  const float* gat1_as  = (const float*)d_in[7];
  const float* gat1_ad  = (const float*)d_in[8];
  const float* gat1_b   = (const float*)d_in[9];
  const float* gat2_w   = (const float*)d_in[10];
  const float* gat2_as  = (const float*)d_in[11];
  const float* gat2_ad  = (const float*)d_in[12];
  const float* gat2_b   = (const float*)d_in[13];
  const float* sage1_wl = (const float*)d_in[14];
  const float* sage1_bl = (const float*)d_in[15];
  const float* sage1_wr = (const float*)d_in[16];
  const float* sage2_wl = (const float*)d_in[17];
  const float* sage2_bl = (const float*)d_in[18];
  const float* sage2_wr = (const float*)d_in[19];
  const float* bn_gcn_g = (const float*)d_in[20];
  const float* bn_gcn_b = (const float*)d_in[21];
  const float* bn_gat_g = (const float*)d_in[22];
  const float* bn_gat_b = (const float*)d_in[23];
  const float* bn_sage_g= (const float*)d_in[24];
  const float* bn_sage_b= (const float*)d_in[25];
  const float* fc1_w    = (const float*)d_in[26];
  const float* fc1_b    = (const float*)d_in[27];
  const float* fc2_w    = (const float*)d_in[28];
  const float* fc2_b    = (const float*)d_in[29];
  float* out = (float*)d_out;

  const int N = in_sizes[0] / 128;
  const int E = in_sizes[1] / 2;
  const int* src = ei;
  const int* dst = ei + E;
  const int nb = (N + 1023) / 1024;

  char* ws = (char*)d_ws;
  size_t off = 0;
  auto alloc = [&](size_t bytes) -> void* {
    void* p = ws + off;
    off = (off + bytes + 255) & ~(size_t)255;
    return p;
  };
  int*   deg   = (int*)  alloc((size_t)N * 4);
  int*   rowp  = (int*)  alloc((size_t)(N + 1) * 4);
  int*   fill  = (int*)  alloc((size_t)N * 4);
  int*   colv  = (int*)  alloc((size_t)E * 4);
  int*   dstv  = (int*)  alloc((size_t)E * 4);
  int*   bsum  = (int*)  alloc(64 * 4);
  float* dinv  = (float*)alloc((size_t)N * 4);
  float* sdinv = (float*)alloc((size_t)N * 4);
  float* as1   = (float*)alloc((size_t)N * 4 * 4);
  float* ad1   = (float*)alloc((size_t)N * 4 * 4);
  float* as2   = (float*)alloc((size_t)N * 4);
  float* ad2   = (float*)alloc((size_t)N * 4);
  float* w4    = (float*)alloc((size_t)E * 4 * 4);
  float* w1    = (float*)alloc((size_t)E * 4);
  float* bnA   = (float*)alloc(128 * 4);
  float* bnB   = (float*)alloc(128 * 4);
  float* bnC   = (float*)alloc(128 * 4);
  unsigned short* xh    = (unsigned short*)alloc((size_t)N * 128 * 2);
  unsigned short* xl    = (unsigned short*)alloc((size_t)N * 128 * 2);
  unsigned short* gath  = (unsigned short*)alloc((size_t)N * 256 * 2);   // GAT1 out (ilv)
  unsigned short* oh    = (unsigned short*)alloc((size_t)N * 256 * 2);   // agg4 out (ilv)
  unsigned short* t1h   = (unsigned short*)alloc((size_t)N * 64 * 2);    // GAT2 GEMM out
  unsigned short* g1h   = (unsigned short*)alloc((size_t)N * 64 * 2);
  unsigned short* g2h   = (unsigned short*)alloc((size_t)N * 64 * 2);
  unsigned short* tg2h  = (unsigned short*)alloc((size_t)N * 64 * 2);
  unsigned short* aggXh = (unsigned short*)alloc((size_t)N * 128 * 2);
  unsigned short* s1h   = (unsigned short*)alloc((size_t)N * 64 * 2);
  unsigned short* aggSh = (unsigned short*)alloc((size_t)N * 64 * 2);
  unsigned short* cath  = (unsigned short*)alloc((size_t)N * 192 * 2);
  unsigned short* t1bf  = (unsigned short*)alloc((size_t)N * 64 * 2);
  // weights
  unsigned short* b320h = (unsigned short*)alloc((size_t)320 * 128 * 2); // gat1(256,col-perm) + gcn1(64)
  unsigned short* b320l = (unsigned short*)alloc((size_t)320 * 128 * 2);
  unsigned short* gcn2h = (unsigned short*)alloc((size_t)64 * 64 * 2);
  unsigned short* gcn2l = (unsigned short*)alloc((size_t)64 * 64 * 2);
  unsigned short* gat2h = (unsigned short*)alloc((size_t)64 * 256 * 2);
  unsigned short* gat2l = (unsigned short*)alloc((size_t)64 * 256 * 2);
  unsigned short* s1wlh = (unsigned short*)alloc((size_t)64 * 128 * 2);
  unsigned short* s1wll = (unsigned short*)alloc((size_t)64 * 128 * 2);
  unsigned short* s1wrh = (unsigned short*)alloc((size_t)64 * 128 * 2);
  unsigned short* s1wrl = (unsigned short*)alloc((size_t)64 * 128 * 2);
  unsigned short* s2wlh = (unsigned short*)alloc((size_t)64 * 64 * 2);
  unsigned short* s2wll = (unsigned short*)alloc((size_t)64 * 64 * 2);
  unsigned short* s2wrh = (unsigned short*)alloc((size_t)64 * 64 * 2);
  unsigned short* s2wrl = (unsigned short*)alloc((size_t)64 * 64 * 2);
  unsigned short* fwh   = (unsigned short*)alloc((size_t)64 * 192 * 2);
  unsigned short* fwl   = (unsigned short*)alloc((size_t)64 * 192 * 2);
  float* fb             = (float*)alloc(64 * 4);

  hipMemsetAsync(deg, 0, (size_t)N * 4, stream);
  hipMemsetAsync(fill, 0, (size_t)N * 4, stream);
  hipMemsetAsync(bnA, 0, 128 * 4, stream);
  hipMemsetAsync(bnB, 0, 128 * 4, stream);
  hipMemsetAsync(bnC, 0, 128 * 4, stream);

  // CSR by destination
  k_count <<<(E + 255) / 256, 256, 0, stream>>>(dst, deg, E);
  k_scan_a<<<nb, 256, 0, stream>>>(deg, bsum, N);
  k_scan_b<<<1, 64, 0, stream>>>(bsum, rowp, nb, N);
  k_scan_c<<<nb, 256, 0, stream>>>(deg, bsum, rowp, dinv, sdinv, N);
  k_scatter<<<(E + 255) / 256, 256, 0, stream>>>(src, dst, rowp, fill, colv, dstv, E);

  // weight splits + x split
  {
    WPack p;
    p.d[0] = {gat1_w, b320h, b320l, 128, 256, 2};                       // col-perm (head-ilv C)
    p.d[1] = {gcn1_w, b320h + 256 * 128, b320l + 256 * 128, 128, 64, 0};
    p.d[2] = {gat2_w, gat2h, gat2l, 256, 64, 1};                        // K-perm (ilv A)
    p.d[3] = {sage1_wl, s1wlh, s1wll, 128, 64, 0};
    p.d[4] = {sage1_wr, s1wrh, s1wrl, 128, 64, 0};
    p.d[5] = {sage2_wl, s2wlh, s2wll, 64, 64, 0};
    p.d[6] = {sage2_wr, s2wrh, s2wrl, 64, 64, 0};
    p.d[7] = {gcn2_w, gcn2h, gcn2l, 64, 64, 0};                         // FIX: gcn2 split restored
    dim3 g(32, 8);
    k_wsplit<<<g, 256, 0, stream>>>(p);
  }
  k_asplit<<<(N * 128 + 255) / 256, 256, 0, stream>>>(x, xh, xl, N * 128);

  const int gx = (N + 127) / 128;

  // ---- GAT1 + GCN1 fused GEMM (B = 320 cols) ----
  {
    dim3 g(gx, 5);
    k_gemm_mfma<<<g, 256, 0, stream>>>(xh, xl, b320h, b320l, nullptr,
                                       gath, 256, g1h, N, 128, 320, 0);
  }
  // ---- GAT branch ----
  k_gat_attn4<<<(N + 3) / 4, 256, 0, stream>>>(gath, gat1_as, gat1_ad, as1, ad1, N);
  k_edge_w4<<<(E + 255) / 256, 256, 0, stream>>>(colv, dstv, as1, ad1, w4, E);
  k_gat_agg4<<<(N + 3) / 4, 256, 0, stream>>>(gath, rowp, colv, w4, as1, ad1, gat1_b, oh, N);
  {
    dim3 g(gx, 1);
    k_gemm_mfma<<<g, 256, 0, stream>>>(oh, nullptr, gat2h, gat2l, nullptr,
                                       t1h, 64, nullptr, N, 256, 64, 0);
  }
  k_gat_attn1<<<(N + 3) / 4, 256, 0, stream>>>(t1h, gat2_as, gat2_ad, as2, ad2, N);
  k_edge_w1<<<(E + 255) / 256, 256, 0, stream>>>(colv, dstv, as2, ad2, w1, E);
  k_gat_agg1<<<(N + 3) / 4, 256, 0, stream>>>(t1h, rowp, colv, w1, as2, ad2, gat2_b, cath, 192, 64, N);

  // ---- GCN branch ----
  k_gcn_agg<<<(N + 3) / 4, 256, 0, stream>>>(g1h, rowp, colv, dinv, gcn1_b, g2h, 64, 0, N);
  {
    dim3 g(gx, 1);
    k_gemm_mfma<<<g, 256, 0, stream>>>(g2h, nullptr, gcn2h, gcn2l, nullptr,
                                       tg2h, 64, nullptr, N, 64, 64, 0);
  }
  k_gcn_agg<<<(N + 3) / 4, 256, 0, stream>>>(tg2h, rowp, colv, dinv, gcn2_b, cath, 192, 0, N);

  // ---- SAGE branch ----
  k_sage_agg128<<<(N + 3) / 4, 256, 0, stream>>>(xh, rowp, colv, sdinv, aggXh, N);
  k_gemm_dual<<<gx, 256, 0, stream>>>(aggXh, s1wlh, s1wll, 128,
                                      xh, xl, s1wrh, s1wrl, 128,
                                      sage1_bl, s1h, 64, 0, N);
  k_sage_agg64<<<(N + 3) / 4, 256, 0, stream>>>(s1h, rowp, colv, sdinv, aggSh, N);
  k_gemm_dual<<<gx, 256, 0, stream>>>(aggSh, s2wlh, s2wll, 64,
                                      s1h, nullptr, s2wrh, s2wrl, 64,
                                      sage2_bl, cath, 192, 128, N);

  // ---- BN stats + fold into fc1 ----
  k_bn_stats_b<<<128, 256, 0, stream>>>(cath, bnB, N, 192, 0);    // gcn
  k_bn_stats_b<<<128, 256, 0, stream>>>(cath, bnA, N, 192, 64);   // gat
  k_bn_stats_b<<<128, 256, 0, stream>>>(cath, bnC, N, 192, 128);  // sage
  k_bnfold<<<1, 256, 0, stream>>>(bnB, bnA, bnC,
                                  bn_gcn_g, bn_gcn_b, bn_gat_g, bn_gat_b, bn_sage_g, bn_sage_b,
                                  fc1_w, fc1_b, (float)N, fwh, fwl, fb);

  // ---- FC head ----
  {
    dim3 g(gx, 1);
    k_gemm_mfma<<<g, 256, 0, stream>>>(cath, nullptr, fwh, fwl, fb,
                                       t1bf, 64, nullptr, N, 192, 64, 1);
  }
  k_fc2<<<(N + 3) / 4, 256, 0, stream>>>(t1bf, fc2_w, fc2_b, out, N);
}

// Round 8
// 656.337 us; speedup vs baseline: 1.9087x; 1.2147x over previous
//
#include <hip/hip_runtime.h>
#include <math.h>

#define NEG_SLOPE 0.2f
#define BN_EPS 1e-5f

typedef short short8 __attribute__((ext_vector_type(8)));
typedef float floatx16 __attribute__((ext_vector_type(16)));

__device__ __forceinline__ float d_leaky(float x){ return x > 0.f ? x : NEG_SLOPE * x; }
__device__ __forceinline__ float d_elu(float x){ return x > 0.f ? x : expm1f(x); }

__device__ __forceinline__ unsigned short f2bf_rne(float f){
  unsigned int u = __float_as_uint(f);
  unsigned int r = (u + 0x7fffu + ((u >> 16) & 1u)) >> 16;
  return (unsigned short)r;
}
__device__ __forceinline__ float bf2f(unsigned short h){ return __uint_as_float((unsigned int)h << 16); }
__device__ __forceinline__ float2 bf2x(unsigned int u){
  float2 r;
  r.x = __uint_as_float(u << 16);
  r.y = __uint_as_float(u & 0xffff0000u);
  return r;
}

__device__ __forceinline__ float wave_sum(float v){
  #pragma unroll
  for (int off = 32; off > 0; off >>= 1) v += __shfl_xor(v, off, 64);
  return v;
}
__device__ __forceinline__ int wave_scan_incl(int v, int lane){
  #pragma unroll
  for (int off = 1; off < 64; off <<= 1){
    int u = __shfl_up(v, off, 64);
    if (lane >= off) v += u;
  }
  return v;
}

// ---------------- CSR build ----------------
__global__ void k_count(const int* __restrict__ dst, int* __restrict__ deg, int E){
  int e = blockIdx.x * blockDim.x + threadIdx.x;
  if (e < E) atomicAdd(&deg[dst[e]], 1);
}

__global__ __launch_bounds__(256) void k_scan_a(const int* __restrict__ deg, int* __restrict__ bsum, int n){
  int t = threadIdx.x;
  int base = blockIdx.x * 1024 + t * 4;
  int d0=0,d1=0,d2=0,d3=0;
  if (base + 3 < n){ int4 v = *(const int4*)(deg + base); d0=v.x; d1=v.y; d2=v.z; d3=v.w; }
  else {
    if (base   < n) d0 = deg[base];
    if (base+1 < n) d1 = deg[base+1];
    if (base+2 < n) d2 = deg[base+2];
    if (base+3 < n) d3 = deg[base+3];
  }
  int s = d0+d1+d2+d3;
  __shared__ int wsm[4];
  int lane = t & 63, w = t >> 6;
  int incl = wave_scan_incl(s, lane);
  if (lane == 63) wsm[w] = incl;
  __syncthreads();
  if (t == 0) bsum[blockIdx.x] = wsm[0]+wsm[1]+wsm[2]+wsm[3];
}

__global__ void k_scan_b(int* __restrict__ bsum, int* __restrict__ rowp, int nb, int n){
  int t = threadIdx.x;  // 64 threads, nb <= 64
  int v = (t < nb) ? bsum[t] : 0;
  int incl = wave_scan_incl(v, t);
  if (t < nb) bsum[t] = incl - v;
  if (t == 63) rowp[n] = incl;
}

__global__ __launch_bounds__(256) void k_scan_c(const int* __restrict__ deg, const int* __restrict__ bsum,
                                                int* __restrict__ rowp, float* __restrict__ dinv,
                                                float* __restrict__ sdinv, int n){
  int t = threadIdx.x;
  int base = blockIdx.x * 1024 + t * 4;
  int d0=0,d1=0,d2=0,d3=0;
  if (base + 3 < n){ int4 v = *(const int4*)(deg + base); d0=v.x; d1=v.y; d2=v.z; d3=v.w; }
  else {
    if (base   < n) d0 = deg[base];
    if (base+1 < n) d1 = deg[base+1];
    if (base+2 < n) d2 = deg[base+2];
    if (base+3 < n) d3 = deg[base+3];
  }
  int s = d0+d1+d2+d3;
  __shared__ int wsm[4];
  int lane = t & 63, w = t >> 6;
  int incl = wave_scan_incl(s, lane);
  if (lane == 63) wsm[w] = incl;
  __syncthreads();
  int woff = 0;
  #pragma unroll
  for (int j = 0; j < 4; j++) if (j < w) woff += wsm[j];
  int r = bsum[blockIdx.x] + woff + incl - s;
  int dd[4] = {d0,d1,d2,d3};
  #pragma unroll
  for (int j = 0; j < 4; j++){
    int i = base + j;
    if (i < n){
      rowp[i] = r;
      dinv[i] = rsqrtf((float)(dd[j] + 1));
      sdinv[i] = 1.0f / fmaxf((float)dd[j], 1.0f);
    }
    r += dd[j];
  }
}

__global__ void k_scatter(const int* __restrict__ src, const int* __restrict__ dst,
                          const int* __restrict__ rowp, int* __restrict__ fill,
                          int* __restrict__ colv, int* __restrict__ dstv, int E){
  int e = blockIdx.x * blockDim.x + threadIdx.x;
  if (e < E){
    int d = dst[e];
    int pos = rowp[d] + atomicAdd(&fill[d], 1);
    colv[pos] = src[e];
    dstv[pos] = d;
  }
}

// ---------------- split fp32 -> bf16 hi/lo ----------------
__global__ void k_asplit(const float* __restrict__ a, unsigned short* __restrict__ h,
                         unsigned short* __restrict__ l, int total){
  int i = blockIdx.x * blockDim.x + threadIdx.x;
  if (i < total){
    float v = a[i];
    unsigned short hh = f2bf_rne(v);
    h[i] = hh;
    l[i] = f2bf_rne(v - bf2f(hh));
  }
}

// ---------------- weight transpose + split ----------------
// perm: 0 none; 1 = K-permute (interleaved-A GEMM, gat2); 2 = col-permute (head-interleave C, gat1)
struct WDesc { const float* w; unsigned short* th; unsigned short* tl; int K; int Nc; int perm; };
struct WPack { WDesc d[8]; };
__global__ void k_wsplit(WPack p){
  WDesc w = p.d[blockIdx.y];
  int total = w.K * w.Nc;
  for (int i = blockIdx.x * blockDim.x + threadIdx.x; i < total; i += gridDim.x * blockDim.x){
    int k = i / w.Nc, n = i % w.Nc;
    int kd = (w.perm == 1) ? ((k & 63) * 4 + (k >> 6)) : k;
    int nd = (w.perm == 2) ? (((n & 63) << 2) | (n >> 6)) : n;
    float v = w.w[i];
    unsigned short h = f2bf_rne(v);
    w.th[(size_t)nd * w.K + kd] = h;
    w.tl[(size_t)nd * w.K + kd] = f2bf_rne(v - bf2f(h));
  }
}

// ---------------- GEMM term helper ----------------
__device__ __forceinline__ void gemm_term(floatx16& acc0, floatx16& acc1,
    const unsigned short* __restrict__ Ah, const unsigned short* __restrict__ Al,
    const unsigned short* __restrict__ Bh, const unsigned short* __restrict__ Bl,
    int K, int lda, int arow, int lr, int ko8){
  const unsigned short* ap  = Ah + (size_t)arow * lda + ko8;
  const unsigned short* alp = Al ? Al + (size_t)arow * lda + ko8 : nullptr;
  const unsigned short* bh0 = Bh + (size_t)lr * K + ko8;
  const unsigned short* bl0 = Bl + (size_t)lr * K + ko8;
  const unsigned short* bh1 = bh0 + (size_t)32 * K;
  const unsigned short* bl1 = bl0 + (size_t)32 * K;
  for (int k0 = 0; k0 < K; k0 += 16){
    short8 a  = *(const short8*)(ap + k0);
    short8 h0 = *(const short8*)(bh0 + k0);
    short8 l0 = *(const short8*)(bl0 + k0);
    short8 h1 = *(const short8*)(bh1 + k0);
    short8 l1 = *(const short8*)(bl1 + k0);
    if (alp){
      short8 a2 = *(const short8*)(alp + k0);
      acc0 = __builtin_amdgcn_mfma_f32_32x32x16_bf16(a2, h0, acc0, 0, 0, 0);
      acc1 = __builtin_amdgcn_mfma_f32_32x32x16_bf16(a2, h1, acc1, 0, 0, 0);
    }
    acc0 = __builtin_amdgcn_mfma_f32_32x32x16_bf16(a, l0, acc0, 0, 0, 0);
    acc0 = __builtin_amdgcn_mfma_f32_32x32x16_bf16(a, h0, acc0, 0, 0, 0);
    acc1 = __builtin_amdgcn_mfma_f32_32x32x16_bf16(a, l1, acc1, 0, 0, 0);
    acc1 = __builtin_amdgcn_mfma_f32_32x32x16_bf16(a, h1, acc1, 0, 0, 0);
  }
}

// ---------------- batched MFMA GEMM: out = act(A1@B1 [+A2@B2] + bias), Nc=64, bf16 out ----
struct BDesc {
  const unsigned short *A1h, *A1l, *B1h, *B1l;
  const unsigned short *A2h, *A2l, *B2h, *B2l;
  int K1, lda1, K2, lda2;
  const float* bias;
  unsigned short* out; int ldc, coloff, act;
};
struct BPack { BDesc d[3]; };
__global__ __launch_bounds__(256) void k_gemm_b(BPack p, int M){
  BDesc d = p.d[blockIdx.y];
  int wave = threadIdx.x >> 6, lane = threadIdx.x & 63;
  int m0 = blockIdx.x * 128 + wave * 32;
  int lr = lane & 31;
  int ko8 = (lane >> 5) * 8;
  floatx16 acc0 = {0,0,0,0,0,0,0,0,0,0,0,0,0,0,0,0};
  floatx16 acc1 = {0,0,0,0,0,0,0,0,0,0,0,0,0,0,0,0};
  int arow = m0 + lr; if (arow >= M) arow = M - 1;
  gemm_term(acc0, acc1, d.A1h, d.A1l, d.B1h, d.B1l, d.K1, d.lda1, arow, lr, ko8);
  if (d.K2) gemm_term(acc0, acc1, d.A2h, d.A2l, d.B2h, d.B2l, d.K2, d.lda2, arow, lr, ko8);
  int col0 = lr, col1 = lr + 32;
  float bias0 = d.bias ? d.bias[col0] : 0.f;
  float bias1 = d.bias ? d.bias[col1] : 0.f;
  int rbase = m0 + 4 * (lane >> 5);
  #pragma unroll
  for (int reg = 0; reg < 16; reg++){
    int row = rbase + (reg & 3) + 8 * (reg >> 2);
    if (row >= M) continue;
    float v0 = acc0[reg] + bias0;
    float v1 = acc1[reg] + bias1;
    if (d.act){ v0 = fmaxf(v0, 0.f); v1 = fmaxf(v1, 0.f); }
    d.out[(size_t)row * d.ldc + d.coloff + col0] = f2bf_rne(v0);
    d.out[(size_t)row * d.ldc + d.coloff + col1] = f2bf_rne(v1);
  }
}

// ---------------- GEMM320: C = x @ [gat1|gcn1], cols<256 -> gath (ld 256), else g1h (ld 64) ----
__global__ __launch_bounds__(256) void k_gemm320(
    const unsigned short* __restrict__ Ah, const unsigned short* __restrict__ Al,
    const unsigned short* __restrict__ Bh, const unsigned short* __restrict__ Bl,
    unsigned short* __restrict__ C1, unsigned short* __restrict__ C2, int M)
{
  const int K = 128;
  int wave = threadIdx.x >> 6, lane = threadIdx.x & 63;
  int m0 = blockIdx.x * 128 + wave * 32;
  int n0 = blockIdx.y * 64;
  int lr = lane & 31;
  int ko8 = (lane >> 5) * 8;
  floatx16 acc0 = {0,0,0,0,0,0,0,0,0,0,0,0,0,0,0,0};
  floatx16 acc1 = {0,0,0,0,0,0,0,0,0,0,0,0,0,0,0,0};
  int arow = m0 + lr; if (arow >= M) arow = M - 1;
  const unsigned short* ap_h = Ah + (size_t)arow * K + ko8;
  const unsigned short* ap_l = Al + (size_t)arow * K + ko8;
  const unsigned short* bp_h0 = Bh + (size_t)(n0 + lr) * K + ko8;
  const unsigned short* bp_l0 = Bl + (size_t)(n0 + lr) * K + ko8;
  const unsigned short* bp_h1 = bp_h0 + (size_t)32 * K;
  const unsigned short* bp_l1 = bp_l0 + (size_t)32 * K;
  for (int k0 = 0; k0 < K; k0 += 16){
    short8 a_h  = *(const short8*)(ap_h + k0);
    short8 a_l  = *(const short8*)(ap_l + k0);
    short8 b_h0 = *(const short8*)(bp_h0 + k0);
    short8 b_l0 = *(const short8*)(bp_l0 + k0);
    short8 b_h1 = *(const short8*)(bp_h1 + k0);
    short8 b_l1 = *(const short8*)(bp_l1 + k0);
    acc0 = __builtin_amdgcn_mfma_f32_32x32x16_bf16(a_l, b_h0, acc0, 0, 0, 0);
    acc0 = __builtin_amdgcn_mfma_f32_32x32x16_bf16(a_h, b_l0, acc0, 0, 0, 0);
    acc0 = __builtin_amdgcn_mfma_f32_32x32x16_bf16(a_h, b_h0, acc0, 0, 0, 0);
    acc1 = __builtin_amdgcn_mfma_f32_32x32x16_bf16(a_l, b_h1, acc1, 0, 0, 0);
    acc1 = __builtin_amdgcn_mfma_f32_32x32x16_bf16(a_h, b_l1, acc1, 0, 0, 0);
    acc1 = __builtin_amdgcn_mfma_f32_32x32x16_bf16(a_h, b_h1, acc1, 0, 0, 0);
  }
  int col0 = n0 + lr, col1 = col0 + 32;
  unsigned short* Cp; int ld, c0, c1;
  if (col0 >= 256){ Cp = C2; ld = 64; c0 = col0 - 256; c1 = col1 - 256; }
  else { Cp = C1; ld = 256; c0 = col0; c1 = col1; }
  int rbase = m0 + 4 * (lane >> 5);
  #pragma unroll
  for (int reg = 0; reg < 16; reg++){
    int row = rbase + (reg & 3) + 8 * (reg >> 2);
    if (row >= M) continue;
    Cp[(size_t)row * ld + c0] = f2bf_rne(acc0[reg]);
    Cp[(size_t)row * ld + c1] = f2bf_rne(acc1[reg]);
  }
}

// ---------------- GAT1 attention coeffs (interleaved bf16 h) ----------------
__global__ __launch_bounds__(256) void k_gat_attn4(
    const unsigned short* __restrict__ h, const float* __restrict__ asrc,
    const float* __restrict__ adst, float* __restrict__ a_s, float* __restrict__ a_d, int n){
  int node = blockIdx.x * 4 + (threadIdx.x >> 6);
  int c = threadIdx.x & 63;
  if (node >= n) return;
  uint2 u = *(const uint2*)(h + (size_t)node * 256 + c * 4);
  float2 p0 = bf2x(u.x), p1 = bf2x(u.y);
  float s0 = wave_sum(p0.x * asrc[c]);
  float s1 = wave_sum(p0.y * asrc[64 + c]);
  float s2 = wave_sum(p1.x * asrc[128 + c]);
  float s3 = wave_sum(p1.y * asrc[192 + c]);
  float d0 = wave_sum(p0.x * adst[c]);
  float d1 = wave_sum(p0.y * adst[64 + c]);
  float d2 = wave_sum(p1.x * adst[128 + c]);
  float d3 = wave_sum(p1.y * adst[192 + c]);
  if (c == 0){
    *(float4*)(a_s + (size_t)node * 4) = make_float4(s0, s1, s2, s3);
    *(float4*)(a_d + (size_t)node * 4) = make_float4(d0, d1, d2, d3);
  }
}

// ---------------- GAT2 attention coeffs (bf16 h, strided) ----------------
__global__ __launch_bounds__(256) void k_gat_attn1(
    const unsigned short* __restrict__ h, int ld, const float* __restrict__ asrc,
    const float* __restrict__ adst, float* __restrict__ a_s, float* __restrict__ a_d, int n){
  int node = blockIdx.x * 4 + (threadIdx.x >> 6);
  int c = threadIdx.x & 63;
  if (node >= n) return;
  float v = bf2f(h[(size_t)node * ld + c]);
  float s = wave_sum(v * asrc[c]);
  float d = wave_sum(v * adst[c]);
  if (c == 0){ a_s[node] = s; a_d[node] = d; }
}

// ---------------- per-edge softmax numerators ----------------
__global__ void k_edge_w4(const int* __restrict__ colv, const int* __restrict__ dstv,
                          const float* __restrict__ a_s, const float* __restrict__ a_d,
                          float* __restrict__ w4, int E){
  int i = blockIdx.x * blockDim.x + threadIdx.x;
  if (i >= E) return;
  float4 s4 = *(const float4*)(a_s + (size_t)colv[i] * 4);
  float4 d4 = *(const float4*)(a_d + (size_t)dstv[i] * 4);
  float4 w;
  w.x = __expf(d_leaky(s4.x + d4.x));
  w.y = __expf(d_leaky(s4.y + d4.y));
  w.z = __expf(d_leaky(s4.z + d4.z));
  w.w = __expf(d_leaky(s4.w + d4.w));
  *(float4*)(w4 + (size_t)i * 4) = w;
}

__global__ void k_edge_w1(const int* __restrict__ colv, const int* __restrict__ dstv,
                          const float* __restrict__ a_s, const float* __restrict__ a_d,
                          float* __restrict__ w1, int E){
  int i = blockIdx.x * blockDim.x + threadIdx.x;
  if (i >= E) return;
  w1[i] = __expf(d_leaky(a_s[colv[i]] + a_d[dstv[i]]));
}

// ---------------- GAT1 aggregation: interleaved bf16, wave/node, 4 heads, bf16 out ----------------
__global__ __launch_bounds__(256) void k_gat_agg4(
    const unsigned short* __restrict__ h, const int* __restrict__ rowp,
    const int* __restrict__ colv, const float* __restrict__ w4,
    const float* __restrict__ a_s, const float* __restrict__ a_d,
    const float* __restrict__ bias, unsigned short* __restrict__ outh, int n){
  int node = blockIdx.x * 4 + (threadIdx.x >> 6);
  int c = threadIdx.x & 63;
  if (node >= n) return;
  float4 asn = *(const float4*)(a_s + (size_t)node * 4);
  float4 adn = *(const float4*)(a_d + (size_t)node * 4);
  float ws0 = __expf(d_leaky(asn.x + adn.x));
  float ws1 = __expf(d_leaky(asn.y + adn.y));
  float ws2 = __expf(d_leaky(asn.z + adn.z));
  float ws3 = __expf(d_leaky(asn.w + adn.w));
  uint2 su = *(const uint2*)(h + (size_t)node * 256 + c * 4);
  float2 sp0 = bf2x(su.x), sp1 = bf2x(su.y);
  float den0 = ws0, den1 = ws1, den2 = ws2, den3 = ws3;
  float acc0 = ws0 * sp0.x, acc1 = ws1 * sp0.y, acc2 = ws2 * sp1.x, acc3 = ws3 * sp1.y;
  int b = rowp[node], e = rowp[node + 1];
  int i = b;
  for (; i + 8 <= e; i += 8){
    int s[8]; float4 w[8]; uint2 hv[8];
    #pragma unroll
    for (int j = 0; j < 8; j++) s[j] = colv[i + j];
    #pragma unroll
    for (int j = 0; j < 8; j++) w[j] = *(const float4*)(w4 + (size_t)(i + j) * 4);
    #pragma unroll
    for (int j = 0; j < 8; j++) hv[j] = *(const uint2*)(h + (size_t)s[j] * 256 + c * 4);
    #pragma unroll
    for (int j = 0; j < 8; j++){
      float2 a = bf2x(hv[j].x), bb = bf2x(hv[j].y);
      den0 += w[j].x; den1 += w[j].y; den2 += w[j].z; den3 += w[j].w;
      acc0 += w[j].x * a.x;  acc1 += w[j].y * a.y;
      acc2 += w[j].z * bb.x; acc3 += w[j].w * bb.y;
    }
  }
  for (; i < e; i++){
    int s = colv[i];
    float4 w = *(const float4*)(w4 + (size_t)i * 4);
    uint2 hv = *(const uint2*)(h + (size_t)s * 256 + c * 4);
    float2 a = bf2x(hv.x), bb = bf2x(hv.y);
    den0 += w.x; den1 += w.y; den2 += w.z; den3 += w.w;
    acc0 += w.x * a.x;  acc1 += w.y * a.y;
    acc2 += w.z * bb.x; acc3 += w.w * bb.y;
  }
  float v0 = d_elu(acc0 / (den0 + 1e-16f) + bias[c]);
  float v1 = d_elu(acc1 / (den1 + 1e-16f) + bias[64 + c]);
  float v2 = d_elu(acc2 / (den2 + 1e-16f) + bias[128 + c]);
  float v3 = d_elu(acc3 / (den3 + 1e-16f) + bias[192 + c]);
  uint2 oh;
  oh.x = (unsigned int)f2bf_rne(v0) | ((unsigned int)f2bf_rne(v1) << 16);
  oh.y = (unsigned int)f2bf_rne(v2) | ((unsigned int)f2bf_rne(v3) << 16);
  *(uint2*)(outh + (size_t)node * 256 + c * 4) = oh;
}

// ---------------- F1: fused GCN1-agg (g1h) + SAGE-agg (xh), wave/node ----------------
__global__ __launch_bounds__(256) void k_f1(
    const unsigned short* __restrict__ xh,   // [N][128]
    const unsigned short* __restrict__ g1h,  // [N][64]
    const int* __restrict__ rowp, const int* __restrict__ colv,
    const float* __restrict__ dinv, const float* __restrict__ sdinv,
    const float* __restrict__ gcn1_b,
    unsigned short* __restrict__ aggXh,      // [N][128]
    unsigned short* __restrict__ g2h,        // [N][64]
    int n){
  int node = blockIdx.x * 4 + (threadIdx.x >> 6);
  int c = threadIdx.x & 63;
  if (node >= n) return;
  float di = dinv[node];
  float gacc = di * bf2f(g1h[(size_t)node * 64 + c]);
  float sx0 = 0.f, sx1 = 0.f;
  int b = rowp[node], e = rowp[node + 1];
  int i = b;
  for (; i + 8 <= e; i += 8){
    int s[8]; float w[8]; unsigned short hg[8]; unsigned int hx[8];
    #pragma unroll
    for (int j = 0; j < 8; j++) s[j] = colv[i + j];
    #pragma unroll
    for (int j = 0; j < 8; j++) w[j] = dinv[s[j]];
    #pragma unroll
    for (int j = 0; j < 8; j++) hg[j] = g1h[(size_t)s[j] * 64 + c];
    #pragma unroll
    for (int j = 0; j < 8; j++) hx[j] = *(const unsigned int*)(xh + (size_t)s[j] * 128 + c * 2);
    #pragma unroll
    for (int j = 0; j < 8; j++){
      gacc += w[j] * bf2f(hg[j]);
      float2 p = bf2x(hx[j]); sx0 += p.x; sx1 += p.y;
    }
  }
  for (; i < e; i++){
    int s = colv[i];
    gacc += dinv[s] * bf2f(g1h[(size_t)s * 64 + c]);
    float2 p = bf2x(*(const unsigned int*)(xh + (size_t)s * 128 + c * 2));
    sx0 += p.x; sx1 += p.y;
  }
  g2h[(size_t)node * 64 + c] = f2bf_rne(fmaxf(di * gacc + gcn1_b[c], 0.f));
  float sd = sdinv[node];
  *(unsigned int*)(aggXh + (size_t)node * 128 + c * 2) =
      (unsigned int)f2bf_rne(sx0 * sd) | ((unsigned int)f2bf_rne(sx1 * sd) << 16);
}

// ---------------- F2: fused GAT2-agg + GCN2-agg + SAGE-s1-agg over m192 ----------------
// m192 cols: 0-63 = t1 (GAT2 GEMM), 64-127 = tg2 (GCN2 GEMM), 128-191 = s1 (SAGE1 GEMM)
__global__ __launch_bounds__(256) void k_f2(
    const unsigned short* __restrict__ m192,
    const int* __restrict__ rowp, const int* __restrict__ colv,
    const float* __restrict__ w1, const float* __restrict__ a_s, const float* __restrict__ a_d,
    const float* __restrict__ dinv, const float* __restrict__ sdinv,
    const float* __restrict__ gat2_b, const float* __restrict__ gcn2_b,
    unsigned short* __restrict__ cat,   // [N][192], writes cols 0-127
    unsigned short* __restrict__ aggSh, // [N][64]
    int n){
  int node = blockIdx.x * 4 + (threadIdx.x >> 6);
  int c = threadIdx.x & 63;
  if (node >= n) return;
  float di = dinv[node];
  const unsigned short* srow = m192 + (size_t)node * 192;
  float tden = __expf(d_leaky(a_s[node] + a_d[node]));
  float tacc = tden * bf2f(srow[c]);
  float gacc = di * bf2f(srow[64 + c]);
  float sacc = 0.f;
  int b = rowp[node], e = rowp[node + 1];
  int i = b;
  for (; i + 8 <= e; i += 8){
    int s[8]; float w[8]; unsigned short ht[8], hg[8], hs[8];
    #pragma unroll
    for (int j = 0; j < 8; j++) s[j] = colv[i + j];
    #pragma unroll
    for (int j = 0; j < 8; j++) w[j] = w1[i + j];
    #pragma unroll
    for (int j = 0; j < 8; j++){
      const unsigned short* r = m192 + (size_t)s[j] * 192;
      ht[j] = r[c]; hg[j] = r[64 + c]; hs[j] = r[128 + c];
    }
    #pragma unroll
    for (int j = 0; j < 8; j++){
      tden += w[j]; tacc += w[j] * bf2f(ht[j]);
      gacc += dinv[s[j]] * bf2f(hg[j]);
      sacc += bf2f(hs[j]);
    }
  }
  for (; i < e; i++){
    int s = colv[i];
    float w = w1[i];
    const unsigned short* r = m192 + (size_t)s * 192;
    tden += w; tacc += w * bf2f(r[c]);
    gacc += dinv[s] * bf2f(r[64 + c]);
    sacc += bf2f(r[128 + c]);
  }
  cat[(size_t)node * 192 + 64 + c] = f2bf_rne(d_elu(tacc / (tden + 1e-16f) + gat2_b[c]));
  cat[(size_t)node * 192 + c] = f2bf_rne(fmaxf(di * gacc + gcn2_b[c], 0.f));
  aggSh[(size_t)node * 64 + c] = f2bf_rne(sacc * sdinv[node]);
}

// ---------------- BN stats, one launch over 3 segments ----------------
__global__ void k_bn_stats3(const unsigned short* __restrict__ x,
                            float* __restrict__ bnGCN, float* __restrict__ bnGAT,
                            float* __restrict__ bnSAGE, int n){
  int seg = blockIdx.y;
  float* sums = (seg == 0) ? bnGCN : (seg == 1) ? bnGAT : bnSAGE;
  int co = seg * 64;
  int c = threadIdx.x & 63;
  int rl = threadIdx.x >> 6;
  float s = 0.f, q = 0.f;
  for (int r = blockIdx.x * 4 + rl; r < n; r += gridDim.x * 4){
    float v = bf2f(x[(size_t)r * 192 + co + c]);
    s += v; q += v * v;
  }
  __shared__ float ls[4][64], lq[4][64];
  ls[rl][c] = s; lq[rl][c] = q;
  __syncthreads();
  if (rl == 0){
    s = ls[0][c] + ls[1][c] + ls[2][c] + ls[3][c];
    q = lq[0][c] + lq[1][c] + lq[2][c] + lq[3][c];
    atomicAdd(&sums[c], s);
    atomicAdd(&sums[64 + c], q);
  }
}

// ---------------- fold BN into fc1 weights ----------------
__global__ __launch_bounds__(256) void k_bnfold(
    const float* __restrict__ bnGCN, const float* __restrict__ bnGAT, const float* __restrict__ bnSAGE,
    const float* __restrict__ gg, const float* __restrict__ gb,
    const float* __restrict__ ag, const float* __restrict__ ab,
    const float* __restrict__ sg, const float* __restrict__ sb,
    const float* __restrict__ w, const float* __restrict__ wb, float nf,
    unsigned short* __restrict__ fwh, unsigned short* __restrict__ fwl, float* __restrict__ fb)
{
  int tid = threadIdx.x;
  auto st = [&](int c, float& s, float& t){
    int cc = c & 63;
    const float *bn, *g, *b;
    if (c < 64){ bn = bnGCN; g = gg; b = gb; }
    else if (c < 128){ bn = bnGAT; g = ag; b = ab; }
    else { bn = bnSAGE; g = sg; b = sb; }
    float m = bn[cc] / nf;
    float var = bn[64 + cc] / nf - m * m;
    float inv = rsqrtf(var + BN_EPS);
    s = inv * g[cc];
    t = b[cc] - m * inv * g[cc];
  };
  if (tid < 64){
    float acc = wb[tid];
    for (int c = 0; c < 192; c++){
      float s, t; st(c, s, t);
      acc += t * w[c * 64 + tid];
    }
    fb[tid] = acc;
  }
  for (int i = tid; i < 192 * 64; i += 256){
    int c = i >> 6, nn = i & 63;
    float s, t; st(c, s, t);
    float v = s * w[i];
    unsigned short hh = f2bf_rne(v);
    fwh[nn * 192 + c] = hh;
    fwl[nn * 192 + c] = f2bf_rne(v - bf2f(hh));
  }
}

// ---------------- final tiny FC (64 -> 2), bf16 in ----------------
__global__ void k_fc2(const unsigned short* __restrict__ h, const float* __restrict__ w,
                      const float* __restrict__ b, float* __restrict__ out, int n){
  int node = blockIdx.x * 4 + (threadIdx.x >> 6);
  int lane = threadIdx.x & 63;
  if (node >= n) return;
  float v = bf2f(h[(size_t)node * 64 + lane]);
  float p0 = wave_sum(v * w[lane * 2 + 0]);
  float p1 = wave_sum(v * w[lane * 2 + 1]);
  if (lane == 0){
    out[node * 2 + 0] = p0 + b[0];
    out[node * 2 + 1] = p1 + b[1];
  }
}

extern "C" void kernel_launch(void* const* d_in, const int* in_sizes, int n_in,
                              void* d_out, int out_size, void* d_ws, size_t ws_size,
                              hipStream_t stream){
  (void)n_in; (void)out_size; (void)ws_size;
  const float* x        = (const float*)d_in[0];
  const int*   ei       = (const int*)  d_in[1];
  const float* gcn1_w   = (const float*)d_in[2];
  const float* gcn1_b   = (const float*)d_in[3];
  const float* gcn2_w   = (const float*)d_in[4];
  const float* gcn2_b   = (const float*)d_in[5];
  const float* gat1_w   = (const float*)d_in[6];
  const float* gat1_as  = (const float*)d_in[7];
  const float* gat1_ad  = (const float*)d_in[8];
  const float* gat1_b   = (const float*)d_in[9];
  const float* gat2_w   = (const float*)d_in[10];
  const float* gat2_as  = (const float*)d_in[11];
  const float* gat2_ad  = (const float*)d_in[12];
  const float* gat2_b   = (const float*)d_in[13];
  const float* sage1_wl = (const float*)d_in[14];
  const float* sage1_bl = (const float*)d_in[15];
  const float* sage1_wr = (const float*)d_in[16];
  const float* sage2_wl = (const float*)d_in[17];
  const float* sage2_bl = (const float*)d_in[18];
  const float* sage2_wr = (const float*)d_in[19];
  const float* bn_gcn_g = (const float*)d_in[20];
  const float* bn_gcn_b = (const float*)d_in[21];
  const float* bn_gat_g = (const float*)d_in[22];
  const float* bn_gat_b = (const float*)d_in[23];
  const float* bn_sage_g= (const float*)d_in[24];
  const float* bn_sage_b= (const float*)d_in[25];
  const float* fc1_w    = (const float*)d_in[26];
  const float* fc1_b    = (const float*)d_in[27];
  const float* fc2_w    = (const float*)d_in[28];
  const float* fc2_b    = (const float*)d_in[29];
  float* out = (float*)d_out;

  const int N = in_sizes[0] / 128;
  const int E = in_sizes[1] / 2;
  const int* src = ei;
  const int* dst = ei + E;
  const int nb = (N + 1023) / 1024;

  char* ws = (char*)d_ws;
  size_t off = 0;
  auto alloc = [&](size_t bytes) -> void* {
    void* p = ws + off;
    off = (off + bytes + 255) & ~(size_t)255;
    return p;
  };
  // contiguous zero region: deg, fill, bnA, bnB, bnC
  char* zbase = (char*)alloc(0);
  int*   deg   = (int*)  alloc((size_t)N * 4);
  int*   fill  = (int*)  alloc((size_t)N * 4);
  float* bnA   = (float*)alloc(128 * 4);
  float* bnB   = (float*)alloc(128 * 4);
  float* bnC   = (float*)alloc(128 * 4);
  size_t zbytes = (size_t)((char*)alloc(0) - zbase);
  int*   rowp  = (int*)  alloc((size_t)(N + 1) * 4);
  int*   colv  = (int*)  alloc((size_t)E * 4);
  int*   dstv  = (int*)  alloc((size_t)E * 4);
  int*   bsum  = (int*)  alloc(64 * 4);
  float* dinv  = (float*)alloc((size_t)N * 4);
  float* sdinv = (float*)alloc((size_t)N * 4);
  float* as1   = (float*)alloc((size_t)N * 4 * 4);
  float* ad1   = (float*)alloc((size_t)N * 4 * 4);
  float* as2   = (float*)alloc((size_t)N * 4);
  float* ad2   = (float*)alloc((size_t)N * 4);
  float* w4    = (float*)alloc((size_t)E * 4 * 4);
  float* w1    = (float*)alloc((size_t)E * 4);
  unsigned short* xh    = (unsigned short*)alloc((size_t)N * 128 * 2);
  unsigned short* xl    = (unsigned short*)alloc((size_t)N * 128 * 2);
  unsigned short* gath  = (unsigned short*)alloc((size_t)N * 256 * 2);   // GAT1 out (ilv)
  unsigned short* oh    = (unsigned short*)alloc((size_t)N * 256 * 2);   // agg4 out (ilv)
  unsigned short* g1h   = (unsigned short*)alloc((size_t)N * 64 * 2);
  unsigned short* g2h   = (unsigned short*)alloc((size_t)N * 64 * 2);
  unsigned short* aggXh = (unsigned short*)alloc((size_t)N * 128 * 2);
  unsigned short* aggSh = (unsigned short*)alloc((size_t)N * 64 * 2);
  unsigned short* m192  = (unsigned short*)alloc((size_t)N * 192 * 2);   // t1|tg2|s1
  unsigned short* cath  = (unsigned short*)alloc((size_t)N * 192 * 2);
  unsigned short* t1bf  = (unsigned short*)alloc((size_t)N * 64 * 2);
  // weights
  unsigned short* b320h = (unsigned short*)alloc((size_t)320 * 128 * 2); // gat1(256,col-perm) + gcn1(64)
  unsigned short* b320l = (unsigned short*)alloc((size_t)320 * 128 * 2);
  unsigned short* gcn2h = (unsigned short*)alloc((size_t)64 * 64 * 2);
  unsigned short* gcn2l = (unsigned short*)alloc((size_t)64 * 64 * 2);
  unsigned short* gat2h = (unsigned short*)alloc((size_t)64 * 256 * 2);
  unsigned short* gat2l = (unsigned short*)alloc((size_t)64 * 256 * 2);
  unsigned short* s1wlh = (unsigned short*)alloc((size_t)64 * 128 * 2);
  unsigned short* s1wll = (unsigned short*)alloc((size_t)64 * 128 * 2);
  unsigned short* s1wrh = (unsigned short*)alloc((size_t)64 * 128 * 2);
  unsigned short* s1wrl = (unsigned short*)alloc((size_t)64 * 128 * 2);
  unsigned short* s2wlh = (unsigned short*)alloc((size_t)64 * 64 * 2);
  unsigned short* s2wll = (unsigned short*)alloc((size_t)64 * 64 * 2);
  unsigned short* s2wrh = (unsigned short*)alloc((size_t)64 * 64 * 2);
  unsigned short* s2wrl = (unsigned short*)alloc((size_t)64 * 64 * 2);
  unsigned short* fwh   = (unsigned short*)alloc((size_t)64 * 192 * 2);
  unsigned short* fwl   = (unsigned short*)alloc((size_t)64 * 192 * 2);
  float* fb             = (float*)alloc(64 * 4);

  hipMemsetAsync(zbase, 0, zbytes, stream);

  // CSR by destination
  k_count <<<(E + 255) / 256, 256, 0, stream>>>(dst, deg, E);
  k_scan_a<<<nb, 256, 0, stream>>>(deg, bsum, N);
  k_scan_b<<<1, 64, 0, stream>>>(bsum, rowp, nb, N);
  k_scan_c<<<nb, 256, 0, stream>>>(deg, bsum, rowp, dinv, sdinv, N);
  k_scatter<<<(E + 255) / 256, 256, 0, stream>>>(src, dst, rowp, fill, colv, dstv, E);

  // weight splits + x split
  {
    WPack p;
    p.d[0] = {gat1_w, b320h, b320l, 128, 256, 2};                        // col-perm (head-ilv C)
    p.d[1] = {gcn1_w, b320h + 256 * 128, b320l + 256 * 128, 128, 64, 0};
    p.d[2] = {gat2_w, gat2h, gat2l, 256, 64, 1};                         // K-perm (ilv A)
    p.d[3] = {sage1_wl, s1wlh, s1wll, 128, 64, 0};
    p.d[4] = {sage1_wr, s1wrh, s1wrl, 128, 64, 0};
    p.d[5] = {sage2_wl, s2wlh, s2wll, 64, 64, 0};
    p.d[6] = {sage2_wr, s2wrh, s2wrl, 64, 64, 0};
    p.d[7] = {gcn2_w, gcn2h, gcn2l, 64, 64, 0};
    dim3 g(32, 8);
    k_wsplit<<<g, 256, 0, stream>>>(p);
  }
  k_asplit<<<(N * 128 + 255) / 256, 256, 0, stream>>>(x, xh, xl, N * 128);

  const int gx = (N + 127) / 128;
  const int gn = (N + 3) / 4;

  // GAT1 + GCN1 fused GEMM (B = 320 cols)
  {
    dim3 g(gx, 5);
    k_gemm320<<<g, 256, 0, stream>>>(xh, xl, b320h, b320l, gath, g1h, N);
  }
  k_gat_attn4<<<gn, 256, 0, stream>>>(gath, gat1_as, gat1_ad, as1, ad1, N);
  k_edge_w4<<<(E + 255) / 256, 256, 0, stream>>>(colv, dstv, as1, ad1, w4, E);
  // F1: GCN1-agg + SAGE-x-agg
  k_f1<<<gn, 256, 0, stream>>>(xh, g1h, rowp, colv, dinv, sdinv, gcn1_b, aggXh, g2h, N);
  k_gat_agg4<<<gn, 256, 0, stream>>>(gath, rowp, colv, w4, as1, ad1, gat1_b, oh, N);

  // batched GEMM: GAT2 (K=256) | GCN2 (K=64) | SAGE1 dual (K=128+128) -> m192
  {
    BPack p;
    p.d[0] = {oh, nullptr, gat2h, gat2l, nullptr, nullptr, nullptr, nullptr,
              256, 256, 0, 0, nullptr, m192, 192, 0, 0};
    p.d[1] = {g2h, nullptr, gcn2h, gcn2l, nullptr, nullptr, nullptr, nullptr,
              64, 64, 0, 0, nullptr, m192, 192, 64, 0};
    p.d[2] = {aggXh, nullptr, s1wlh, s1wll, xh, xl, s1wrh, s1wrl,
              128, 128, 128, 128, sage1_bl, m192, 192, 128, 1};
    dim3 g(gx, 3);
    k_gemm_b<<<g, 256, 0, stream>>>(p, N);
  }
  k_gat_attn1<<<gn, 256, 0, stream>>>(m192, 192, gat2_as, gat2_ad, as2, ad2, N);
  k_edge_w1<<<(E + 255) / 256, 256, 0, stream>>>(colv, dstv, as2, ad2, w1, E);
  // F2: GAT2-agg + GCN2-agg + SAGE-s1-agg
  k_f2<<<gn, 256, 0, stream>>>(m192, rowp, colv, w1, as2, ad2, dinv, sdinv,
                               gat2_b, gcn2_b, cath, aggSh, N);

  // SAGE2 dual GEMM -> cat cols 128-191
  {
    BPack p;
    p.d[0] = {aggSh, nullptr, s2wlh, s2wll, m192 + 128, nullptr, s2wrh, s2wrl,
              64, 64, 64, 192, sage2_bl, cath, 192, 128, 1};
    p.d[1] = p.d[0]; p.d[2] = p.d[0];
    dim3 g(gx, 1);
    k_gemm_b<<<g, 256, 0, stream>>>(p, N);
  }

  // BN stats (one launch) + fold into fc1
  {
    dim3 g(128, 3);
    k_bn_stats3<<<g, 256, 0, stream>>>(cath, bnB, bnA, bnC, N);
  }
  k_bnfold<<<1, 256, 0, stream>>>(bnB, bnA, bnC,
                                  bn_gcn_g, bn_gcn_b, bn_gat_g, bn_gat_b, bn_sage_g, bn_sage_b,
                                  fc1_w, fc1_b, (float)N, fwh, fwl, fb);

  // FC1 GEMM
  {
    BPack p;
    p.d[0] = {cath, nullptr, fwh, fwl, nullptr, nullptr, nullptr, nullptr,
              192, 192, 0, 0, fb, t1bf, 64, 0, 1};
    p.d[1] = p.d[0]; p.d[2] = p.d[0];
    dim3 g(gx, 1);
    k_gemm_b<<<g, 256, 0, stream>>>(p, N);
  }
  k_fc2<<<gn, 256, 0, stream>>>(t1bf, fc2_w, fc2_b, out, N);
}

// Round 9
// 633.308 us; speedup vs baseline: 1.9781x; 1.0364x over previous
//
#include <hip/hip_runtime.h>
#include <math.h>

#define NEG_SLOPE 0.2f
#define BN_EPS 1e-5f

typedef short short8 __attribute__((ext_vector_type(8)));
typedef float floatx16 __attribute__((ext_vector_type(16)));

__device__ __forceinline__ float d_leaky(float x){ return x > 0.f ? x : NEG_SLOPE * x; }
__device__ __forceinline__ float d_elu(float x){ return x > 0.f ? x : expm1f(x); }

__device__ __forceinline__ unsigned short f2bf_rne(float f){
  unsigned int u = __float_as_uint(f);
  unsigned int r = (u + 0x7fffu + ((u >> 16) & 1u)) >> 16;
  return (unsigned short)r;
}
__device__ __forceinline__ float bf2f(unsigned short h){ return __uint_as_float((unsigned int)h << 16); }
__device__ __forceinline__ float2 bf2x(unsigned int u){
  float2 r;
  r.x = __uint_as_float(u << 16);
  r.y = __uint_as_float(u & 0xffff0000u);
  return r;
}

__device__ __forceinline__ float wave_sum(float v){
  #pragma unroll
  for (int off = 32; off > 0; off >>= 1) v += __shfl_xor(v, off, 64);
  return v;
}
__device__ __forceinline__ int wave_scan_incl(int v, int lane){
  #pragma unroll
  for (int off = 1; off < 64; off <<= 1){
    int u = __shfl_up(v, off, 64);
    if (lane >= off) v += u;
  }
  return v;
}

// ---------------- CSR build ----------------
__global__ void k_count(const int* __restrict__ dst, int* __restrict__ deg, int E){
  int e = blockIdx.x * blockDim.x + threadIdx.x;
  if (e < E) atomicAdd(&deg[dst[e]], 1);
}

__global__ __launch_bounds__(256) void k_scan_a(const int* __restrict__ deg, int* __restrict__ bsum, int n){
  int t = threadIdx.x;
  int base = blockIdx.x * 1024 + t * 4;
  int d0=0,d1=0,d2=0,d3=0;
  if (base + 3 < n){ int4 v = *(const int4*)(deg + base); d0=v.x; d1=v.y; d2=v.z; d3=v.w; }
  else {
    if (base   < n) d0 = deg[base];
    if (base+1 < n) d1 = deg[base+1];
    if (base+2 < n) d2 = deg[base+2];
    if (base+3 < n) d3 = deg[base+3];
  }
  int s = d0+d1+d2+d3;
  __shared__ int wsm[4];
  int lane = t & 63, w = t >> 6;
  int incl = wave_scan_incl(s, lane);
  if (lane == 63) wsm[w] = incl;
  __syncthreads();
  if (t == 0) bsum[blockIdx.x] = wsm[0]+wsm[1]+wsm[2]+wsm[3];
}

__global__ void k_scan_b(int* __restrict__ bsum, int* __restrict__ rowp, int nb, int n){
  int t = threadIdx.x;  // 64 threads, nb <= 64
  int v = (t < nb) ? bsum[t] : 0;
  int incl = wave_scan_incl(v, t);
  if (t < nb) bsum[t] = incl - v;
  if (t == 63) rowp[n] = incl;
}

__global__ __launch_bounds__(256) void k_scan_c(const int* __restrict__ deg, const int* __restrict__ bsum,
                                                int* __restrict__ rowp, float* __restrict__ dinv,
                                                float* __restrict__ sdinv, int n){
  int t = threadIdx.x;
  int base = blockIdx.x * 1024 + t * 4;
  int d0=0,d1=0,d2=0,d3=0;
  if (base + 3 < n){ int4 v = *(const int4*)(deg + base); d0=v.x; d1=v.y; d2=v.z; d3=v.w; }
  else {
    if (base   < n) d0 = deg[base];
    if (base+1 < n) d1 = deg[base+1];
    if (base+2 < n) d2 = deg[base+2];
    if (base+3 < n) d3 = deg[base+3];
  }
  int s = d0+d1+d2+d3;
  __shared__ int wsm[4];
  int lane = t & 63, w = t >> 6;
  int incl = wave_scan_incl(s, lane);
  if (lane == 63) wsm[w] = incl;
  __syncthreads();
  int woff = 0;
  #pragma unroll
  for (int j = 0; j < 4; j++) if (j < w) woff += wsm[j];
  int r = bsum[blockIdx.x] + woff + incl - s;
  int dd[4] = {d0,d1,d2,d3};
  #pragma unroll
  for (int j = 0; j < 4; j++){
    int i = base + j;
    if (i < n){
      rowp[i] = r;
      dinv[i] = rsqrtf((float)(dd[j] + 1));
      sdinv[i] = 1.0f / fmaxf((float)dd[j], 1.0f);
    }
    r += dd[j];
  }
}

__global__ void k_scatter(const int* __restrict__ src, const int* __restrict__ dst,
                          const int* __restrict__ rowp, int* __restrict__ fill,
                          int* __restrict__ colv, int* __restrict__ dstv, int E){
  int e = blockIdx.x * blockDim.x + threadIdx.x;
  if (e < E){
    int d = dst[e];
    int pos = rowp[d] + atomicAdd(&fill[d], 1);
    colv[pos] = src[e];
    dstv[pos] = d;
  }
}

// ---------------- split fp32 -> bf16 hi/lo ----------------
__global__ void k_asplit(const float* __restrict__ a, unsigned short* __restrict__ h,
                         unsigned short* __restrict__ l, int total){
  int i = blockIdx.x * blockDim.x + threadIdx.x;
  if (i < total){
    float v = a[i];
    unsigned short hh = f2bf_rne(v);
    h[i] = hh;
    l[i] = f2bf_rne(v - bf2f(hh));
  }
}

// ---------------- weight transpose + split ----------------
// perm: 0 none; 1 = K-permute (interleaved-A GEMM, gat2); 2 = col-permute (head-interleave C, gat1)
struct WDesc { const float* w; unsigned short* th; unsigned short* tl; int K; int Nc; int perm; };
struct WPack { WDesc d[8]; };
__global__ void k_wsplit(WPack p){
  WDesc w = p.d[blockIdx.y];
  int total = w.K * w.Nc;
  for (int i = blockIdx.x * blockDim.x + threadIdx.x; i < total; i += gridDim.x * blockDim.x){
    int k = i / w.Nc, n = i % w.Nc;
    int kd = (w.perm == 1) ? ((k & 63) * 4 + (k >> 6)) : k;
    int nd = (w.perm == 2) ? (((n & 63) << 2) | (n >> 6)) : n;
    float v = w.w[i];
    unsigned short h = f2bf_rne(v);
    w.th[(size_t)nd * w.K + kd] = h;
    w.tl[(size_t)nd * w.K + kd] = f2bf_rne(v - bf2f(h));
  }
}

// ---------------- GEMM term helper ----------------
__device__ __forceinline__ void gemm_term(floatx16& acc0, floatx16& acc1,
    const unsigned short* __restrict__ Ah, const unsigned short* __restrict__ Al,
    const unsigned short* __restrict__ Bh, const unsigned short* __restrict__ Bl,
    int K, int lda, int arow, int lr, int ko8){
  const unsigned short* ap  = Ah + (size_t)arow * lda + ko8;
  const unsigned short* alp = Al ? Al + (size_t)arow * lda + ko8 : nullptr;
  const unsigned short* bh0 = Bh + (size_t)lr * K + ko8;
  const unsigned short* bl0 = Bl + (size_t)lr * K + ko8;
  const unsigned short* bh1 = bh0 + (size_t)32 * K;
  const unsigned short* bl1 = bl0 + (size_t)32 * K;
  for (int k0 = 0; k0 < K; k0 += 16){
    short8 a  = *(const short8*)(ap + k0);
    short8 h0 = *(const short8*)(bh0 + k0);
    short8 l0 = *(const short8*)(bl0 + k0);
    short8 h1 = *(const short8*)(bh1 + k0);
    short8 l1 = *(const short8*)(bl1 + k0);
    if (alp){
      short8 a2 = *(const short8*)(alp + k0);
      acc0 = __builtin_amdgcn_mfma_f32_32x32x16_bf16(a2, h0, acc0, 0, 0, 0);
      acc1 = __builtin_amdgcn_mfma_f32_32x32x16_bf16(a2, h1, acc1, 0, 0, 0);
    }
    acc0 = __builtin_amdgcn_mfma_f32_32x32x16_bf16(a, l0, acc0, 0, 0, 0);
    acc0 = __builtin_amdgcn_mfma_f32_32x32x16_bf16(a, h0, acc0, 0, 0, 0);
    acc1 = __builtin_amdgcn_mfma_f32_32x32x16_bf16(a, l1, acc1, 0, 0, 0);
    acc1 = __builtin_amdgcn_mfma_f32_32x32x16_bf16(a, h1, acc1, 0, 0, 0);
  }
}

// ---------------- batched MFMA GEMM: out = act(A1@B1 [+A2@B2] + bias), Nc=64, bf16 out ----
// Optional fused 64->2 FC: outf[row*2+q] = sum_col act(v[col]) * fc2w[col*2+q] + fc2b[q]
struct BDesc {
  const unsigned short *A1h, *A1l, *B1h, *B1l;
  const unsigned short *A2h, *A2l, *B2h, *B2l;
  int K1, lda1, K2, lda2;
  const float* bias;
  unsigned short* out; int ldc, coloff, act;
  const float* fc2w; const float* fc2b; float* outf;
};
struct BPack { BDesc d[3]; };
__global__ __launch_bounds__(256) void k_gemm_b(BPack p, int M){
  BDesc d = p.d[blockIdx.y];
  int wave = threadIdx.x >> 6, lane = threadIdx.x & 63;
  int m0 = blockIdx.x * 128 + wave * 32;
  int lr = lane & 31;
  int ko8 = (lane >> 5) * 8;
  floatx16 acc0 = {0,0,0,0,0,0,0,0,0,0,0,0,0,0,0,0};
  floatx16 acc1 = {0,0,0,0,0,0,0,0,0,0,0,0,0,0,0,0};
  int arow = m0 + lr; if (arow >= M) arow = M - 1;
  gemm_term(acc0, acc1, d.A1h, d.A1l, d.B1h, d.B1l, d.K1, d.lda1, arow, lr, ko8);
  if (d.K2) gemm_term(acc0, acc1, d.A2h, d.A2l, d.B2h, d.B2l, d.K2, d.lda2, arow, lr, ko8);
  int col0 = lr, col1 = lr + 32;
  float bias0 = d.bias ? d.bias[col0] : 0.f;
  float bias1 = d.bias ? d.bias[col1] : 0.f;
  float w00 = 0.f, w01 = 0.f, w10 = 0.f, w11 = 0.f;
  if (d.fc2w){
    w00 = d.fc2w[col0 * 2 + 0]; w01 = d.fc2w[col0 * 2 + 1];
    w10 = d.fc2w[col1 * 2 + 0]; w11 = d.fc2w[col1 * 2 + 1];
  }
  int rbase = m0 + 4 * (lane >> 5);
  #pragma unroll
  for (int reg = 0; reg < 16; reg++){
    int row = rbase + (reg & 3) + 8 * (reg >> 2);
    float v0 = acc0[reg] + bias0;
    float v1 = acc1[reg] + bias1;
    if (d.act){ v0 = fmaxf(v0, 0.f); v1 = fmaxf(v1, 0.f); }
    if (d.out && row < M){
      d.out[(size_t)row * d.ldc + d.coloff + col0] = f2bf_rne(v0);
      d.out[(size_t)row * d.ldc + d.coloff + col1] = f2bf_rne(v1);
    }
    if (d.fc2w){
      // half-wave reduction: lanes 0-31 hold one row, lanes 32-63 hold row+4
      float p0 = v0 * w00 + v1 * w10;
      float p1 = v0 * w01 + v1 * w11;
      #pragma unroll
      for (int off = 16; off > 0; off >>= 1){
        p0 += __shfl_xor(p0, off, 64);
        p1 += __shfl_xor(p1, off, 64);
      }
      if ((lane & 31) == 0 && row < M){
        d.outf[(size_t)row * 2 + 0] = p0 + d.fc2b[0];
        d.outf[(size_t)row * 2 + 1] = p1 + d.fc2b[1];
      }
    }
  }
}

// ---------------- GEMM320: C = x @ [gat1|gcn1], cols<256 -> gath (ld 256), else g1h (ld 64) ----
__global__ __launch_bounds__(256) void k_gemm320(
    const unsigned short* __restrict__ Ah, const unsigned short* __restrict__ Al,
    const unsigned short* __restrict__ Bh, const unsigned short* __restrict__ Bl,
    unsigned short* __restrict__ C1, unsigned short* __restrict__ C2, int M)
{
  const int K = 128;
  int wave = threadIdx.x >> 6, lane = threadIdx.x & 63;
  int m0 = blockIdx.x * 128 + wave * 32;
  int n0 = blockIdx.y * 64;
  int lr = lane & 31;
  int ko8 = (lane >> 5) * 8;
  floatx16 acc0 = {0,0,0,0,0,0,0,0,0,0,0,0,0,0,0,0};
  floatx16 acc1 = {0,0,0,0,0,0,0,0,0,0,0,0,0,0,0,0};
  int arow = m0 + lr; if (arow >= M) arow = M - 1;
  const unsigned short* ap_h = Ah + (size_t)arow * K + ko8;
  const unsigned short* ap_l = Al + (size_t)arow * K + ko8;
  const unsigned short* bp_h0 = Bh + (size_t)(n0 + lr) * K + ko8;
  const unsigned short* bp_l0 = Bl + (size_t)(n0 + lr) * K + ko8;
  const unsigned short* bp_h1 = bp_h0 + (size_t)32 * K;
  const unsigned short* bp_l1 = bp_l0 + (size_t)32 * K;
  for (int k0 = 0; k0 < K; k0 += 16){
    short8 a_h  = *(const short8*)(ap_h + k0);
    short8 a_l  = *(const short8*)(ap_l + k0);
    short8 b_h0 = *(const short8*)(bp_h0 + k0);
    short8 b_l0 = *(const short8*)(bp_l0 + k0);
    short8 b_h1 = *(const short8*)(bp_h1 + k0);
    short8 b_l1 = *(const short8*)(bp_l1 + k0);
    acc0 = __builtin_amdgcn_mfma_f32_32x32x16_bf16(a_l, b_h0, acc0, 0, 0, 0);
    acc0 = __builtin_amdgcn_mfma_f32_32x32x16_bf16(a_h, b_l0, acc0, 0, 0, 0);
    acc0 = __builtin_amdgcn_mfma_f32_32x32x16_bf16(a_h, b_h0, acc0, 0, 0, 0);
    acc1 = __builtin_amdgcn_mfma_f32_32x32x16_bf16(a_l, b_h1, acc1, 0, 0, 0);
    acc1 = __builtin_amdgcn_mfma_f32_32x32x16_bf16(a_h, b_l1, acc1, 0, 0, 0);
    acc1 = __builtin_amdgcn_mfma_f32_32x32x16_bf16(a_h, b_h1, acc1, 0, 0, 0);
  }
  int col0 = n0 + lr, col1 = col0 + 32;
  unsigned short* Cp; int ld, c0, c1;
  if (col0 >= 256){ Cp = C2; ld = 64; c0 = col0 - 256; c1 = col1 - 256; }
  else { Cp = C1; ld = 256; c0 = col0; c1 = col1; }
  int rbase = m0 + 4 * (lane >> 5);
  #pragma unroll
  for (int reg = 0; reg < 16; reg++){
    int row = rbase + (reg & 3) + 8 * (reg >> 2);
    if (row >= M) continue;
    Cp[(size_t)row * ld + c0] = f2bf_rne(acc0[reg]);
    Cp[(size_t)row * ld + c1] = f2bf_rne(acc1[reg]);
  }
}

// ---------------- GAT1 attention coeffs (interleaved bf16 h) ----------------
__global__ __launch_bounds__(256) void k_gat_attn4(
    const unsigned short* __restrict__ h, const float* __restrict__ asrc,
    const float* __restrict__ adst, float* __restrict__ a_s, float* __restrict__ a_d, int n){
  int node = blockIdx.x * 4 + (threadIdx.x >> 6);
  int c = threadIdx.x & 63;
  if (node >= n) return;
  uint2 u = *(const uint2*)(h + (size_t)node * 256 + c * 4);
  float2 p0 = bf2x(u.x), p1 = bf2x(u.y);
  float s0 = wave_sum(p0.x * asrc[c]);
  float s1 = wave_sum(p0.y * asrc[64 + c]);
  float s2 = wave_sum(p1.x * asrc[128 + c]);
  float s3 = wave_sum(p1.y * asrc[192 + c]);
  float d0 = wave_sum(p0.x * adst[c]);
  float d1 = wave_sum(p0.y * adst[64 + c]);
  float d2 = wave_sum(p1.x * adst[128 + c]);
  float d3 = wave_sum(p1.y * adst[192 + c]);
  if (c == 0){
    *(float4*)(a_s + (size_t)node * 4) = make_float4(s0, s1, s2, s3);
    *(float4*)(a_d + (size_t)node * 4) = make_float4(d0, d1, d2, d3);
  }
}

// ---------------- GAT2 attention coeffs (bf16 h, strided) ----------------
__global__ __launch_bounds__(256) void k_gat_attn1(
    const unsigned short* __restrict__ h, int ld, const float* __restrict__ asrc,
    const float* __restrict__ adst, float* __restrict__ a_s, float* __restrict__ a_d, int n){
  int node = blockIdx.x * 4 + (threadIdx.x >> 6);
  int c = threadIdx.x & 63;
  if (node >= n) return;
  float v = bf2f(h[(size_t)node * ld + c]);
  float s = wave_sum(v * asrc[c]);
  float d = wave_sum(v * adst[c]);
  if (c == 0){ a_s[node] = s; a_d[node] = d; }
}

// ---------------- per-edge softmax numerators ----------------
// w4b: 4 bf16 per edge (packed uint2)
__global__ void k_edge_w4(const int* __restrict__ colv, const int* __restrict__ dstv,
                          const float* __restrict__ a_s, const float* __restrict__ a_d,
                          unsigned short* __restrict__ w4b, int E){
  int i = blockIdx.x * blockDim.x + threadIdx.x;
  if (i >= E) return;
  float4 s4 = *(const float4*)(a_s + (size_t)colv[i] * 4);
  float4 d4 = *(const float4*)(a_d + (size_t)dstv[i] * 4);
  float w0 = __expf(d_leaky(s4.x + d4.x));
  float w1 = __expf(d_leaky(s4.y + d4.y));
  float w2 = __expf(d_leaky(s4.z + d4.z));
  float w3 = __expf(d_leaky(s4.w + d4.w));
  uint2 q;
  q.x = (unsigned int)f2bf_rne(w0) | ((unsigned int)f2bf_rne(w1) << 16);
  q.y = (unsigned int)f2bf_rne(w2) | ((unsigned int)f2bf_rne(w3) << 16);
  *(uint2*)(w4b + (size_t)i * 4) = q;
}

__global__ void k_edge_w1(const int* __restrict__ colv, const int* __restrict__ dstv,
                          const float* __restrict__ a_s, const float* __restrict__ a_d,
                          float* __restrict__ w1, int E){
  int i = blockIdx.x * blockDim.x + threadIdx.x;
  if (i >= E) return;
  w1[i] = __expf(d_leaky(a_s[colv[i]] + a_d[dstv[i]]));
}

// ---------------- L1AGG: fused GAT1-agg (4 heads) + GCN1-agg + SAGE-x-agg ----------------
// One CSR walk per node; per lane per edge gathers gath(8B) + xh(4B) + g1h(2B).
// Masked batches of 8 (clamped indices, zeroed weights) -- no serial remainder.
__global__ __launch_bounds__(256) void k_l1agg(
    const unsigned short* __restrict__ gath, const unsigned short* __restrict__ xh,
    const unsigned short* __restrict__ g1h,
    const int* __restrict__ rowp, const int* __restrict__ colv,
    const unsigned short* __restrict__ w4b,
    const float* __restrict__ a_s, const float* __restrict__ a_d,
    const float* __restrict__ gat1_b, const float* __restrict__ gcn1_b,
    const float* __restrict__ dinv, const float* __restrict__ sdinv,
    unsigned short* __restrict__ oh, unsigned short* __restrict__ g2h,
    unsigned short* __restrict__ aggXh, int n)
{
  int node = blockIdx.x * 4 + (threadIdx.x >> 6);
  int c = threadIdx.x & 63;
  if (node >= n) return;
  float4 asn = *(const float4*)(a_s + (size_t)node * 4);
  float4 adn = *(const float4*)(a_d + (size_t)node * 4);
  float ws0 = __expf(d_leaky(asn.x + adn.x));
  float ws1 = __expf(d_leaky(asn.y + adn.y));
  float ws2 = __expf(d_leaky(asn.z + adn.z));
  float ws3 = __expf(d_leaky(asn.w + adn.w));
  uint2 su = *(const uint2*)(gath + (size_t)node * 256 + c * 4);
  float2 sp0 = bf2x(su.x), sp1 = bf2x(su.y);
  float den0 = ws0, den1 = ws1, den2 = ws2, den3 = ws3;
  float acc0 = ws0 * sp0.x, acc1 = ws1 * sp0.y, acc2 = ws2 * sp1.x, acc3 = ws3 * sp1.y;
  float di = dinv[node];
  float gacc = di * bf2f(g1h[(size_t)node * 64 + c]);
  float sx0 = 0.f, sx1 = 0.f;
  int b = rowp[node], e = rowp[node + 1];
  for (int i = b; i < e; i += 8){
    int idx[8]; float mm[8]; int s[8];
    #pragma unroll
    for (int j = 0; j < 8; j++){
      int t = i + j;
      mm[j] = (t < e) ? 1.f : 0.f;
      idx[j] = (t < e) ? t : (e - 1);
    }
    #pragma unroll
    for (int j = 0; j < 8; j++) s[j] = colv[idx[j]];
    uint2 wq[8];
    #pragma unroll
    for (int j = 0; j < 8; j++) wq[j] = *(const uint2*)(w4b + (size_t)idx[j] * 4);
    uint2 hv[8];
    #pragma unroll
    for (int j = 0; j < 8; j++) hv[j] = *(const uint2*)(gath + (size_t)s[j] * 256 + c * 4);
    unsigned int hx[8];
    #pragma unroll
    for (int j = 0; j < 8; j++) hx[j] = *(const unsigned int*)(xh + (size_t)s[j] * 128 + c * 2);
    unsigned short hg[8];
    #pragma unroll
    for (int j = 0; j < 8; j++) hg[j] = g1h[(size_t)s[j] * 64 + c];
    float wd[8];
    #pragma unroll
    for (int j = 0; j < 8; j++) wd[j] = dinv[s[j]];
    #pragma unroll
    for (int j = 0; j < 8; j++){
      float m = mm[j];
      float2 w01 = bf2x(wq[j].x), w23 = bf2x(wq[j].y);
      float w0 = m * w01.x, w1 = m * w01.y, w2 = m * w23.x, w3 = m * w23.y;
      float2 a = bf2x(hv[j].x), bb = bf2x(hv[j].y);
      den0 += w0; den1 += w1; den2 += w2; den3 += w3;
      acc0 += w0 * a.x;  acc1 += w1 * a.y;
      acc2 += w2 * bb.x; acc3 += w3 * bb.y;
      gacc += m * wd[j] * bf2f(hg[j]);
      float2 p = bf2x(hx[j]);
      sx0 += m * p.x; sx1 += m * p.y;
    }
  }
  float v0 = d_elu(acc0 / (den0 + 1e-16f) + gat1_b[c]);
  float v1 = d_elu(acc1 / (den1 + 1e-16f) + gat1_b[64 + c]);
  float v2 = d_elu(acc2 / (den2 + 1e-16f) + gat1_b[128 + c]);
  float v3 = d_elu(acc3 / (den3 + 1e-16f) + gat1_b[192 + c]);
  uint2 ohv;
  ohv.x = (unsigned int)f2bf_rne(v0) | ((unsigned int)f2bf_rne(v1) << 16);
  ohv.y = (unsigned int)f2bf_rne(v2) | ((unsigned int)f2bf_rne(v3) << 16);
  *(uint2*)(oh + (size_t)node * 256 + c * 4) = ohv;
  g2h[(size_t)node * 64 + c] = f2bf_rne(fmaxf(di * gacc + gcn1_b[c], 0.f));
  float sd = sdinv[node];
  *(unsigned int*)(aggXh + (size_t)node * 128 + c * 2) =
      (unsigned int)f2bf_rne(sx0 * sd) | ((unsigned int)f2bf_rne(sx1 * sd) << 16);
}

// ---------------- F2: fused GAT2-agg + GCN2-agg + SAGE-s1-agg over m192 ----------------
// m192 cols: 0-63 = t1 (GAT2 GEMM), 64-127 = tg2 (GCN2 GEMM), 128-191 = s1 (SAGE1 GEMM)
__global__ __launch_bounds__(256) void k_f2(
    const unsigned short* __restrict__ m192,
    const int* __restrict__ rowp, const int* __restrict__ colv,
    const float* __restrict__ w1, const float* __restrict__ a_s, const float* __restrict__ a_d,
    const float* __restrict__ dinv, const float* __restrict__ sdinv,
    const float* __restrict__ gat2_b, const float* __restrict__ gcn2_b,
    unsigned short* __restrict__ cat,   // [N][192], writes cols 0-127
    unsigned short* __restrict__ aggSh, // [N][64]
    int n){
  int node = blockIdx.x * 4 + (threadIdx.x >> 6);
  int c = threadIdx.x & 63;
  if (node >= n) return;
  float di = dinv[node];
  const unsigned short* srow = m192 + (size_t)node * 192;
  float tden = __expf(d_leaky(a_s[node] + a_d[node]));
  float tacc = tden * bf2f(srow[c]);
  float gacc = di * bf2f(srow[64 + c]);
  float sacc = 0.f;
  int b = rowp[node], e = rowp[node + 1];
  for (int i = b; i < e; i += 8){
    int idx[8]; float mm[8]; int s[8];
    #pragma unroll
    for (int j = 0; j < 8; j++){
      int t = i + j;
      mm[j] = (t < e) ? 1.f : 0.f;
      idx[j] = (t < e) ? t : (e - 1);
    }
    #pragma unroll
    for (int j = 0; j < 8; j++) s[j] = colv[idx[j]];
    float w[8];
    #pragma unroll
    for (int j = 0; j < 8; j++) w[j] = w1[idx[j]] * mm[j];
    unsigned short ht[8], hg[8], hs[8];
    #pragma unroll
    for (int j = 0; j < 8; j++){
      const unsigned short* r = m192 + (size_t)s[j] * 192;
      ht[j] = r[c]; hg[j] = r[64 + c]; hs[j] = r[128 + c];
    }
    float wd[8];
    #pragma unroll
    for (int j = 0; j < 8; j++) wd[j] = dinv[s[j]];
    #pragma unroll
    for (int j = 0; j < 8; j++){
      tden += w[j]; tacc += w[j] * bf2f(ht[j]);
      gacc += mm[j] * wd[j] * bf2f(hg[j]);
      sacc += mm[j] * bf2f(hs[j]);
    }
  }
  cat[(size_t)node * 192 + 64 + c] = f2bf_rne(d_elu(tacc / (tden + 1e-16f) + gat2_b[c]));
  cat[(size_t)node * 192 + c] = f2bf_rne(fmaxf(di * gacc + gcn2_b[c], 0.f));
  aggSh[(size_t)node * 64 + c] = f2bf_rne(sacc * sdinv[node]);
}

// ---------------- BN stats, one launch over 3 segments ----------------
__global__ void k_bn_stats3(const unsigned short* __restrict__ x,
                            float* __restrict__ bnGCN, float* __restrict__ bnGAT,
                            float* __restrict__ bnSAGE, int n){
  int seg = blockIdx.y;
  float* sums = (seg == 0) ? bnGCN : (seg == 1) ? bnGAT : bnSAGE;
  int co = seg * 64;
  int c = threadIdx.x & 63;
  int rl = threadIdx.x >> 6;
  float s = 0.f, q = 0.f;
  for (int r = blockIdx.x * 4 + rl; r < n; r += gridDim.x * 4){
    float v = bf2f(x[(size_t)r * 192 + co + c]);
    s += v; q += v * v;
  }
  __shared__ float ls[4][64], lq[4][64];
  ls[rl][c] = s; lq[rl][c] = q;
  __syncthreads();
  if (rl == 0){
    s = ls[0][c] + ls[1][c] + ls[2][c] + ls[3][c];
    q = lq[0][c] + lq[1][c] + lq[2][c] + lq[3][c];
    atomicAdd(&sums[c], s);
    atomicAdd(&sums[64 + c], q);
  }
}

// ---------------- fold BN into fc1 weights ----------------
__global__ __launch_bounds__(256) void k_bnfold(
    const float* __restrict__ bnGCN, const float* __restrict__ bnGAT, const float* __restrict__ bnSAGE,
    const float* __restrict__ gg, const float* __restrict__ gb,
    const float* __restrict__ ag, const float* __restrict__ ab,
    const float* __restrict__ sg, const float* __restrict__ sb,
    const float* __restrict__ w, const float* __restrict__ wb, float nf,
    unsigned short* __restrict__ fwh, unsigned short* __restrict__ fwl, float* __restrict__ fb)
{
  int tid = threadIdx.x;
  auto st = [&](int c, float& s, float& t){
    int cc = c & 63;
    const float *bn, *g, *b;
    if (c < 64){ bn = bnGCN; g = gg; b = gb; }
    else if (c < 128){ bn = bnGAT; g = ag; b = ab; }
    else { bn = bnSAGE; g = sg; b = sb; }
    float m = bn[cc] / nf;
    float var = bn[64 + cc] / nf - m * m;
    float inv = rsqrtf(var + BN_EPS);
    s = inv * g[cc];
    t = b[cc] - m * inv * g[cc];
  };
  if (tid < 64){
    float acc = wb[tid];
    for (int c = 0; c < 192; c++){
      float s, t; st(c, s, t);
      acc += t * w[c * 64 + tid];
    }
    fb[tid] = acc;
  }
  for (int i = tid; i < 192 * 64; i += 256){
    int c = i >> 6, nn = i & 63;
    float s, t; st(c, s, t);
    float v = s * w[i];
    unsigned short hh = f2bf_rne(v);
    fwh[nn * 192 + c] = hh;
    fwl[nn * 192 + c] = f2bf_rne(v - bf2f(hh));
  }
}

extern "C" void kernel_launch(void* const* d_in, const int* in_sizes, int n_in,
                              void* d_out, int out_size, void* d_ws, size_t ws_size,
                              hipStream_t stream){
  (void)n_in; (void)out_size; (void)ws_size;
  const float* x        = (const float*)d_in[0];
  const int*   ei       = (const int*)  d_in[1];
  const float* gcn1_w   = (const float*)d_in[2];
  const float* gcn1_b   = (const float*)d_in[3];
  const float* gcn2_w   = (const float*)d_in[4];
  const float* gcn2_b   = (const float*)d_in[5];
  const float* gat1_w   = (const float*)d_in[6];
  const float* gat1_as  = (const float*)d_in[7];
  const float* gat1_ad  = (const float*)d_in[8];
  const float* gat1_b   = (const float*)d_in[9];
  const float* gat2_w   = (const float*)d_in[10];
  const float* gat2_as  = (const float*)d_in[11];
  const float* gat2_ad  = (const float*)d_in[12];
  const float* gat2_b   = (const float*)d_in[13];
  const float* sage1_wl = (const float*)d_in[14];
  const float* sage1_bl = (const float*)d_in[15];
  const float* sage1_wr = (const float*)d_in[16];
  const float* sage2_wl = (const float*)d_in[17];
  const float* sage2_bl = (const float*)d_in[18];
  const float* sage2_wr = (const float*)d_in[19];
  const float* bn_gcn_g = (const float*)d_in[20];
  const float* bn_gcn_b = (const float*)d_in[21];
  const float* bn_gat_g = (const float*)d_in[22];
  const float* bn_gat_b = (const float*)d_in[23];
  const float* bn_sage_g= (const float*)d_in[24];
  const float* bn_sage_b= (const float*)d_in[25];
  const float* fc1_w    = (const float*)d_in[26];
  const float* fc1_b    = (const float*)d_in[27];
  const float* fc2_w    = (const float*)d_in[28];
  const float* fc2_b    = (const float*)d_in[29];
  float* out = (float*)d_out;

  const int N = in_sizes[0] / 128;
  const int E = in_sizes[1] / 2;
  const int* src = ei;
  const int* dst = ei + E;
  const int nb = (N + 1023) / 1024;

  char* ws = (char*)d_ws;
  size_t off = 0;
  auto alloc = [&](size_t bytes) -> void* {
    void* p = ws + off;
    off = (off + bytes + 255) & ~(size_t)255;
    return p;
  };
  // contiguous zero region: deg, fill, bnA, bnB, bnC
  char* zbase = (char*)alloc(0);
  int*   deg   = (int*)  alloc((size_t)N * 4);
  int*   fill  = (int*)  alloc((size_t)N * 4);
  float* bnA   = (float*)alloc(128 * 4);
  float* bnB   = (float*)alloc(128 * 4);
  float* bnC   = (float*)alloc(128 * 4);
  size_t zbytes = (size_t)((char*)alloc(0) - zbase);
  int*   rowp  = (int*)  alloc((size_t)(N + 1) * 4);
  int*   colv  = (int*)  alloc((size_t)E * 4);
  int*   dstv  = (int*)  alloc((size_t)E * 4);
  int*   bsum  = (int*)  alloc(64 * 4);
  float* dinv  = (float*)alloc((size_t)N * 4);
  float* sdinv = (float*)alloc((size_t)N * 4);
  float* as1   = (float*)alloc((size_t)N * 4 * 4);
  float* ad1   = (float*)alloc((size_t)N * 4 * 4);
  float* as2   = (float*)alloc((size_t)N * 4);
  float* ad2   = (float*)alloc((size_t)N * 4);
  unsigned short* w4b = (unsigned short*)alloc((size_t)E * 4 * 2);
  float* w1    = (float*)alloc((size_t)E * 4);
  unsigned short* xh    = (unsigned short*)alloc((size_t)N * 128 * 2);
  unsigned short* xl    = (unsigned short*)alloc((size_t)N * 128 * 2);
  unsigned short* gath  = (unsigned short*)alloc((size_t)N * 256 * 2);   // GAT1 out (ilv)
  unsigned short* oh    = (unsigned short*)alloc((size_t)N * 256 * 2);   // l1agg GAT out (ilv)
  unsigned short* g1h   = (unsigned short*)alloc((size_t)N * 64 * 2);
  unsigned short* g2h   = (unsigned short*)alloc((size_t)N * 64 * 2);
  unsigned short* aggXh = (unsigned short*)alloc((size_t)N * 128 * 2);
  unsigned short* aggSh = (unsigned short*)alloc((size_t)N * 64 * 2);
  unsigned short* m192  = (unsigned short*)alloc((size_t)N * 192 * 2);   // t1|tg2|s1
  unsigned short* cath  = (unsigned short*)alloc((size_t)N * 192 * 2);
  // weights
  unsigned short* b320h = (unsigned short*)alloc((size_t)320 * 128 * 2); // gat1(256,col-perm) + gcn1(64)
  unsigned short* b320l = (unsigned short*)alloc((size_t)320 * 128 * 2);
  unsigned short* gcn2h = (unsigned short*)alloc((size_t)64 * 64 * 2);
  unsigned short* gcn2l = (unsigned short*)alloc((size_t)64 * 64 * 2);
  unsigned short* gat2h = (unsigned short*)alloc((size_t)64 * 256 * 2);
  unsigned short* gat2l = (unsigned short*)alloc((size_t)64 * 256 * 2);
  unsigned short* s1wlh = (unsigned short*)alloc((size_t)64 * 128 * 2);
  unsigned short* s1wll = (unsigned short*)alloc((size_t)64 * 128 * 2);
  unsigned short* s1wrh = (unsigned short*)alloc((size_t)64 * 128 * 2);
  unsigned short* s1wrl = (unsigned short*)alloc((size_t)64 * 128 * 2);
  unsigned short* s2wlh = (unsigned short*)alloc((size_t)64 * 64 * 2);
  unsigned short* s2wll = (unsigned short*)alloc((size_t)64 * 64 * 2);
  unsigned short* s2wrh = (unsigned short*)alloc((size_t)64 * 64 * 2);
  unsigned short* s2wrl = (unsigned short*)alloc((size_t)64 * 64 * 2);
  unsigned short* fwh   = (unsigned short*)alloc((size_t)64 * 192 * 2);
  unsigned short* fwl   = (unsigned short*)alloc((size_t)64 * 192 * 2);
  float* fb             = (float*)alloc(64 * 4);

  hipMemsetAsync(zbase, 0, zbytes, stream);

  // CSR by destination
  k_count <<<(E + 255) / 256, 256, 0, stream>>>(dst, deg, E);
  k_scan_a<<<nb, 256, 0, stream>>>(deg, bsum, N);
  k_scan_b<<<1, 64, 0, stream>>>(bsum, rowp, nb, N);
  k_scan_c<<<nb, 256, 0, stream>>>(deg, bsum, rowp, dinv, sdinv, N);
  k_scatter<<<(E + 255) / 256, 256, 0, stream>>>(src, dst, rowp, fill, colv, dstv, E);

  // weight splits + x split
  {
    WPack p;
    p.d[0] = {gat1_w, b320h, b320l, 128, 256, 2};                        // col-perm (head-ilv C)
    p.d[1] = {gcn1_w, b320h + 256 * 128, b320l + 256 * 128, 128, 64, 0};
    p.d[2] = {gat2_w, gat2h, gat2l, 256, 64, 1};                         // K-perm (ilv A)
    p.d[3] = {sage1_wl, s1wlh, s1wll, 128, 64, 0};
    p.d[4] = {sage1_wr, s1wrh, s1wrl, 128, 64, 0};
    p.d[5] = {sage2_wl, s2wlh, s2wll, 64, 64, 0};
    p.d[6] = {sage2_wr, s2wrh, s2wrl, 64, 64, 0};
    p.d[7] = {gcn2_w, gcn2h, gcn2l, 64, 64, 0};
    dim3 g(32, 8);
    k_wsplit<<<g, 256, 0, stream>>>(p);
  }
  k_asplit<<<(N * 128 + 255) / 256, 256, 0, stream>>>(x, xh, xl, N * 128);

  const int gx = (N + 127) / 128;
  const int gn = (N + 3) / 4;

  // GAT1 + GCN1 fused GEMM (B = 320 cols)
  {
    dim3 g(gx, 5);
    k_gemm320<<<g, 256, 0, stream>>>(xh, xl, b320h, b320l, gath, g1h, N);
  }
  k_gat_attn4<<<gn, 256, 0, stream>>>(gath, gat1_as, gat1_ad, as1, ad1, N);
  k_edge_w4<<<(E + 255) / 256, 256, 0, stream>>>(colv, dstv, as1, ad1, w4b, E);
  // fused layer-1 aggregation: GAT1-agg + GCN1-agg + SAGE-x-agg
  k_l1agg<<<gn, 256, 0, stream>>>(gath, xh, g1h, rowp, colv, w4b, as1, ad1,
                                  gat1_b, gcn1_b, dinv, sdinv, oh, g2h, aggXh, N);

  // batched GEMM: GAT2 (K=256) | GCN2 (K=64) | SAGE1 dual (K=128+128) -> m192
  {
    BPack p;
    p.d[0] = {oh, nullptr, gat2h, gat2l, nullptr, nullptr, nullptr, nullptr,
              256, 256, 0, 0, nullptr, m192, 192, 0, 0, nullptr, nullptr, nullptr};
    p.d[1] = {g2h, nullptr, gcn2h, gcn2l, nullptr, nullptr, nullptr, nullptr,
              64, 64, 0, 0, nullptr, m192, 192, 64, 0, nullptr, nullptr, nullptr};
    p.d[2] = {aggXh, nullptr, s1wlh, s1wll, xh, xl, s1wrh, s1wrl,
              128, 128, 128, 128, sage1_bl, m192, 192, 128, 1, nullptr, nullptr, nullptr};
    dim3 g(gx, 3);
    k_gemm_b<<<g, 256, 0, stream>>>(p, N);
  }
  k_gat_attn1<<<gn, 256, 0, stream>>>(m192, 192, gat2_as, gat2_ad, as2, ad2, N);
  k_edge_w1<<<(E + 255) / 256, 256, 0, stream>>>(colv, dstv, as2, ad2, w1, E);
  // F2: GAT2-agg + GCN2-agg + SAGE-s1-agg
  k_f2<<<gn, 256, 0, stream>>>(m192, rowp, colv, w1, as2, ad2, dinv, sdinv,
                               gat2_b, gcn2_b, cath, aggSh, N);

  // SAGE2 dual GEMM -> cat cols 128-191
  {
    BPack p;
    p.d[0] = {aggSh, nullptr, s2wlh, s2wll, m192 + 128, nullptr, s2wrh, s2wrl,
              64, 64, 64, 192, sage2_bl, cath, 192, 128, 1, nullptr, nullptr, nullptr};
    p.d[1] = p.d[0]; p.d[2] = p.d[0];
    dim3 g(gx, 1);
    k_gemm_b<<<g, 256, 0, stream>>>(p, N);
  }

  // BN stats (one launch) + fold into fc1
  {
    dim3 g(128, 3);
    k_bn_stats3<<<g, 256, 0, stream>>>(cath, bnB, bnA, bnC, N);
  }
  k_bnfold<<<1, 256, 0, stream>>>(bnB, bnA, bnC,
                                  bn_gcn_g, bn_gcn_b, bn_gat_g, bn_gat_b, bn_sage_g, bn_sage_b,
                                  fc1_w, fc1_b, (float)N, fwh, fwl, fb);

  // FC1 GEMM with fused 64->2 FC2 epilogue -> out
  {
    BPack p;
    p.d[0] = {cath, nullptr, fwh, fwl, nullptr, nullptr, nullptr, nullptr,
              192, 192, 0, 0, fb, nullptr, 64, 0, 1, fc2_w, fc2_b, out};
    p.d[1] = p.d[0]; p.d[2] = p.d[0];
    dim3 g(gx, 1);
    k_gemm_b<<<g, 256, 0, stream>>>(p, N);
  }
}

// Round 10
// 622.060 us; speedup vs baseline: 2.0139x; 1.0181x over previous
//
#include <hip/hip_runtime.h>
#include <math.h>

#define NEG_SLOPE 0.2f
#define BN_EPS 1e-5f

typedef short short8 __attribute__((ext_vector_type(8)));
typedef float floatx16 __attribute__((ext_vector_type(16)));

__device__ __forceinline__ float d_leaky(float x){ return x > 0.f ? x : NEG_SLOPE * x; }
__device__ __forceinline__ float d_elu(float x){ return x > 0.f ? x : expm1f(x); }

__device__ __forceinline__ unsigned short f2bf_rne(float f){
  unsigned int u = __float_as_uint(f);
  unsigned int r = (u + 0x7fffu + ((u >> 16) & 1u)) >> 16;
  return (unsigned short)r;
}
__device__ __forceinline__ float bf2f(unsigned short h){ return __uint_as_float((unsigned int)h << 16); }
__device__ __forceinline__ float2 bf2x(unsigned int u){
  float2 r;
  r.x = __uint_as_float(u << 16);
  r.y = __uint_as_float(u & 0xffff0000u);
  return r;
}

__device__ __forceinline__ float wave_sum(float v){
  #pragma unroll
  for (int off = 32; off > 0; off >>= 1) v += __shfl_xor(v, off, 64);
  return v;
}
__device__ __forceinline__ int wave_scan_incl(int v, int lane){
  #pragma unroll
  for (int off = 1; off < 64; off <<= 1){
    int u = __shfl_up(v, off, 64);
    if (lane >= off) v += u;
  }
  return v;
}

// ---------------- CSR build ----------------
// also stashes the interleaved gat2 attention weights (64 threads' worth)
__global__ void k_count(const int* __restrict__ dst, int* __restrict__ deg, int E,
                        const float* __restrict__ g2as, const float* __restrict__ g2ad,
                        float* __restrict__ aw2){
  int e = blockIdx.x * blockDim.x + threadIdx.x;
  if (e < 64){ aw2[e * 2 + 0] = g2as[e]; aw2[e * 2 + 1] = g2ad[e]; }
  if (e < E) atomicAdd(&deg[dst[e]], 1);
}

__global__ __launch_bounds__(256) void k_scan_a(const int* __restrict__ deg, int* __restrict__ bsum, int n){
  int t = threadIdx.x;
  int base = blockIdx.x * 1024 + t * 4;
  int d0=0,d1=0,d2=0,d3=0;
  if (base + 3 < n){ int4 v = *(const int4*)(deg + base); d0=v.x; d1=v.y; d2=v.z; d3=v.w; }
  else {
    if (base   < n) d0 = deg[base];
    if (base+1 < n) d1 = deg[base+1];
    if (base+2 < n) d2 = deg[base+2];
    if (base+3 < n) d3 = deg[base+3];
  }
  int s = d0+d1+d2+d3;
  __shared__ int wsm[4];
  int lane = t & 63, w = t >> 6;
  int incl = wave_scan_incl(s, lane);
  if (lane == 63) wsm[w] = incl;
  __syncthreads();
  if (t == 0) bsum[blockIdx.x] = wsm[0]+wsm[1]+wsm[2]+wsm[3];
}

// scan_c with in-kernel block-prefix (bsum holds raw per-block sums; nb <= 64)
__global__ __launch_bounds__(256) void k_scan_c(const int* __restrict__ deg, const int* __restrict__ bsum,
                                                int* __restrict__ rowp, int* __restrict__ fill,
                                                float* __restrict__ dinv,
                                                float* __restrict__ sdinv, int n, int nb){
  __shared__ int sbx[2];  // [0]=exclusive prefix of this block, [1]=grand total
  int t = threadIdx.x;
  if (t < 64){
    int v = (t < nb) ? bsum[t] : 0;
    int incl = wave_scan_incl(v, t);
    if (t == (int)blockIdx.x) sbx[0] = incl - v;
    if (t == 63) sbx[1] = incl;
  }
  int base = blockIdx.x * 1024 + t * 4;
  int d0=0,d1=0,d2=0,d3=0;
  if (base + 3 < n){ int4 v = *(const int4*)(deg + base); d0=v.x; d1=v.y; d2=v.z; d3=v.w; }
  else {
    if (base   < n) d0 = deg[base];
    if (base+1 < n) d1 = deg[base+1];
    if (base+2 < n) d2 = deg[base+2];
    if (base+3 < n) d3 = deg[base+3];
  }
  int s = d0+d1+d2+d3;
  __shared__ int wsm[4];
  int lane = t & 63, w = t >> 6;
  int incl = wave_scan_incl(s, lane);
  if (lane == 63) wsm[w] = incl;
  __syncthreads();
  int woff = 0;
  #pragma unroll
  for (int j = 0; j < 4; j++) if (j < w) woff += wsm[j];
  int r = sbx[0] + woff + incl - s;
  int dd[4] = {d0,d1,d2,d3};
  #pragma unroll
  for (int j = 0; j < 4; j++){
    int i = base + j;
    if (i < n){
      rowp[i] = r;
      fill[i] = r;  // scatter's running cursor starts at rowp
      dinv[i] = rsqrtf((float)(dd[j] + 1));
      sdinv[i] = 1.0f / fmaxf((float)dd[j], 1.0f);
    }
    r += dd[j];
  }
  if (blockIdx.x == 0 && t == 0) rowp[n] = sbx[1];
}

__global__ void k_scatter(const int* __restrict__ src, const int* __restrict__ dst,
                          int* __restrict__ fill,
                          int* __restrict__ colv, int* __restrict__ dstv, int E){
  int e = blockIdx.x * blockDim.x + threadIdx.x;
  if (e < E){
    int d = dst[e];
    int pos = atomicAdd(&fill[d], 1);
    colv[pos] = src[e];
    dstv[pos] = d;
  }
}

// ---------------- weight transpose + split (+ x-split as perm 3) ----------------
// perm: 0 none; 1 = K-permute (ilv-A GEMM, gat2); 2 = col-permute (head-ilv C, gat1); 3 = plain split
struct WDesc { const float* w; unsigned short* th; unsigned short* tl; int K; int Nc; int perm; };
struct WPack { WDesc d[9]; };
__global__ void k_wsplit(WPack p){
  WDesc w = p.d[blockIdx.y];
  int total = w.K * w.Nc;
  if (w.perm == 3){
    for (int i = blockIdx.x * blockDim.x + threadIdx.x; i < total; i += gridDim.x * blockDim.x){
      float v = w.w[i];
      unsigned short h = f2bf_rne(v);
      w.th[i] = h;
      w.tl[i] = f2bf_rne(v - bf2f(h));
    }
    return;
  }
  for (int i = blockIdx.x * blockDim.x + threadIdx.x; i < total; i += gridDim.x * blockDim.x){
    int k = i / w.Nc, n = i % w.Nc;
    int kd = (w.perm == 1) ? ((k & 63) * 4 + (k >> 6)) : k;
    int nd = (w.perm == 2) ? (((n & 63) << 2) | (n >> 6)) : n;
    float v = w.w[i];
    unsigned short h = f2bf_rne(v);
    w.th[(size_t)nd * w.K + kd] = h;
    w.tl[(size_t)nd * w.K + kd] = f2bf_rne(v - bf2f(h));
  }
}

// ---------------- GEMM term helper ----------------
__device__ __forceinline__ void gemm_term(floatx16& acc0, floatx16& acc1,
    const unsigned short* __restrict__ Ah, const unsigned short* __restrict__ Al,
    const unsigned short* __restrict__ Bh, const unsigned short* __restrict__ Bl,
    int K, int lda, int arow, int lr, int ko8){
  const unsigned short* ap  = Ah + (size_t)arow * lda + ko8;
  const unsigned short* alp = Al ? Al + (size_t)arow * lda + ko8 : nullptr;
  const unsigned short* bh0 = Bh + (size_t)lr * K + ko8;
  const unsigned short* bl0 = Bl + (size_t)lr * K + ko8;
  const unsigned short* bh1 = bh0 + (size_t)32 * K;
  const unsigned short* bl1 = bl0 + (size_t)32 * K;
  for (int k0 = 0; k0 < K; k0 += 16){
    short8 a  = *(const short8*)(ap + k0);
    short8 h0 = *(const short8*)(bh0 + k0);
    short8 l0 = *(const short8*)(bl0 + k0);
    short8 h1 = *(const short8*)(bh1 + k0);
    short8 l1 = *(const short8*)(bl1 + k0);
    if (alp){
      short8 a2 = *(const short8*)(alp + k0);
      acc0 = __builtin_amdgcn_mfma_f32_32x32x16_bf16(a2, h0, acc0, 0, 0, 0);
      acc1 = __builtin_amdgcn_mfma_f32_32x32x16_bf16(a2, h1, acc1, 0, 0, 0);
    }
    acc0 = __builtin_amdgcn_mfma_f32_32x32x16_bf16(a, l0, acc0, 0, 0, 0);
    acc0 = __builtin_amdgcn_mfma_f32_32x32x16_bf16(a, h0, acc0, 0, 0, 0);
    acc1 = __builtin_amdgcn_mfma_f32_32x32x16_bf16(a, l1, acc1, 0, 0, 0);
    acc1 = __builtin_amdgcn_mfma_f32_32x32x16_bf16(a, h1, acc1, 0, 0, 0);
  }
}

// ---------------- batched MFMA GEMM: out = act(A1@B1 [+A2@B2] + bias), Nc=64, bf16 out ----
// Optional fused per-row 64->2 reduction (fc2 head, or attn coeffs via interleaved weights):
//   outf[row*2+q] = sum_col v[col] * fc2w[col*2+q] + (fc2b?fc2b[q]:0)
struct BDesc {
  const unsigned short *A1h, *A1l, *B1h, *B1l;
  const unsigned short *A2h, *A2l, *B2h, *B2l;
  int K1, lda1, K2, lda2;
  const float* bias;
  unsigned short* out; int ldc, coloff, act;
  const float* fc2w; const float* fc2b; float* outf;
};
struct BPack { BDesc d[3]; };
__global__ __launch_bounds__(256) void k_gemm_b(BPack p, int M){
  BDesc d = p.d[blockIdx.y];
  int wave = threadIdx.x >> 6, lane = threadIdx.x & 63;
  int m0 = blockIdx.x * 128 + wave * 32;
  int lr = lane & 31;
  int ko8 = (lane >> 5) * 8;
  floatx16 acc0 = {0,0,0,0,0,0,0,0,0,0,0,0,0,0,0,0};
  floatx16 acc1 = {0,0,0,0,0,0,0,0,0,0,0,0,0,0,0,0};
  int arow = m0 + lr; if (arow >= M) arow = M - 1;
  gemm_term(acc0, acc1, d.A1h, d.A1l, d.B1h, d.B1l, d.K1, d.lda1, arow, lr, ko8);
  if (d.K2) gemm_term(acc0, acc1, d.A2h, d.A2l, d.B2h, d.B2l, d.K2, d.lda2, arow, lr, ko8);
  int col0 = lr, col1 = lr + 32;
  float bias0 = d.bias ? d.bias[col0] : 0.f;
  float bias1 = d.bias ? d.bias[col1] : 0.f;
  float w00 = 0.f, w01 = 0.f, w10 = 0.f, w11 = 0.f, fb0 = 0.f, fb1 = 0.f;
  if (d.fc2w){
    w00 = d.fc2w[col0 * 2 + 0]; w01 = d.fc2w[col0 * 2 + 1];
    w10 = d.fc2w[col1 * 2 + 0]; w11 = d.fc2w[col1 * 2 + 1];
    if (d.fc2b){ fb0 = d.fc2b[0]; fb1 = d.fc2b[1]; }
  }
  int rbase = m0 + 4 * (lane >> 5);
  #pragma unroll
  for (int reg = 0; reg < 16; reg++){
    int row = rbase + (reg & 3) + 8 * (reg >> 2);
    float v0 = acc0[reg] + bias0;
    float v1 = acc1[reg] + bias1;
    if (d.act){ v0 = fmaxf(v0, 0.f); v1 = fmaxf(v1, 0.f); }
    if (d.out && row < M){
      d.out[(size_t)row * d.ldc + d.coloff + col0] = f2bf_rne(v0);
      d.out[(size_t)row * d.ldc + d.coloff + col1] = f2bf_rne(v1);
    }
    if (d.fc2w){
      // half-wave reduction: lanes 0-31 hold one row, lanes 32-63 hold row+4
      float p0 = v0 * w00 + v1 * w10;
      float p1 = v0 * w01 + v1 * w11;
      #pragma unroll
      for (int off = 16; off > 0; off >>= 1){
        p0 += __shfl_xor(p0, off, 64);
        p1 += __shfl_xor(p1, off, 64);
      }
      if ((lane & 31) == 0 && row < M){
        d.outf[(size_t)row * 2 + 0] = p0 + fb0;
        d.outf[(size_t)row * 2 + 1] = p1 + fb1;
      }
    }
  }
}

// ---------------- GEMM320: C = x @ [gat1|gcn1], cols<256 -> gath (ld 256), else g1h (ld 64) ----
__global__ __launch_bounds__(256) void k_gemm320(
    const unsigned short* __restrict__ Ah, const unsigned short* __restrict__ Al,
    const unsigned short* __restrict__ Bh, const unsigned short* __restrict__ Bl,
    unsigned short* __restrict__ C1, unsigned short* __restrict__ C2, int M)
{
  const int K = 128;
  int wave = threadIdx.x >> 6, lane = threadIdx.x & 63;
  int m0 = blockIdx.x * 128 + wave * 32;
  int n0 = blockIdx.y * 64;
  int lr = lane & 31;
  int ko8 = (lane >> 5) * 8;
  floatx16 acc0 = {0,0,0,0,0,0,0,0,0,0,0,0,0,0,0,0};
  floatx16 acc1 = {0,0,0,0,0,0,0,0,0,0,0,0,0,0,0,0};
  int arow = m0 + lr; if (arow >= M) arow = M - 1;
  const unsigned short* ap_h = Ah + (size_t)arow * K + ko8;
  const unsigned short* ap_l = Al + (size_t)arow * K + ko8;
  const unsigned short* bp_h0 = Bh + (size_t)(n0 + lr) * K + ko8;
  const unsigned short* bp_l0 = Bl + (size_t)(n0 + lr) * K + ko8;
  const unsigned short* bp_h1 = bp_h0 + (size_t)32 * K;
  const unsigned short* bp_l1 = bp_l0 + (size_t)32 * K;
  for (int k0 = 0; k0 < K; k0 += 16){
    short8 a_h  = *(const short8*)(ap_h + k0);
    short8 a_l  = *(const short8*)(ap_l + k0);
    short8 b_h0 = *(const short8*)(bp_h0 + k0);
    short8 b_l0 = *(const short8*)(bp_l0 + k0);
    short8 b_h1 = *(const short8*)(bp_h1 + k0);
    short8 b_l1 = *(const short8*)(bp_l1 + k0);
    acc0 = __builtin_amdgcn_mfma_f32_32x32x16_bf16(a_l, b_h0, acc0, 0, 0, 0);
    acc0 = __builtin_amdgcn_mfma_f32_32x32x16_bf16(a_h, b_l0, acc0, 0, 0, 0);
    acc0 = __builtin_amdgcn_mfma_f32_32x32x16_bf16(a_h, b_h0, acc0, 0, 0, 0);
    acc1 = __builtin_amdgcn_mfma_f32_32x32x16_bf16(a_l, b_h1, acc1, 0, 0, 0);
    acc1 = __builtin_amdgcn_mfma_f32_32x32x16_bf16(a_h, b_l1, acc1, 0, 0, 0);
    acc1 = __builtin_amdgcn_mfma_f32_32x32x16_bf16(a_h, b_h1, acc1, 0, 0, 0);
  }
  int col0 = n0 + lr, col1 = col0 + 32;
  unsigned short* Cp; int ld, c0, c1;
  if (col0 >= 256){ Cp = C2; ld = 64; c0 = col0 - 256; c1 = col1 - 256; }
  else { Cp = C1; ld = 256; c0 = col0; c1 = col1; }
  int rbase = m0 + 4 * (lane >> 5);
  #pragma unroll
  for (int reg = 0; reg < 16; reg++){
    int row = rbase + (reg & 3) + 8 * (reg >> 2);
    if (row >= M) continue;
    Cp[(size_t)row * ld + c0] = f2bf_rne(acc0[reg]);
    Cp[(size_t)row * ld + c1] = f2bf_rne(acc1[reg]);
  }
}

// ---------------- GAT1 attention coeffs (interleaved bf16 h) ----------------
__global__ __launch_bounds__(256) void k_gat_attn4(
    const unsigned short* __restrict__ h, const float* __restrict__ asrc,
    const float* __restrict__ adst, float* __restrict__ a_s, float* __restrict__ a_d, int n){
  int node = blockIdx.x * 4 + (threadIdx.x >> 6);
  int c = threadIdx.x & 63;
  if (node >= n) return;
  uint2 u = *(const uint2*)(h + (size_t)node * 256 + c * 4);
  float2 p0 = bf2x(u.x), p1 = bf2x(u.y);
  float s0 = wave_sum(p0.x * asrc[c]);
  float s1 = wave_sum(p0.y * asrc[64 + c]);
  float s2 = wave_sum(p1.x * asrc[128 + c]);
  float s3 = wave_sum(p1.y * asrc[192 + c]);
  float d0 = wave_sum(p0.x * adst[c]);
  float d1 = wave_sum(p0.y * adst[64 + c]);
  float d2 = wave_sum(p1.x * adst[128 + c]);
  float d3 = wave_sum(p1.y * adst[192 + c]);
  if (c == 0){
    *(float4*)(a_s + (size_t)node * 4) = make_float4(s0, s1, s2, s3);
    *(float4*)(a_d + (size_t)node * 4) = make_float4(d0, d1, d2, d3);
  }
}

// ---------------- per-edge softmax numerators (layer 1, packed bf16) ----------------
__global__ void k_edge_w4(const int* __restrict__ colv, const int* __restrict__ dstv,
                          const float* __restrict__ a_s, const float* __restrict__ a_d,
                          unsigned short* __restrict__ w4b, int E){
  int i = blockIdx.x * blockDim.x + threadIdx.x;
  if (i >= E) return;
  float4 s4 = *(const float4*)(a_s + (size_t)colv[i] * 4);
  float4 d4 = *(const float4*)(a_d + (size_t)dstv[i] * 4);
  float w0 = __expf(d_leaky(s4.x + d4.x));
  float w1 = __expf(d_leaky(s4.y + d4.y));
  float w2 = __expf(d_leaky(s4.z + d4.z));
  float w3 = __expf(d_leaky(s4.w + d4.w));
  uint2 q;
  q.x = (unsigned int)f2bf_rne(w0) | ((unsigned int)f2bf_rne(w1) << 16);
  q.y = (unsigned int)f2bf_rne(w2) | ((unsigned int)f2bf_rne(w3) << 16);
  *(uint2*)(w4b + (size_t)i * 4) = q;
}

// ---------------- L1AGG: fused GAT1-agg (4 heads) + GCN1-agg + SAGE-x-agg ----------------
__global__ __launch_bounds__(256) void k_l1agg(
    const unsigned short* __restrict__ gath, const unsigned short* __restrict__ xh,
    const unsigned short* __restrict__ g1h,
    const int* __restrict__ rowp, const int* __restrict__ colv,
    const unsigned short* __restrict__ w4b,
    const float* __restrict__ a_s, const float* __restrict__ a_d,
    const float* __restrict__ gat1_b, const float* __restrict__ gcn1_b,
    const float* __restrict__ dinv, const float* __restrict__ sdinv,
    unsigned short* __restrict__ oh, unsigned short* __restrict__ g2h,
    unsigned short* __restrict__ aggXh, int n)
{
  int node = blockIdx.x * 4 + (threadIdx.x >> 6);
  int c = threadIdx.x & 63;
  if (node >= n) return;
  float4 asn = *(const float4*)(a_s + (size_t)node * 4);
  float4 adn = *(const float4*)(a_d + (size_t)node * 4);
  float ws0 = __expf(d_leaky(asn.x + adn.x));
  float ws1 = __expf(d_leaky(asn.y + adn.y));
  float ws2 = __expf(d_leaky(asn.z + adn.z));
  float ws3 = __expf(d_leaky(asn.w + adn.w));
  uint2 su = *(const uint2*)(gath + (size_t)node * 256 + c * 4);
  float2 sp0 = bf2x(su.x), sp1 = bf2x(su.y);
  float den0 = ws0, den1 = ws1, den2 = ws2, den3 = ws3;
  float acc0 = ws0 * sp0.x, acc1 = ws1 * sp0.y, acc2 = ws2 * sp1.x, acc3 = ws3 * sp1.y;
  float di = dinv[node];
  float gacc = di * bf2f(g1h[(size_t)node * 64 + c]);
  float sx0 = 0.f, sx1 = 0.f;
  int b = rowp[node], e = rowp[node + 1];
  for (int i = b; i < e; i += 8){
    int idx[8]; float mm[8]; int s[8];
    #pragma unroll
    for (int j = 0; j < 8; j++){
      int t = i + j;
      mm[j] = (t < e) ? 1.f : 0.f;
      idx[j] = (t < e) ? t : (e - 1);
    }
    #pragma unroll
    for (int j = 0; j < 8; j++) s[j] = colv[idx[j]];
    uint2 wq[8];
    #pragma unroll
    for (int j = 0; j < 8; j++) wq[j] = *(const uint2*)(w4b + (size_t)idx[j] * 4);
    uint2 hv[8];
    #pragma unroll
    for (int j = 0; j < 8; j++) hv[j] = *(const uint2*)(gath + (size_t)s[j] * 256 + c * 4);
    unsigned int hx[8];
    #pragma unroll
    for (int j = 0; j < 8; j++) hx[j] = *(const unsigned int*)(xh + (size_t)s[j] * 128 + c * 2);
    unsigned short hg[8];
    #pragma unroll
    for (int j = 0; j < 8; j++) hg[j] = g1h[(size_t)s[j] * 64 + c];
    float wd[8];
    #pragma unroll
    for (int j = 0; j < 8; j++) wd[j] = dinv[s[j]];
    #pragma unroll
    for (int j = 0; j < 8; j++){
      float m = mm[j];
      float2 w01 = bf2x(wq[j].x), w23 = bf2x(wq[j].y);
      float w0 = m * w01.x, w1 = m * w01.y, w2 = m * w23.x, w3 = m * w23.y;
      float2 a = bf2x(hv[j].x), bb = bf2x(hv[j].y);
      den0 += w0; den1 += w1; den2 += w2; den3 += w3;
      acc0 += w0 * a.x;  acc1 += w1 * a.y;
      acc2 += w2 * bb.x; acc3 += w3 * bb.y;
      gacc += m * wd[j] * bf2f(hg[j]);
      float2 p = bf2x(hx[j]);
      sx0 += m * p.x; sx1 += m * p.y;
    }
  }
  float v0 = d_elu(acc0 / (den0 + 1e-16f) + gat1_b[c]);
  float v1 = d_elu(acc1 / (den1 + 1e-16f) + gat1_b[64 + c]);
  float v2 = d_elu(acc2 / (den2 + 1e-16f) + gat1_b[128 + c]);
  float v3 = d_elu(acc3 / (den3 + 1e-16f) + gat1_b[192 + c]);
  uint2 ohv;
  ohv.x = (unsigned int)f2bf_rne(v0) | ((unsigned int)f2bf_rne(v1) << 16);
  ohv.y = (unsigned int)f2bf_rne(v2) | ((unsigned int)f2bf_rne(v3) << 16);
  *(uint2*)(oh + (size_t)node * 256 + c * 4) = ohv;
  g2h[(size_t)node * 64 + c] = f2bf_rne(fmaxf(di * gacc + gcn1_b[c], 0.f));
  float sd = sdinv[node];
  *(unsigned int*)(aggXh + (size_t)node * 128 + c * 2) =
      (unsigned int)f2bf_rne(sx0 * sd) | ((unsigned int)f2bf_rne(sx1 * sd) << 16);
}

// ---------------- F2: fused GAT2-agg (inline edge weights) + GCN2-agg + SAGE-s1-agg ----------------
// m192 cols: 0-63 = t1 (GAT2 GEMM), 64-127 = tg2 (GCN2 GEMM), 128-191 = s1 (SAGE1 GEMM)
// as2ad2: interleaved per-node [a_s, a_d] produced by the GEMM epilogue.
__global__ __launch_bounds__(256) void k_f2(
    const unsigned short* __restrict__ m192,
    const int* __restrict__ rowp, const int* __restrict__ colv,
    const float* __restrict__ as2ad2,
    const float* __restrict__ dinv, const float* __restrict__ sdinv,
    const float* __restrict__ gat2_b, const float* __restrict__ gcn2_b,
    unsigned short* __restrict__ cat,   // [N][192], writes cols 0-127
    unsigned short* __restrict__ aggSh, // [N][64]
    int n){
  int node = blockIdx.x * 4 + (threadIdx.x >> 6);
  int c = threadIdx.x & 63;
  if (node >= n) return;
  float di = dinv[node];
  const unsigned short* srow = m192 + (size_t)node * 192;
  float adn = as2ad2[node * 2 + 1];
  float tden = __expf(d_leaky(as2ad2[node * 2 + 0] + adn));
  float tacc = tden * bf2f(srow[c]);
  float gacc = di * bf2f(srow[64 + c]);
  float sacc = 0.f;
  int b = rowp[node], e = rowp[node + 1];
  for (int i = b; i < e; i += 8){
    int idx[8]; float mm[8]; int s[8];
    #pragma unroll
    for (int j = 0; j < 8; j++){
      int t = i + j;
      mm[j] = (t < e) ? 1.f : 0.f;
      idx[j] = (t < e) ? t : (e - 1);
    }
    #pragma unroll
    for (int j = 0; j < 8; j++) s[j] = colv[idx[j]];
    float w[8];
    #pragma unroll
    for (int j = 0; j < 8; j++) w[j] = mm[j] * __expf(d_leaky(as2ad2[(size_t)s[j] * 2] + adn));
    unsigned short ht[8], hg[8], hs[8];
    #pragma unroll
    for (int j = 0; j < 8; j++){
      const unsigned short* r = m192 + (size_t)s[j] * 192;
      ht[j] = r[c]; hg[j] = r[64 + c]; hs[j] = r[128 + c];
    }
    float wd[8];
    #pragma unroll
    for (int j = 0; j < 8; j++) wd[j] = dinv[s[j]];
    #pragma unroll
    for (int j = 0; j < 8; j++){
      tden += w[j]; tacc += w[j] * bf2f(ht[j]);
      gacc += mm[j] * wd[j] * bf2f(hg[j]);
      sacc += mm[j] * bf2f(hs[j]);
    }
  }
  cat[(size_t)node * 192 + 64 + c] = f2bf_rne(d_elu(tacc / (tden + 1e-16f) + gat2_b[c]));
  cat[(size_t)node * 192 + c] = f2bf_rne(fmaxf(di * gacc + gcn2_b[c], 0.f));
  aggSh[(size_t)node * 64 + c] = f2bf_rne(sacc * sdinv[node]);
}

// ---------------- BN stats (grid 128x3) + last-block BN-fold into fc1 weights ----------------
__global__ __launch_bounds__(256) void k_bn_stats_fold(
    const unsigned short* __restrict__ x,
    float* __restrict__ bnGCN, float* __restrict__ bnGAT, float* __restrict__ bnSAGE,
    const float* __restrict__ gg, const float* __restrict__ gb,
    const float* __restrict__ ag, const float* __restrict__ ab,
    const float* __restrict__ sg, const float* __restrict__ sb,
    const float* __restrict__ w, const float* __restrict__ wb, float nf,
    unsigned short* __restrict__ fwh, unsigned short* __restrict__ fwl, float* __restrict__ fb,
    int* __restrict__ done, int nblocks, int n)
{
  int seg = blockIdx.y;
  float* sums = (seg == 0) ? bnGCN : (seg == 1) ? bnGAT : bnSAGE;
  int co = seg * 64;
  int c = threadIdx.x & 63;
  int rl = threadIdx.x >> 6;
  float s = 0.f, q = 0.f;
  for (int r = blockIdx.x * 4 + rl; r < n; r += gridDim.x * 4){
    float v = bf2f(x[(size_t)r * 192 + co + c]);
    s += v; q += v * v;
  }
  __shared__ float ls[4][64], lq[4][64];
  ls[rl][c] = s; lq[rl][c] = q;
  __syncthreads();
  if (rl == 0){
    s = ls[0][c] + ls[1][c] + ls[2][c] + ls[3][c];
    q = lq[0][c] + lq[1][c] + lq[2][c] + lq[3][c];
    atomicAdd(&sums[c], s);
    atomicAdd(&sums[64 + c], q);
  }
  __syncthreads();
  __shared__ int lastflag;
  if (threadIdx.x == 0){
    __threadfence();
    int old = atomicAdd(done, 1);
    lastflag = (old == nblocks - 1);
  }
  __syncthreads();
  if (!lastflag) return;
  __threadfence();
  // ---- fold (runs in the last-finishing block only) ----
  __shared__ float sbn[3][128];
  for (int i = threadIdx.x; i < 384; i += 256){
    float* p = (i < 128) ? bnGCN : (i < 256) ? bnGAT : bnSAGE;
    sbn[i >> 7][i & 127] = atomicAdd(&p[i & 127], 0.0f);  // coherent read
  }
  __syncthreads();
  int tid = threadIdx.x;
  auto st = [&](int c2, float& sc, float& tc){
    int cc = c2 & 63;
    int sg2 = c2 >> 6;  // 0 gcn, 1 gat, 2 sage
    const float *g, *b;
    if (sg2 == 0){ g = gg; b = gb; }
    else if (sg2 == 1){ g = ag; b = ab; }
    else { g = sg; b = sb; }
    float m = sbn[sg2][cc] / nf;
    float var = sbn[sg2][64 + cc] / nf - m * m;
    float inv = rsqrtf(var + BN_EPS);
    sc = inv * g[cc];
    tc = b[cc] - m * inv * g[cc];
  };
  if (tid < 64){
    float acc = wb[tid];
    for (int c2 = 0; c2 < 192; c2++){
      float sc, tc; st(c2, sc, tc);
      acc += tc * w[c2 * 64 + tid];
    }
    fb[tid] = acc;
  }
  for (int i = tid; i < 192 * 64; i += 256){
    int c2 = i >> 6, nn = i & 63;
    float sc, tc; st(c2, sc, tc);
    float v = sc * w[i];
    unsigned short hh = f2bf_rne(v);
    fwh[nn * 192 + c2] = hh;
    fwl[nn * 192 + c2] = f2bf_rne(v - bf2f(hh));
  }
}

extern "C" void kernel_launch(void* const* d_in, const int* in_sizes, int n_in,
                              void* d_out, int out_size, void* d_ws, size_t ws_size,
                              hipStream_t stream){
  (void)n_in; (void)out_size; (void)ws_size;
  const float* x        = (const float*)d_in[0];
  const int*   ei       = (const int*)  d_in[1];
  const float* gcn1_w   = (const float*)d_in[2];
  const float* gcn1_b   = (const float*)d_in[3];
  const float* gcn2_w   = (const float*)d_in[4];
  const float* gcn2_b   = (const float*)d_in[5];
  const float* gat1_w   = (const float*)d_in[6];
  const float* gat1_as  = (const float*)d_in[7];
  const float* gat1_ad  = (const float*)d_in[8];
  const float* gat1_b   = (const float*)d_in[9];
  const float* gat2_w   = (const float*)d_in[10];
  const float* gat2_as  = (const float*)d_in[11];
  const float* gat2_ad  = (const float*)d_in[12];
  const float* gat2_b   = (const float*)d_in[13];
  const float* sage1_wl = (const float*)d_in[14];
  const float* sage1_bl = (const float*)d_in[15];
  const float* sage1_wr = (const float*)d_in[16];
  const float* sage2_wl = (const float*)d_in[17];
  const float* sage2_bl = (const float*)d_in[18];
  const float* sage2_wr = (const float*)d_in[19];
  const float* bn_gcn_g = (const float*)d_in[20];
  const float* bn_gcn_b = (const float*)d_in[21];
  const float* bn_gat_g = (const float*)d_in[22];
  const float* bn_gat_b = (const float*)d_in[23];
  const float* bn_sage_g= (const float*)d_in[24];
  const float* bn_sage_b= (const float*)d_in[25];
  const float* fc1_w    = (const float*)d_in[26];
  const float* fc1_b    = (const float*)d_in[27];
  const float* fc2_w    = (const float*)d_in[28];
  const float* fc2_b    = (const float*)d_in[29];
  float* out = (float*)d_out;

  const int N = in_sizes[0] / 128;
  const int E = in_sizes[1] / 2;
  const int* src = ei;
  const int* dst = ei + E;
  const int nb = (N + 1023) / 1024;

  char* ws = (char*)d_ws;
  size_t off = 0;
  auto alloc = [&](size_t bytes) -> void* {
    void* p = ws + off;
    off = (off + bytes + 255) & ~(size_t)255;
    return p;
  };
  // contiguous zero region: deg, bnA, bnB, bnC, done
  char* zbase = (char*)alloc(0);
  int*   deg   = (int*)  alloc((size_t)N * 4);
  float* bnA   = (float*)alloc(128 * 4);
  float* bnB   = (float*)alloc(128 * 4);
  float* bnC   = (float*)alloc(128 * 4);
  int*   done  = (int*)  alloc(4);
  size_t zbytes = (size_t)((char*)alloc(0) - zbase);
  int*   rowp  = (int*)  alloc((size_t)(N + 1) * 4);
  int*   fill  = (int*)  alloc((size_t)N * 4);
  int*   colv  = (int*)  alloc((size_t)E * 4);
  int*   dstv  = (int*)  alloc((size_t)E * 4);
  int*   bsum  = (int*)  alloc(64 * 4);
  float* dinv  = (float*)alloc((size_t)N * 4);
  float* sdinv = (float*)alloc((size_t)N * 4);
  float* as1   = (float*)alloc((size_t)N * 4 * 4);
  float* ad1   = (float*)alloc((size_t)N * 4 * 4);
  float* as2ad2= (float*)alloc((size_t)N * 2 * 4);
  float* aw2   = (float*)alloc(128 * 4);
  unsigned short* w4b = (unsigned short*)alloc((size_t)E * 4 * 2);
  unsigned short* xh    = (unsigned short*)alloc((size_t)N * 128 * 2);
  unsigned short* xl    = (unsigned short*)alloc((size_t)N * 128 * 2);
  unsigned short* gath  = (unsigned short*)alloc((size_t)N * 256 * 2);   // GAT1 out (ilv)
  unsigned short* oh    = (unsigned short*)alloc((size_t)N * 256 * 2);   // l1agg GAT out (ilv)
  unsigned short* g1h   = (unsigned short*)alloc((size_t)N * 64 * 2);
  unsigned short* g2h   = (unsigned short*)alloc((size_t)N * 64 * 2);
  unsigned short* aggXh = (unsigned short*)alloc((size_t)N * 128 * 2);
  unsigned short* aggSh = (unsigned short*)alloc((size_t)N * 64 * 2);
  unsigned short* m192  = (unsigned short*)alloc((size_t)N * 192 * 2);   // t1|tg2|s1
  unsigned short* cath  = (unsigned short*)alloc((size_t)N * 192 * 2);
  // weights
  unsigned short* b320h = (unsigned short*)alloc((size_t)320 * 128 * 2); // gat1(256,col-perm) + gcn1(64)
  unsigned short* b320l = (unsigned short*)alloc((size_t)320 * 128 * 2);
  unsigned short* gcn2h = (unsigned short*)alloc((size_t)64 * 64 * 2);
  unsigned short* gcn2l = (unsigned short*)alloc((size_t)64 * 64 * 2);
  unsigned short* gat2h = (unsigned short*)alloc((size_t)64 * 256 * 2);
  unsigned short* gat2l = (unsigned short*)alloc((size_t)64 * 256 * 2);
  unsigned short* s1wlh = (unsigned short*)alloc((size_t)64 * 128 * 2);
  unsigned short* s1wll = (unsigned short*)alloc((size_t)64 * 128 * 2);
  unsigned short* s1wrh = (unsigned short*)alloc((size_t)64 * 128 * 2);
  unsigned short* s1wrl = (unsigned short*)alloc((size_t)64 * 128 * 2);
  unsigned short* s2wlh = (unsigned short*)alloc((size_t)64 * 64 * 2);
  unsigned short* s2wll = (unsigned short*)alloc((size_t)64 * 64 * 2);
  unsigned short* s2wrh = (unsigned short*)alloc((size_t)64 * 64 * 2);
  unsigned short* s2wrl = (unsigned short*)alloc((size_t)64 * 64 * 2);
  unsigned short* fwh   = (unsigned short*)alloc((size_t)64 * 192 * 2);
  unsigned short* fwl   = (unsigned short*)alloc((size_t)64 * 192 * 2);
  float* fb             = (float*)alloc(64 * 4);

  hipMemsetAsync(zbase, 0, zbytes, stream);

  // CSR by destination (scan_b folded into scan_c; fill pre-init to rowp)
  k_count <<<(E + 255) / 256, 256, 0, stream>>>(dst, deg, E, gat2_as, gat2_ad, aw2);
  k_scan_a<<<nb, 256, 0, stream>>>(deg, bsum, N);
  k_scan_c<<<nb, 256, 0, stream>>>(deg, bsum, rowp, fill, dinv, sdinv, N, nb);
  k_scatter<<<(E + 255) / 256, 256, 0, stream>>>(src, dst, fill, colv, dstv, E);

  // weight splits + x split (one launch)
  {
    WPack p;
    p.d[0] = {gat1_w, b320h, b320l, 128, 256, 2};                        // col-perm (head-ilv C)
    p.d[1] = {gcn1_w, b320h + 256 * 128, b320l + 256 * 128, 128, 64, 0};
    p.d[2] = {gat2_w, gat2h, gat2l, 256, 64, 1};                         // K-perm (ilv A)
    p.d[3] = {sage1_wl, s1wlh, s1wll, 128, 64, 0};
    p.d[4] = {sage1_wr, s1wrh, s1wrl, 128, 64, 0};
    p.d[5] = {sage2_wl, s2wlh, s2wll, 64, 64, 0};
    p.d[6] = {sage2_wr, s2wrh, s2wrl, 64, 64, 0};
    p.d[7] = {gcn2_w, gcn2h, gcn2l, 64, 64, 0};
    p.d[8] = {x, xh, xl, N, 128, 3};                                     // plain split
    dim3 g(1024, 9);
    k_wsplit<<<g, 256, 0, stream>>>(p);
  }

  const int gx = (N + 127) / 128;
  const int gn = (N + 3) / 4;

  // GAT1 + GCN1 fused GEMM (B = 320 cols)
  {
    dim3 g(gx, 5);
    k_gemm320<<<g, 256, 0, stream>>>(xh, xl, b320h, b320l, gath, g1h, N);
  }
  k_gat_attn4<<<gn, 256, 0, stream>>>(gath, gat1_as, gat1_ad, as1, ad1, N);
  k_edge_w4<<<(E + 255) / 256, 256, 0, stream>>>(colv, dstv, as1, ad1, w4b, E);
  // fused layer-1 aggregation: GAT1-agg + GCN1-agg + SAGE-x-agg
  k_l1agg<<<gn, 256, 0, stream>>>(gath, xh, g1h, rowp, colv, w4b, as1, ad1,
                                  gat1_b, gcn1_b, dinv, sdinv, oh, g2h, aggXh, N);

  // batched GEMM: GAT2 (K=256, + fused attn1 epilogue) | GCN2 (K=64) | SAGE1 dual -> m192
  {
    BPack p;
    p.d[0] = {oh, nullptr, gat2h, gat2l, nullptr, nullptr, nullptr, nullptr,
              256, 256, 0, 0, nullptr, m192, 192, 0, 0, aw2, nullptr, as2ad2};
    p.d[1] = {g2h, nullptr, gcn2h, gcn2l, nullptr, nullptr, nullptr, nullptr,
              64, 64, 0, 0, nullptr, m192, 192, 64, 0, nullptr, nullptr, nullptr};
    p.d[2] = {aggXh, nullptr, s1wlh, s1wll, xh, xl, s1wrh, s1wrl,
              128, 128, 128, 128, sage1_bl, m192, 192, 128, 1, nullptr, nullptr, nullptr};
    dim3 g(gx, 3);
    k_gemm_b<<<g, 256, 0, stream>>>(p, N);
  }
  // F2: GAT2-agg (inline edge weights) + GCN2-agg + SAGE-s1-agg
  k_f2<<<gn, 256, 0, stream>>>(m192, rowp, colv, as2ad2, dinv, sdinv,
                               gat2_b, gcn2_b, cath, aggSh, N);

  // SAGE2 dual GEMM -> cat cols 128-191
  {
    BPack p;
    p.d[0] = {aggSh, nullptr, s2wlh, s2wll, m192 + 128, nullptr, s2wrh, s2wrl,
              64, 64, 64, 192, sage2_bl, cath, 192, 128, 1, nullptr, nullptr, nullptr};
    p.d[1] = p.d[0]; p.d[2] = p.d[0];
    dim3 g(gx, 1);
    k_gemm_b<<<g, 256, 0, stream>>>(p, N);
  }

  // BN stats + last-block fold into fc1 weights (one launch)
  {
    dim3 g(128, 3);
    k_bn_stats_fold<<<g, 256, 0, stream>>>(cath, bnB, bnA, bnC,
                                           bn_gcn_g, bn_gcn_b, bn_gat_g, bn_gat_b,
                                           bn_sage_g, bn_sage_b,
                                           fc1_w, fc1_b, (float)N, fwh, fwl, fb,
                                           done, 128 * 3, N);
  }

  // FC1 GEMM with fused 64->2 FC2 epilogue -> out
  {
    BPack p;
    p.d[0] = {cath, nullptr, fwh, fwl, nullptr, nullptr, nullptr, nullptr,
              192, 192, 0, 0, fb, nullptr, 64, 0, 1, fc2_w, fc2_b, out};
    p.d[1] = p.d[0]; p.d[2] = p.d[0];
    dim3 g(gx, 1);
    k_gemm_b<<<g, 256, 0, stream>>>(p, N);
  }
}